// Round 1
// baseline (1081.085 us; speedup 1.0000x reference)
//
#include <hip/hip_runtime.h>

// GraphTemporal: N=50000 nodes, E=500000 edges, B=64 graphs, H=64, L=4 shared layers.
// fp32 baseline. Edge MLP algebraically reduced:
//   msg[j,h] = relu( y[row_j,h] + dist_j*p[h] + q[h] ),  y = x @ W_el[:, :64].T
//   p = W_el[:,64:] @ W_edge,  q = W_el[:,64:] @ b_edge + b_el
// scatter-max via atomicMax on float bits (msg >= 0, agg init 0 == empty-segment value).
// Workspace (floats): x[N*64] | y[N*64] | agg[N*64] | u[4096] | xu_enc[4096 u32]
//                     | cgr[64*256] | p[64] | q[64] | Wt1[128*256] | Wn2t[256*64]
// total ~36.9 MB.

__global__ void k_xinit(const float* __restrict__ v0, const float* __restrict__ v1,
                        const float* __restrict__ wte,
                        const float* __restrict__ Wi0, const float* __restrict__ bi0,
                        const float* __restrict__ Wi1, const float* __restrict__ bi1,
                        float* __restrict__ x, int N) {
  int idx = blockIdx.x * 256 + threadIdx.x;
  if (idx >= N * 64) return;
  int n = idx >> 6, h = idx & 63;
  x[idx] = wte[h] + wte[64 + h] + bi0[h] + bi1[h] + v0[n] * Wi0[h] + v1[n] * Wi1[h];
}

__global__ void k_prep_pq(const float* __restrict__ W_el, const float* __restrict__ b_el,
                          const float* __restrict__ W_edge, const float* __restrict__ b_edge,
                          float* __restrict__ p, float* __restrict__ q) {
  int h = threadIdx.x;  // 64 threads
  float pp = 0.f, qq = 0.f;
  for (int k = 0; k < 64; ++k) {
    float w = W_el[h * 128 + 64 + k];
    pp += w * W_edge[k];
    qq += w * b_edge[k];
  }
  p[h] = pp;
  q[h] = qq + b_el[h];
}

// init u=0, xu_enc=enc(-inf), cgr=b_n1 (u=0 for layer 0), transpose W_n1[:, :128] and W_n2
__global__ void k_prep_misc(float* __restrict__ u, unsigned* __restrict__ xu_enc,
                            float* __restrict__ cgr, float* __restrict__ Wt1,
                            float* __restrict__ Wn2t,
                            const float* __restrict__ b_n1,
                            const float* __restrict__ W_n1, const float* __restrict__ W_n2) {
  int gt = blockIdx.x * 256 + threadIdx.x;
  if (gt < 4096) {
    u[gt] = 0.f;
  } else if (gt < 8192) {
    xu_enc[gt - 4096] = 0x007FFFFFu;  // enc(-inf)
  } else if (gt < 24576) {
    int i = gt - 8192;
    cgr[i] = b_n1[i & 255];
  } else if (gt < 57344) {
    int i = gt - 24576;           // [128][256]
    int k = i >> 8, o = i & 255;
    Wt1[i] = W_n1[o * 192 + k];   // cols 0..127 = [agg | x]
  } else if (gt < 73728) {
    int i = gt - 57344;           // [256][64]
    int o = i >> 6, h = i & 63;
    Wn2t[i] = W_n2[h * 256 + o];
  }
}

// y = x @ W_el[:, :64].T   (block: 64 nodes, 256 threads)
__global__ __launch_bounds__(256) void k_ygemm(const float* __restrict__ x,
                                               const float* __restrict__ W_el,
                                               float* __restrict__ y, int N) {
  __shared__ float xT[64 * 68];   // [k][n], pad 68 (272B rows, 16B aligned)
  __shared__ float wT[64 * 64];   // [k][h]
  int tid = threadIdx.x;
  int n0 = blockIdx.x * 64;
  for (int i = 0; i < 16; ++i) {
    int idx = tid + i * 256;
    int a = idx >> 6, k = idx & 63;
    xT[k * 68 + a] = (n0 + a < N) ? x[(n0 + a) * 64 + k] : 0.f;
    wT[k * 64 + a] = W_el[a * 128 + k];
  }
  __syncthreads();
  int h = tid & 63, ng = tid >> 6;
  int nb = ng * 16;
  float acc[16];
#pragma unroll
  for (int j = 0; j < 16; ++j) acc[j] = 0.f;
  for (int k = 0; k < 64; ++k) {
    float w = wT[k * 64 + h];
    const float4* row = (const float4*)&xT[k * 68 + nb];
#pragma unroll
    for (int j = 0; j < 4; ++j) {
      float4 v = row[j];
      acc[j * 4 + 0] += w * v.x;
      acc[j * 4 + 1] += w * v.y;
      acc[j * 4 + 2] += w * v.z;
      acc[j * 4 + 3] += w * v.w;
    }
  }
#pragma unroll
  for (int j = 0; j < 16; ++j) {
    int node = n0 + nb + j;
    if (node < N) y[node * 64 + h] = acc[j];
  }
}

// one wave per edge (grid-stride): msg = relu(y[row] + dist*p + q); atomicMax into agg[col]
__global__ __launch_bounds__(256) void k_edge(const int* __restrict__ eidx,
                                              const float* __restrict__ dist,
                                              const float* __restrict__ y,
                                              const float* __restrict__ p,
                                              const float* __restrict__ q,
                                              float* __restrict__ agg, int E) {
  int lane = threadIdx.x & 63;
  int wid = (blockIdx.x * 256 + threadIdx.x) >> 6;
  int nw = (gridDim.x * 256) >> 6;
  float pv = p[lane], qv = q[lane];
  for (int e = wid; e < E; e += nw) {
    int r = eidx[e];
    int c = eidx[E + e];
    float d = dist[e];
    float m = fmaxf(y[r * 64 + lane] + d * pv + qv, 0.f);
    atomicMax((int*)agg + c * 64 + lane, __float_as_int(m));  // m >= 0: int order == float order
  }
}

// node MLP: h1 = relu(W1a@agg + W1b@x + cgr[batch]); x += W2@h1 + b_n2
// block: 32 nodes, 256 threads, two stages via LDS
__global__ __launch_bounds__(256) void k_node(const float* __restrict__ agg,
                                              float* __restrict__ x,
                                              const int* __restrict__ batch,
                                              const float* __restrict__ cgr,
                                              const float* __restrict__ Wt1,
                                              const float* __restrict__ Wn2t,
                                              const float* __restrict__ b_n2, int N) {
  __shared__ float inT[128 * 36];  // [k][n], 144B rows (16B aligned)
  __shared__ float h1T[256 * 40];  // [o][n], 160B rows (16B aligned)
  __shared__ int sb[32];
  int tid = threadIdx.x;
  int n0 = blockIdx.x * 32;
  for (int i = 0; i < 8; ++i) {
    int idx = tid + i * 256;       // 0..2047
    int a = idx >> 6, k = idx & 63;
    int node = n0 + a;
    float av = (node < N) ? agg[node * 64 + k] : 0.f;
    float xv = (node < N) ? x[node * 64 + k] : 0.f;
    inT[k * 36 + a] = av;
    inT[(64 + k) * 36 + a] = xv;
  }
  if (tid < 32) sb[tid] = (n0 + tid < N) ? batch[n0 + tid] : 0;
  __syncthreads();
  // stage 1: each thread owns output o = tid, 32 node accumulators
  {
    int o = tid;
    float acc[32];
#pragma unroll
    for (int n = 0; n < 32; ++n) acc[n] = cgr[sb[n] * 256 + o];
    for (int k = 0; k < 128; ++k) {
      float w = Wt1[k * 256 + o];
      const float4* row = (const float4*)&inT[k * 36];
#pragma unroll
      for (int j = 0; j < 8; ++j) {
        float4 v = row[j];
        acc[j * 4 + 0] += w * v.x;
        acc[j * 4 + 1] += w * v.y;
        acc[j * 4 + 2] += w * v.z;
        acc[j * 4 + 3] += w * v.w;
      }
    }
    float4* hrow = (float4*)&h1T[o * 40];
#pragma unroll
    for (int j = 0; j < 8; ++j) {
      float4 v;
      v.x = fmaxf(acc[j * 4 + 0], 0.f);
      v.y = fmaxf(acc[j * 4 + 1], 0.f);
      v.z = fmaxf(acc[j * 4 + 2], 0.f);
      v.w = fmaxf(acc[j * 4 + 3], 0.f);
      hrow[j] = v;
    }
  }
  __syncthreads();
  // stage 2: dx[n][h] = sum_o h1[n][o] * W_n2[h][o]
  {
    int h = tid & 63, ng = tid >> 6;
    float acc2[8];
#pragma unroll
    for (int j = 0; j < 8; ++j) acc2[j] = 0.f;
    for (int o = 0; o < 256; ++o) {
      float w = Wn2t[o * 64 + h];
      const float4* hr = (const float4*)&h1T[o * 40 + ng * 8];
      float4 a = hr[0], b = hr[1];
      acc2[0] += w * a.x; acc2[1] += w * a.y; acc2[2] += w * a.z; acc2[3] += w * a.w;
      acc2[4] += w * b.x; acc2[5] += w * b.y; acc2[6] += w * b.z; acc2[7] += w * b.w;
    }
    float bn = b_n2[h];
#pragma unroll
    for (int j = 0; j < 8; ++j) {
      int node = n0 + ng * 8 + j;
      if (node < N) x[node * 64 + h] += acc2[j] + bn;
    }
  }
}

__device__ __forceinline__ unsigned enc_ordered(float f) {
  unsigned u = __float_as_uint(f);
  return (u >> 31) ? ~u : (u | 0x80000000u);
}

// per-graph max of x (batch sorted -> sequential scan with flush-on-change)
__global__ __launch_bounds__(256) void k_xu(const float* __restrict__ x,
                                            const int* __restrict__ batch,
                                            unsigned* __restrict__ xu_enc, int N) {
  int lane = threadIdx.x & 63;
  int gg = blockIdx.x * 4 + (threadIdx.x >> 6);
  int nstart = gg * 64;
  if (nstart >= N) return;
  int nend = min(nstart + 64, N);
  int cur = batch[nstart];
  float m = -__builtin_huge_valf();
  for (int n = nstart; n < nend; ++n) {
    int b = batch[n];
    if (b != cur) {
      atomicMax(&xu_enc[cur * 64 + lane], enc_ordered(m));
      cur = b;
      m = -__builtin_huge_valf();
    }
    m = fmaxf(m, x[n * 64 + lane]);
  }
  atomicMax(&xu_enc[cur * 64 + lane], enc_ordered(m));
}

// per-graph: u update, LSTM cell, cgr for next layer, reset xu_enc. one wave per graph.
__global__ __launch_bounds__(64) void k_graph(unsigned* __restrict__ xu_enc,
                                              float* __restrict__ u,
                                              float* __restrict__ cgr,
                                              const float* __restrict__ W_gl,
                                              const float* __restrict__ b_gl,
                                              const float* __restrict__ W_ih,
                                              const float* __restrict__ b_ih,
                                              const float* __restrict__ b_hh,
                                              const float* __restrict__ W_n1,
                                              const float* __restrict__ b_n1,
                                              float* __restrict__ c_out) {
  __shared__ float xu_s[64], us[64], un[64], u2[64];
  int g = blockIdx.x, h = threadIdx.x;
  unsigned Ev = xu_enc[g * 64 + h];
  float f = (Ev & 0x80000000u) ? __uint_as_float(Ev & 0x7FFFFFFFu) : __uint_as_float(~Ev);
  if (!isfinite(f)) f = 0.f;  // empty segment -> 0
  xu_s[h] = f;
  float uo = u[g * 64 + h];
  us[h] = uo;
  __syncthreads();
  float pre = b_gl[h];
  for (int k = 0; k < 64; ++k) pre += xu_s[k] * W_gl[h * 128 + k];
  for (int k = 0; k < 64; ++k) pre += us[k] * W_gl[h * 128 + 64 + k];
  float unew = uo + fmaxf(pre, 0.f);
  un[h] = unew;
  __syncthreads();
  float gi = b_ih[h] + b_hh[h];
  float gg = b_ih[128 + h] + b_hh[128 + h];
  float go = b_ih[192 + h] + b_hh[192 + h];
  for (int k = 0; k < 64; ++k) {
    float uv = un[k];
    gi += uv * W_ih[h * 64 + k];
    gg += uv * W_ih[(128 + h) * 64 + k];
    go += uv * W_ih[(192 + h) * 64 + k];
  }
  float cc = (1.f / (1.f + expf(-gi))) * tanhf(gg);
  float u2v = (1.f / (1.f + expf(-go))) * tanhf(cc);
  c_out[g * 64 + h] = cc;
  u[g * 64 + h] = u2v;
  u2[h] = u2v;
  __syncthreads();
  for (int j = 0; j < 4; ++j) {
    int o = j * 64 + h;
    float acc = b_n1[o];
    for (int k = 0; k < 64; ++k) acc += W_n1[o * 192 + 128 + k] * u2[k];
    cgr[g * 256 + o] = acc;
  }
  xu_enc[g * 64 + h] = 0x007FFFFFu;  // reset for next layer / next call
}

// outs: two 64-dot products per node, wave-reduce
__global__ __launch_bounds__(256) void k_out(const float* __restrict__ x,
                                             const float* __restrict__ Wo0,
                                             const float* __restrict__ bo0,
                                             const float* __restrict__ Wo1,
                                             const float* __restrict__ bo1,
                                             float* __restrict__ out, int N) {
  int lane = threadIdx.x & 63;
  int n = blockIdx.x * 4 + (threadIdx.x >> 6);
  if (n >= N) return;
  float xv = x[n * 64 + lane];
  float s0 = xv * Wo0[lane];
  float s1 = xv * Wo1[lane];
  for (int off = 32; off > 0; off >>= 1) {
    s0 += __shfl_down(s0, off);
    s1 += __shfl_down(s1, off);
  }
  if (lane == 0) {
    out[n] = s0 + bo0[0];
    out[N + n] = s1 + bo1[0];
  }
}

extern "C" void kernel_launch(void* const* d_in, const int* in_sizes, int n_in,
                              void* d_out, int out_size, void* d_ws, size_t ws_size,
                              hipStream_t stream) {
  const float* v0 = (const float*)d_in[0];
  const float* v1 = (const float*)d_in[1];
  const float* dist = (const float*)d_in[2];
  const int* eidx = (const int*)d_in[3];
  const int* batch = (const int*)d_in[4];
  // d_in[5] = batch_size (device scalar); B = 64 fixed by problem
  const float* wte = (const float*)d_in[6];
  const float* Wi0 = (const float*)d_in[7];
  const float* bi0 = (const float*)d_in[8];
  const float* Wi1 = (const float*)d_in[9];
  const float* bi1 = (const float*)d_in[10];
  const float* Wo0 = (const float*)d_in[11];
  const float* bo0 = (const float*)d_in[12];
  const float* Wo1 = (const float*)d_in[13];
  const float* bo1 = (const float*)d_in[14];
  const float* W_edge = (const float*)d_in[15];
  const float* b_edge = (const float*)d_in[16];
  const float* W_el = (const float*)d_in[17];
  const float* b_el = (const float*)d_in[18];
  const float* W_n1 = (const float*)d_in[19];
  const float* b_n1 = (const float*)d_in[20];
  const float* W_n2 = (const float*)d_in[21];
  const float* b_n2 = (const float*)d_in[22];
  const float* W_gl = (const float*)d_in[23];
  const float* b_gl = (const float*)d_in[24];
  const float* W_ih = (const float*)d_in[25];
  // d_in[26] = W_hh (unused: h_prev = 0)
  const float* b_ih = (const float*)d_in[27];
  const float* b_hh = (const float*)d_in[28];

  const int N = in_sizes[0];
  const int E = in_sizes[2];
  const int NH = N * 64;

  float* ws = (float*)d_ws;
  float* x = ws;
  float* y = ws + NH;
  float* agg = ws + 2 * NH;
  float* u = ws + 3 * NH;
  unsigned* xu_enc = (unsigned*)(ws + 3 * NH + 4096);
  float* cgr = ws + 3 * NH + 8192;
  float* p = cgr + 16384;
  float* q = p + 64;
  float* Wt1 = q + 64;
  float* Wn2t = Wt1 + 32768;

  float* outp = (float*)d_out;

  k_xinit<<<(NH + 255) / 256, 256, 0, stream>>>(v0, v1, wte, Wi0, bi0, Wi1, bi1, x, N);
  k_prep_pq<<<1, 64, 0, stream>>>(W_el, b_el, W_edge, b_edge, p, q);
  k_prep_misc<<<288, 256, 0, stream>>>(u, xu_enc, cgr, Wt1, Wn2t, b_n1, W_n1, W_n2);

  for (int l = 0; l < 4; ++l) {
    k_ygemm<<<(N + 63) / 64, 256, 0, stream>>>(x, W_el, y, N);
    hipMemsetAsync(agg, 0, (size_t)NH * sizeof(float), stream);
    k_edge<<<2048, 256, 0, stream>>>(eidx, dist, y, p, q, agg, E);
    k_node<<<(N + 31) / 32, 256, 0, stream>>>(agg, x, batch, cgr, Wt1, Wn2t, b_n2, N);
    k_xu<<<(N + 255) / 256, 256, 0, stream>>>(x, batch, xu_enc, N);
    k_graph<<<64, 64, 0, stream>>>(xu_enc, u, cgr, W_gl, b_gl, W_ih, b_ih, b_hh,
                                   W_n1, b_n1, outp + 2 * N + l * 4096);
  }
  k_out<<<(N + 3) / 4, 256, 0, stream>>>(x, Wo0, bo0, Wo1, bo1, outp, N);
}

// Round 2
// 687.794 us; speedup vs baseline: 1.5718x; 1.5718x over previous
//
#include <hip/hip_runtime.h>

// GraphTemporal: N=50000, E=500000, B=64, H=64, L=4 shared layers.
// Node MLP + global-feature append + fused next-layer y-GEMM in bf16 MFMA.
// Edge MLP algebraically reduced: msg = relu(y[row] + dist*p + q),
//   y = x @ W_el[:, :64].T ; p = W_el[:,64:]@W_edge ; q = W_el[:,64:]@b_edge + b_el
// scatter-max via atomicMax on float bits (msg >= 0).
// Node MLP input = [agg | x | u[batch]] (K=192) so bias is just b_n1 (no cgr).

typedef __attribute__((ext_vector_type(8))) short short8;
typedef __attribute__((ext_vector_type(4))) float f32x4;

__device__ __forceinline__ unsigned short f2bf(float f) {
  union { float f; unsigned u; } v; v.f = f;
  unsigned r = v.u + 0x7FFFu + ((v.u >> 16) & 1u);
  return (unsigned short)(r >> 16);
}

__global__ void k_xinit(const float* __restrict__ v0, const float* __restrict__ v1,
                        const float* __restrict__ wte,
                        const float* __restrict__ Wi0, const float* __restrict__ bi0,
                        const float* __restrict__ Wi1, const float* __restrict__ bi1,
                        float* __restrict__ x, int N) {
  int idx = blockIdx.x * 256 + threadIdx.x;
  if (idx >= N * 64) return;
  int n = idx >> 6, h = idx & 63;
  x[idx] = wte[h] + wte[64 + h] + bi0[h] + bi1[h] + v0[n] * Wi0[h] + v1[n] * Wi1[h];
}

__global__ void k_prep_pq(const float* __restrict__ W_el, const float* __restrict__ b_el,
                          const float* __restrict__ W_edge, const float* __restrict__ b_edge,
                          float* __restrict__ p, float* __restrict__ q) {
  int h = threadIdx.x;  // 64 threads
  float pp = 0.f, qq = 0.f;
  for (int k = 0; k < 64; ++k) {
    float w = W_el[h * 128 + 64 + k];
    pp += w * W_edge[k];
    qq += w * b_edge[k];
  }
  p[h] = pp;
  q[h] = qq + b_el[h];
}

// u=0, xu_enc=enc(-inf), bf16 weight conversion
__global__ void k_prep2(float* __restrict__ u, unsigned* __restrict__ xu_enc,
                        unsigned short* __restrict__ W1b, unsigned short* __restrict__ W2b,
                        unsigned short* __restrict__ Welb,
                        const float* __restrict__ W_n1, const float* __restrict__ W_n2,
                        const float* __restrict__ W_el) {
  int gt = blockIdx.x * 256 + threadIdx.x;
  if (gt < 4096) {
    u[gt] = 0.f;
  } else if (gt < 8192) {
    xu_enc[gt - 4096] = 0x007FFFFFu;  // enc(-inf)
  } else if (gt < 8192 + 49152) {
    int i = gt - 8192;                 // W_n1 [256][192] row-major -> direct
    W1b[i] = f2bf(W_n1[i]);
  } else if (gt < 8192 + 49152 + 16384) {
    int i = gt - 57344;                // W_n2 [64][256] row-major -> direct
    W2b[i] = f2bf(W_n2[i]);
  } else if (gt < 8192 + 49152 + 16384 + 4096) {
    int i = gt - 73728;                // W_el[:, :64] compacted to stride 64
    Welb[i] = f2bf(W_el[(i >> 6) * 128 + (i & 63)]);
  }
}

// y = x @ W_el[:, :64].T  (fp32, layer-0 only)
__global__ __launch_bounds__(256) void k_ygemm(const float* __restrict__ x,
                                               const float* __restrict__ W_el,
                                               float* __restrict__ y, int N) {
  __shared__ float xT[64 * 68];
  __shared__ float wT[64 * 64];
  int tid = threadIdx.x;
  int n0 = blockIdx.x * 64;
  for (int i = 0; i < 16; ++i) {
    int idx = tid + i * 256;
    int a = idx >> 6, k = idx & 63;
    xT[k * 68 + a] = (n0 + a < N) ? x[(n0 + a) * 64 + k] : 0.f;
    wT[k * 64 + a] = W_el[a * 128 + k];
  }
  __syncthreads();
  int h = tid & 63, ng = tid >> 6;
  int nb = ng * 16;
  float acc[16];
#pragma unroll
  for (int j = 0; j < 16; ++j) acc[j] = 0.f;
  for (int k = 0; k < 64; ++k) {
    float w = wT[k * 64 + h];
    const float4* row = (const float4*)&xT[k * 68 + nb];
#pragma unroll
    for (int j = 0; j < 4; ++j) {
      float4 v = row[j];
      acc[j * 4 + 0] += w * v.x;
      acc[j * 4 + 1] += w * v.y;
      acc[j * 4 + 2] += w * v.z;
      acc[j * 4 + 3] += w * v.w;
    }
  }
#pragma unroll
  for (int j = 0; j < 16; ++j) {
    int node = n0 + nb + j;
    if (node < N) y[node * 64 + h] = acc[j];
  }
}

// msg = relu(y[row] + dist*p + q); atomicMax into agg[col]
__global__ __launch_bounds__(256) void k_edge(const int* __restrict__ eidx,
                                              const float* __restrict__ dist,
                                              const float* __restrict__ y,
                                              const float* __restrict__ p,
                                              const float* __restrict__ q,
                                              float* __restrict__ agg, int E) {
  int lane = threadIdx.x & 63;
  int wid = (blockIdx.x * 256 + threadIdx.x) >> 6;
  int nw = (gridDim.x * 256) >> 6;
  float pv = p[lane], qv = q[lane];
  for (int e = wid; e < E; e += nw) {
    int r = eidx[e];
    int c = eidx[E + e];
    float d = dist[e];
    float m = fmaxf(y[r * 64 + lane] + d * pv + qv, 0.f);
    atomicMax((int*)agg + c * 64 + lane, __float_as_int(m));  // m >= 0
  }
}

// Node MLP (MFMA): in=[agg|x|u[batch]] K=192 -> h1=relu(.+b_n1) (O=256)
//                  x += h1 @ W_n2.T + b_n2 ; y_next = x_new @ Welb.T
// 32 nodes/block, 4 waves. D = W * X^T so D col=node, row=output.
__global__ __launch_bounds__(256) void k_node(
    const float* __restrict__ agg, float* __restrict__ x, float* __restrict__ y,
    const int* __restrict__ batch, const float* __restrict__ u,
    const unsigned short* __restrict__ W1b, const unsigned short* __restrict__ W2b,
    const unsigned short* __restrict__ Welb,
    const float* __restrict__ b_n1, const float* __restrict__ b_n2,
    int N, int want_y) {
  __shared__ __align__(16) char inb[32 * 384];  // [32][192] bf16 (xnb aliases)
  __shared__ __align__(16) char h1T[32 * 512];  // [32][256] bf16
  int t = threadIdx.x;
  int n0 = blockIdx.x * 32;

  // ---- stage inputs as bf16, XOR-swizzled ----
  const float4* agg4 = (const float4*)agg;
  const float4* x4 = (const float4*)x;
  const float4* u4 = (const float4*)u;
#pragma unroll
  for (int i = 0; i < 2; ++i) {
    int idx = i * 256 + t;
    int nd = idx >> 4, kq = idx & 15;
    int node = n0 + nd;
    float4 av, xv, uv;
    if (node < N) {
      av = agg4[node * 16 + kq];
      xv = x4[node * 16 + kq];
      uv = u4[batch[node] * 16 + kq];
    } else {
      av = make_float4(0.f, 0.f, 0.f, 0.f); xv = av; uv = av;
    }
    int swz = (nd & 7) << 4;
    char* row = inb + nd * 384;
    {
      unsigned lo = f2bf(av.x) | ((unsigned)f2bf(av.y) << 16);
      unsigned hi = f2bf(av.z) | ((unsigned)f2bf(av.w) << 16);
      *(uint2*)(row + (((kq * 8) + 0) ^ swz)) = make_uint2(lo, hi);
    }
    {
      unsigned lo = f2bf(xv.x) | ((unsigned)f2bf(xv.y) << 16);
      unsigned hi = f2bf(xv.z) | ((unsigned)f2bf(xv.w) << 16);
      *(uint2*)(row + (((kq * 8) + 128) ^ swz)) = make_uint2(lo, hi);
    }
    {
      unsigned lo = f2bf(uv.x) | ((unsigned)f2bf(uv.y) << 16);
      unsigned hi = f2bf(uv.z) | ((unsigned)f2bf(uv.w) << 16);
      *(uint2*)(row + (((kq * 8) + 256) ^ swz)) = make_uint2(lo, hi);
    }
  }
  __syncthreads();

  int l = t & 63, w = t >> 6;
  int lr = l & 15;              // tile row/col lane index
  int lk8 = (l >> 4) << 3;      // k offset: 0,8,16,24
  int jo = (l >> 4) << 2;       // output offset: 0,4,8,12
  int swzr = (lr & 7) << 4;     // same for lr and 16+lr

  // ---- stage 1: h1 = relu(W1 @ in^T + b_n1), O=256 (wave owns 64 o), K=192 ----
  f32x4 acc[4][2];
#pragma unroll
  for (int ot = 0; ot < 4; ++ot)
#pragma unroll
    for (int nt = 0; nt < 2; ++nt) acc[ot][nt] = (f32x4){0.f, 0.f, 0.f, 0.f};
  const unsigned short* W1p = W1b + (w * 64 + lr) * 192 + lk8;
#pragma unroll
  for (int ks = 0; ks < 6; ++ks) {
    int kb = ks * 64 + lk8 * 2;
    short8 b0 = *(const short8*)(inb + lr * 384 + (kb ^ swzr));
    short8 b1 = *(const short8*)(inb + (16 + lr) * 384 + (kb ^ swzr));
#pragma unroll
    for (int ot = 0; ot < 4; ++ot) {
      short8 a = *(const short8*)(W1p + ot * (16 * 192) + ks * 32);
      acc[ot][0] = __builtin_amdgcn_mfma_f32_16x16x32_bf16(a, b0, acc[ot][0], 0, 0, 0);
      acc[ot][1] = __builtin_amdgcn_mfma_f32_16x16x32_bf16(a, b1, acc[ot][1], 0, 0, 0);
    }
  }
#pragma unroll
  for (int ot = 0; ot < 4; ++ot) {
    int o = w * 64 + ot * 16 + jo;
    float4 bs = *(const float4*)(b_n1 + o);
#pragma unroll
    for (int nt = 0; nt < 2; ++nt) {
      int nd = nt * 16 + lr;
      unsigned lo = (unsigned)f2bf(fmaxf(acc[ot][nt][0] + bs.x, 0.f)) |
                    ((unsigned)f2bf(fmaxf(acc[ot][nt][1] + bs.y, 0.f)) << 16);
      unsigned hi = (unsigned)f2bf(fmaxf(acc[ot][nt][2] + bs.z, 0.f)) |
                    ((unsigned)f2bf(fmaxf(acc[ot][nt][3] + bs.w, 0.f)) << 16);
      *(uint2*)(h1T + nd * 512 + ((o * 2) ^ ((nd & 7) << 4))) = make_uint2(lo, hi);
    }
  }
  __syncthreads();

  // ---- stage 2: x += W2 @ h1^T + b_n2, O=64 (wave owns 16 h), K=256 ----
  f32x4 acc2[2] = {{0.f, 0.f, 0.f, 0.f}, {0.f, 0.f, 0.f, 0.f}};
  const unsigned short* W2p = W2b + (w * 16 + lr) * 256 + lk8;
#pragma unroll
  for (int ks = 0; ks < 8; ++ks) {
    short8 a = *(const short8*)(W2p + ks * 32);
    int kb = ks * 64 + lk8 * 2;
    short8 b0 = *(const short8*)(h1T + lr * 512 + (kb ^ swzr));
    short8 b1 = *(const short8*)(h1T + (16 + lr) * 512 + (kb ^ swzr));
    acc2[0] = __builtin_amdgcn_mfma_f32_16x16x32_bf16(a, b0, acc2[0], 0, 0, 0);
    acc2[1] = __builtin_amdgcn_mfma_f32_16x16x32_bf16(a, b1, acc2[1], 0, 0, 0);
  }
  int h0 = w * 16 + jo;
  float4 b2 = *(const float4*)(b_n2 + h0);
  char* xnb = inb;  // alias (inb fully consumed)
#pragma unroll
  for (int nt = 0; nt < 2; ++nt) {
    int nd = nt * 16 + lr;
    int node = n0 + nd;
    float4 xn = make_float4(0.f, 0.f, 0.f, 0.f);
    if (node < N) {
      float4 xo = *(const float4*)(x + node * 64 + h0);
      xn.x = xo.x + acc2[nt][0] + b2.x;
      xn.y = xo.y + acc2[nt][1] + b2.y;
      xn.z = xo.z + acc2[nt][2] + b2.z;
      xn.w = xo.w + acc2[nt][3] + b2.w;
      *(float4*)(x + node * 64 + h0) = xn;
    }
    unsigned lo = (unsigned)f2bf(xn.x) | ((unsigned)f2bf(xn.y) << 16);
    unsigned hi = (unsigned)f2bf(xn.z) | ((unsigned)f2bf(xn.w) << 16);
    *(uint2*)(xnb + nd * 128 + ((h0 * 2) ^ ((nd & 7) << 4))) = make_uint2(lo, hi);
  }
  __syncthreads();

  // ---- stage 3: y_next = Welb @ x_new^T, O=64, K=64 ----
  if (want_y) {
    f32x4 acc3[2] = {{0.f, 0.f, 0.f, 0.f}, {0.f, 0.f, 0.f, 0.f}};
    const unsigned short* W3p = Welb + (w * 16 + lr) * 64 + lk8;
#pragma unroll
    for (int ks = 0; ks < 2; ++ks) {
      short8 a = *(const short8*)(W3p + ks * 32);
      int kb = ks * 64 + lk8 * 2;
      short8 b0 = *(const short8*)(xnb + lr * 128 + (kb ^ swzr));
      short8 b1 = *(const short8*)(xnb + (16 + lr) * 128 + (kb ^ swzr));
      acc3[0] = __builtin_amdgcn_mfma_f32_16x16x32_bf16(a, b0, acc3[0], 0, 0, 0);
      acc3[1] = __builtin_amdgcn_mfma_f32_16x16x32_bf16(a, b1, acc3[1], 0, 0, 0);
    }
    int o0 = w * 16 + jo;
#pragma unroll
    for (int nt = 0; nt < 2; ++nt) {
      int node = n0 + nt * 16 + lr;
      if (node < N) {
        float4 yv;
        yv.x = acc3[nt][0]; yv.y = acc3[nt][1];
        yv.z = acc3[nt][2]; yv.w = acc3[nt][3];
        *(float4*)(y + node * 64 + o0) = yv;
      }
    }
  }
}

__device__ __forceinline__ unsigned enc_ordered(float f) {
  unsigned u = __float_as_uint(f);
  return (u >> 31) ? ~u : (u | 0x80000000u);
}

// per-graph max of x (batch sorted)
__global__ __launch_bounds__(256) void k_xu(const float* __restrict__ x,
                                            const int* __restrict__ batch,
                                            unsigned* __restrict__ xu_enc, int N) {
  int lane = threadIdx.x & 63;
  int gg = blockIdx.x * 4 + (threadIdx.x >> 6);
  int nstart = gg * 64;
  if (nstart >= N) return;
  int nend = min(nstart + 64, N);
  int cur = batch[nstart];
  float m = -__builtin_huge_valf();
  for (int n = nstart; n < nend; ++n) {
    int b = batch[n];
    if (b != cur) {
      atomicMax(&xu_enc[cur * 64 + lane], enc_ordered(m));
      cur = b;
      m = -__builtin_huge_valf();
    }
    m = fmaxf(m, x[n * 64 + lane]);
  }
  atomicMax(&xu_enc[cur * 64 + lane], enc_ordered(m));
}

// per-graph: u update, LSTM, reset xu_enc
__global__ __launch_bounds__(64) void k_graph(unsigned* __restrict__ xu_enc,
                                              float* __restrict__ u,
                                              const float* __restrict__ W_gl,
                                              const float* __restrict__ b_gl,
                                              const float* __restrict__ W_ih,
                                              const float* __restrict__ b_ih,
                                              const float* __restrict__ b_hh,
                                              float* __restrict__ c_out) {
  __shared__ float xu_s[64], us[64], un[64];
  int g = blockIdx.x, h = threadIdx.x;
  unsigned Ev = xu_enc[g * 64 + h];
  float f = (Ev & 0x80000000u) ? __uint_as_float(Ev & 0x7FFFFFFFu) : __uint_as_float(~Ev);
  if (!isfinite(f)) f = 0.f;
  xu_s[h] = f;
  float uo = u[g * 64 + h];
  us[h] = uo;
  __syncthreads();
  float pre = b_gl[h];
  for (int k = 0; k < 64; ++k) pre += xu_s[k] * W_gl[h * 128 + k];
  for (int k = 0; k < 64; ++k) pre += us[k] * W_gl[h * 128 + 64 + k];
  float unew = uo + fmaxf(pre, 0.f);
  un[h] = unew;
  __syncthreads();
  float gi = b_ih[h] + b_hh[h];
  float gg = b_ih[128 + h] + b_hh[128 + h];
  float go = b_ih[192 + h] + b_hh[192 + h];
  for (int k = 0; k < 64; ++k) {
    float uv = un[k];
    gi += uv * W_ih[h * 64 + k];
    gg += uv * W_ih[(128 + h) * 64 + k];
    go += uv * W_ih[(192 + h) * 64 + k];
  }
  float cc = (1.f / (1.f + expf(-gi))) * tanhf(gg);
  float u2v = (1.f / (1.f + expf(-go))) * tanhf(cc);
  c_out[g * 64 + h] = cc;
  u[g * 64 + h] = u2v;
  xu_enc[g * 64 + h] = 0x007FFFFFu;  // reset for next layer / next call
}

__global__ __launch_bounds__(256) void k_out(const float* __restrict__ x,
                                             const float* __restrict__ Wo0,
                                             const float* __restrict__ bo0,
                                             const float* __restrict__ Wo1,
                                             const float* __restrict__ bo1,
                                             float* __restrict__ out, int N) {
  int lane = threadIdx.x & 63;
  int n = blockIdx.x * 4 + (threadIdx.x >> 6);
  if (n >= N) return;
  float xv = x[n * 64 + lane];
  float s0 = xv * Wo0[lane];
  float s1 = xv * Wo1[lane];
  for (int off = 32; off > 0; off >>= 1) {
    s0 += __shfl_down(s0, off);
    s1 += __shfl_down(s1, off);
  }
  if (lane == 0) {
    out[n] = s0 + bo0[0];
    out[N + n] = s1 + bo1[0];
  }
}

extern "C" void kernel_launch(void* const* d_in, const int* in_sizes, int n_in,
                              void* d_out, int out_size, void* d_ws, size_t ws_size,
                              hipStream_t stream) {
  const float* v0 = (const float*)d_in[0];
  const float* v1 = (const float*)d_in[1];
  const float* dist = (const float*)d_in[2];
  const int* eidx = (const int*)d_in[3];
  const int* batch = (const int*)d_in[4];
  const float* wte = (const float*)d_in[6];
  const float* Wi0 = (const float*)d_in[7];
  const float* bi0 = (const float*)d_in[8];
  const float* Wi1 = (const float*)d_in[9];
  const float* bi1 = (const float*)d_in[10];
  const float* Wo0 = (const float*)d_in[11];
  const float* bo0 = (const float*)d_in[12];
  const float* Wo1 = (const float*)d_in[13];
  const float* bo1 = (const float*)d_in[14];
  const float* W_edge = (const float*)d_in[15];
  const float* b_edge = (const float*)d_in[16];
  const float* W_el = (const float*)d_in[17];
  const float* b_el = (const float*)d_in[18];
  const float* W_n1 = (const float*)d_in[19];
  const float* b_n1 = (const float*)d_in[20];
  const float* W_n2 = (const float*)d_in[21];
  const float* b_n2 = (const float*)d_in[22];
  const float* W_gl = (const float*)d_in[23];
  const float* b_gl = (const float*)d_in[24];
  const float* W_ih = (const float*)d_in[25];
  const float* b_ih = (const float*)d_in[27];
  const float* b_hh = (const float*)d_in[28];

  const int N = in_sizes[0];
  const int E = in_sizes[2];
  const int NH = N * 64;

  float* ws = (float*)d_ws;
  float* x = ws;
  float* y = ws + NH;
  float* agg = ws + 2 * NH;
  float* u = ws + 3 * NH;
  unsigned* xu_enc = (unsigned*)(ws + 3 * NH + 4096);
  float* p = ws + 3 * NH + 8192;
  float* q = p + 64;
  unsigned short* W1b = (unsigned short*)(q + 64);
  unsigned short* W2b = W1b + 49152;
  unsigned short* Welb = W2b + 16384;

  float* outp = (float*)d_out;

  k_xinit<<<(NH + 255) / 256, 256, 0, stream>>>(v0, v1, wte, Wi0, bi0, Wi1, bi1, x, N);
  k_prep_pq<<<1, 64, 0, stream>>>(W_el, b_el, W_edge, b_edge, p, q);
  k_prep2<<<304, 256, 0, stream>>>(u, xu_enc, W1b, W2b, Welb, W_n1, W_n2, W_el);
  k_ygemm<<<(N + 63) / 64, 256, 0, stream>>>(x, W_el, y, N);

  for (int l = 0; l < 4; ++l) {
    hipMemsetAsync(agg, 0, (size_t)NH * sizeof(float), stream);
    k_edge<<<2048, 256, 0, stream>>>(eidx, dist, y, p, q, agg, E);
    k_node<<<(N + 31) / 32, 256, 0, stream>>>(agg, x, y, batch, u, W1b, W2b, Welb,
                                              b_n1, b_n2, N, (l < 3) ? 1 : 0);
    k_xu<<<(N + 255) / 256, 256, 0, stream>>>(x, batch, xu_enc, N);
    k_graph<<<64, 64, 0, stream>>>(xu_enc, u, W_gl, b_gl, W_ih, b_ih, b_hh,
                                   outp + 2 * N + l * 4096);
  }
  k_out<<<(N + 3) / 4, 256, 0, stream>>>(x, Wo0, bo0, Wo1, bo1, outp, N);
}

// Round 3
// 514.099 us; speedup vs baseline: 2.1029x; 1.3379x over previous
//
#include <hip/hip_runtime.h>

// GraphTemporal: N=50000, E=500000, B=64, H=64, L=4 shared layers.
// Edge MLP algebraically reduced: msg = relu(y[row] + dist*p + q),
//   y = x @ W_el[:, :64].T ; p = W_el[:,64:]@W_edge ; q = W_el[:,64:]@b_edge + b_el
// Edges CSR-sorted by destination once per call -> aggregation has NO atomics.
// y/agg stored bf16. Node MLP + fused next-layer y-GEMM in bf16 MFMA.
// Node MLP input = [agg | x | u[batch]] (K=192), bias = b_n1.

typedef __attribute__((ext_vector_type(8))) short short8;
typedef __attribute__((ext_vector_type(4))) float f32x4;

__device__ __forceinline__ unsigned short f2bf(float f) {
  union { float f; unsigned u; } v; v.f = f;
  unsigned r = v.u + 0x7FFFu + ((v.u >> 16) & 1u);
  return (unsigned short)(r >> 16);
}
__device__ __forceinline__ float bf2f(unsigned short s) {
  return __uint_as_float((unsigned)s << 16);
}

// p,q (edge affine), c0..c2 (closed-form layer-0 y): 64 threads
__global__ void k_prep_pq(const float* __restrict__ W_el, const float* __restrict__ b_el,
                          const float* __restrict__ W_edge, const float* __restrict__ b_edge,
                          const float* __restrict__ wte,
                          const float* __restrict__ Wi0, const float* __restrict__ bi0,
                          const float* __restrict__ Wi1, const float* __restrict__ bi1,
                          float* __restrict__ p, float* __restrict__ q,
                          float* __restrict__ c0, float* __restrict__ c1,
                          float* __restrict__ c2) {
  int h = threadIdx.x;
  float pp = 0.f, qq = 0.f, s0 = 0.f, s1 = 0.f, s2 = 0.f;
  for (int k = 0; k < 64; ++k) {
    float w2 = W_el[h * 128 + 64 + k];
    pp += w2 * W_edge[k];
    qq += w2 * b_edge[k];
    float w1 = W_el[h * 128 + k];
    float base = wte[k] + wte[64 + k] + bi0[k] + bi1[k];
    s0 += w1 * base;
    s1 += w1 * Wi0[k];
    s2 += w1 * Wi1[k];
  }
  p[h] = pp; q[h] = qq + b_el[h];
  c0[h] = s0; c1[h] = s1; c2[h] = s2;
}

// u=0, xu_enc=enc(-inf), bf16 weight conversion
__global__ void k_prep2(float* __restrict__ u, unsigned* __restrict__ xu_enc,
                        unsigned short* __restrict__ W1b, unsigned short* __restrict__ W2b,
                        unsigned short* __restrict__ Welb,
                        const float* __restrict__ W_n1, const float* __restrict__ W_n2,
                        const float* __restrict__ W_el) {
  int gt = blockIdx.x * 256 + threadIdx.x;
  if (gt < 4096) {
    u[gt] = 0.f;
  } else if (gt < 8192) {
    xu_enc[gt - 4096] = 0x007FFFFFu;  // enc(-inf)
  } else if (gt < 8192 + 49152) {
    int i = gt - 8192;                 // W_n1 [256][192]
    W1b[i] = f2bf(W_n1[i]);
  } else if (gt < 8192 + 49152 + 16384) {
    int i = gt - 57344;                // W_n2 [64][256]
    W2b[i] = f2bf(W_n2[i]);
  } else if (gt < 8192 + 49152 + 16384 + 4096) {
    int i = gt - 73728;                // W_el[:, :64] compact stride 64
    Welb[i] = f2bf(W_el[(i >> 6) * 128 + (i & 63)]);
  }
}

// x init + closed-form y0 (bf16)
__global__ void k_xinit(const float* __restrict__ v0, const float* __restrict__ v1,
                        const float* __restrict__ wte,
                        const float* __restrict__ Wi0, const float* __restrict__ bi0,
                        const float* __restrict__ Wi1, const float* __restrict__ bi1,
                        const float* __restrict__ c0, const float* __restrict__ c1,
                        const float* __restrict__ c2,
                        float* __restrict__ x, unsigned short* __restrict__ y_bf, int N) {
  int idx = blockIdx.x * 256 + threadIdx.x;
  if (idx >= N * 64) return;
  int n = idx >> 6, h = idx & 63;
  float a = v0[n], b = v1[n];
  x[idx] = wte[h] + wte[64 + h] + bi0[h] + bi1[h] + a * Wi0[h] + b * Wi1[h];
  y_bf[idx] = f2bf(c0[h] + a * c1[h] + b * c2[h]);
}

// ---- CSR build (once per call) ----
__global__ __launch_bounds__(256) void k_hist(const int* __restrict__ eidx,
                                              int* __restrict__ deg, int E) {
  int e = blockIdx.x * 256 + threadIdx.x;
  if (e < E) atomicAdd(&deg[eidx[E + e]], 1);
}

// per-512-chunk inclusive scan
__global__ __launch_bounds__(256) void k_scan1(const int* __restrict__ deg,
                                               int* __restrict__ off,
                                               int* __restrict__ bsum, int N) {
  __shared__ int s[256];
  int b = blockIdx.x, t = threadIdx.x;
  int i0 = b * 512 + t * 2;
  int v0 = (i0 < N) ? deg[i0] : 0;
  int v1 = (i0 + 1 < N) ? deg[i0 + 1] : 0;
  int sum = v0 + v1;
  s[t] = sum;
  __syncthreads();
  for (int d = 1; d < 256; d <<= 1) {
    int val = (t >= d) ? s[t - d] : 0;
    __syncthreads();
    s[t] += val;
    __syncthreads();
  }
  int excl = s[t] - sum;
  if (i0 < N) off[i0] = excl + v0;
  if (i0 + 1 < N) off[i0 + 1] = excl + v0 + v1;
  if (t == 255) bsum[b] = s[t];
}

// exclusive scan of block sums (nb <= 128)
__global__ void k_scan2(int* __restrict__ bsum, int nb) {
  __shared__ int s[128];
  int t = threadIdx.x;
  int v = (t < nb) ? bsum[t] : 0;
  s[t] = v;
  __syncthreads();
  for (int d = 1; d < 128; d <<= 1) {
    int val = (t >= d) ? s[t - d] : 0;
    __syncthreads();
    s[t] += val;
    __syncthreads();
  }
  if (t < nb) bsum[t] = s[t] - v;
}

__global__ __launch_bounds__(256) void k_scan3(int* __restrict__ off,
                                               const int* __restrict__ bsum, int N) {
  int i = blockIdx.x * 256 + threadIdx.x;
  if (i < N) off[i] += bsum[i >> 9];
}

__global__ __launch_bounds__(256) void k_scatter(const int* __restrict__ eidx,
                                                 const float* __restrict__ dist,
                                                 const int* __restrict__ off,
                                                 int* __restrict__ cur,
                                                 uint2* __restrict__ spack, int E) {
  int e = blockIdx.x * 256 + threadIdx.x;
  if (e >= E) return;
  int c = eidx[E + e];
  int base = (c == 0) ? 0 : off[c - 1];
  int pos = base + atomicAdd(&cur[c], 1);
  spack[pos] = make_uint2((unsigned)eidx[e], __float_as_uint(dist[e]));
}

// ---- per-layer: CSR aggregation, no atomics; agg out bf16 ----
__global__ __launch_bounds__(256) void k_edge2(const int* __restrict__ off,
                                               const uint2* __restrict__ spack,
                                               const unsigned short* __restrict__ y_bf,
                                               const float* __restrict__ p,
                                               const float* __restrict__ q,
                                               unsigned short* __restrict__ agg_bf, int N) {
  int lane = threadIdx.x & 63;
  int c = blockIdx.x * 4 + (threadIdx.x >> 6);
  if (c >= N) return;
  int s = (c == 0) ? 0 : off[c - 1];
  int eend = off[c];
  float pv = p[lane], qv = q[lane];
  float m = 0.f;  // relu >= 0, empty segment -> 0
  if (s < eend) {
    uint2 rd = spack[s];
    for (int e = s; e < eend; ++e) {
      uint2 crd = rd;
      if (e + 1 < eend) rd = spack[e + 1];
      float yv = bf2f(y_bf[(size_t)crd.x * 64 + lane]);
      m = fmaxf(m, fmaf(__uint_as_float(crd.y), pv, yv + qv));
    }
  }
  agg_bf[(size_t)c * 64 + lane] = f2bf(m);
}

// Node MLP (MFMA): in=[agg|x|u[batch]] K=192 -> h1=relu(.+b_n1) (O=256)
//                  x += h1 @ W_n2.T + b_n2 ; y_next = Welb @ x_new^T (bf16)
__global__ __launch_bounds__(256) void k_node(
    const unsigned short* __restrict__ agg_bf, float* __restrict__ x,
    unsigned short* __restrict__ y_bf,
    const int* __restrict__ batch, const float* __restrict__ u,
    const unsigned short* __restrict__ W1b, const unsigned short* __restrict__ W2b,
    const unsigned short* __restrict__ Welb,
    const float* __restrict__ b_n1, const float* __restrict__ b_n2,
    int N, int want_y) {
  __shared__ __align__(16) char inb[32 * 384];  // [32][192] bf16 (xnb aliases)
  __shared__ __align__(16) char h1T[32 * 512];  // [32][256] bf16
  int t = threadIdx.x;
  int n0 = blockIdx.x * 32;

  // ---- stage inputs bf16, XOR-swizzled: [agg | x | u[batch]] ----
  {
    int nd = t >> 3, ko = t & 7;  // 32 nodes x 8 16B-chunks
    int node = n0 + nd;
    int swz = (nd & 7) << 4;
    char* row = inb + nd * 384;
    uint4 av = make_uint4(0, 0, 0, 0);
    float4 xa = make_float4(0.f, 0.f, 0.f, 0.f), xb = xa, ua = xa, ub = xa;
    if (node < N) {
      av = *(const uint4*)(agg_bf + (size_t)node * 64 + ko * 8);
      const float4* x4 = (const float4*)x;
      xa = x4[node * 16 + ko * 2];
      xb = x4[node * 16 + ko * 2 + 1];
      int g = batch[node];
      const float4* u4 = (const float4*)u;
      ua = u4[g * 16 + ko * 2];
      ub = u4[g * 16 + ko * 2 + 1];
    }
    *(uint4*)(row + ((ko * 16) ^ swz)) = av;
    uint4 xv, uv;
    xv.x = f2bf(xa.x) | ((unsigned)f2bf(xa.y) << 16);
    xv.y = f2bf(xa.z) | ((unsigned)f2bf(xa.w) << 16);
    xv.z = f2bf(xb.x) | ((unsigned)f2bf(xb.y) << 16);
    xv.w = f2bf(xb.z) | ((unsigned)f2bf(xb.w) << 16);
    *(uint4*)(row + ((128 + ko * 16) ^ swz)) = xv;
    uv.x = f2bf(ua.x) | ((unsigned)f2bf(ua.y) << 16);
    uv.y = f2bf(ua.z) | ((unsigned)f2bf(ua.w) << 16);
    uv.z = f2bf(ub.x) | ((unsigned)f2bf(ub.y) << 16);
    uv.w = f2bf(ub.z) | ((unsigned)f2bf(ub.w) << 16);
    *(uint4*)(row + ((256 + ko * 16) ^ swz)) = uv;
  }
  __syncthreads();

  int l = t & 63, w = t >> 6;
  int lr = l & 15;
  int lk8 = (l >> 4) << 3;
  int jo = (l >> 4) << 2;
  int swzr = (lr & 7) << 4;

  // ---- stage 1: h1 = relu(W1 @ in^T + b_n1) ----
  f32x4 acc[4][2];
#pragma unroll
  for (int ot = 0; ot < 4; ++ot)
#pragma unroll
    for (int nt = 0; nt < 2; ++nt) acc[ot][nt] = (f32x4){0.f, 0.f, 0.f, 0.f};
  const unsigned short* W1p = W1b + (w * 64 + lr) * 192 + lk8;
#pragma unroll
  for (int ks = 0; ks < 6; ++ks) {
    int kb = ks * 64 + lk8 * 2;
    short8 b0 = *(const short8*)(inb + lr * 384 + (kb ^ swzr));
    short8 b1 = *(const short8*)(inb + (16 + lr) * 384 + (kb ^ swzr));
#pragma unroll
    for (int ot = 0; ot < 4; ++ot) {
      short8 a = *(const short8*)(W1p + ot * (16 * 192) + ks * 32);
      acc[ot][0] = __builtin_amdgcn_mfma_f32_16x16x32_bf16(a, b0, acc[ot][0], 0, 0, 0);
      acc[ot][1] = __builtin_amdgcn_mfma_f32_16x16x32_bf16(a, b1, acc[ot][1], 0, 0, 0);
    }
  }
#pragma unroll
  for (int ot = 0; ot < 4; ++ot) {
    int o = w * 64 + ot * 16 + jo;
    float4 bs = *(const float4*)(b_n1 + o);
#pragma unroll
    for (int nt = 0; nt < 2; ++nt) {
      int nd = nt * 16 + lr;
      unsigned lo = (unsigned)f2bf(fmaxf(acc[ot][nt][0] + bs.x, 0.f)) |
                    ((unsigned)f2bf(fmaxf(acc[ot][nt][1] + bs.y, 0.f)) << 16);
      unsigned hi = (unsigned)f2bf(fmaxf(acc[ot][nt][2] + bs.z, 0.f)) |
                    ((unsigned)f2bf(fmaxf(acc[ot][nt][3] + bs.w, 0.f)) << 16);
      *(uint2*)(h1T + nd * 512 + ((o * 2) ^ ((nd & 7) << 4))) = make_uint2(lo, hi);
    }
  }
  __syncthreads();

  // ---- stage 2: x += W2 @ h1^T + b_n2 ----
  f32x4 acc2[2] = {{0.f, 0.f, 0.f, 0.f}, {0.f, 0.f, 0.f, 0.f}};
  const unsigned short* W2p = W2b + (w * 16 + lr) * 256 + lk8;
#pragma unroll
  for (int ks = 0; ks < 8; ++ks) {
    short8 a = *(const short8*)(W2p + ks * 32);
    int kb = ks * 64 + lk8 * 2;
    short8 b0 = *(const short8*)(h1T + lr * 512 + (kb ^ swzr));
    short8 b1 = *(const short8*)(h1T + (16 + lr) * 512 + (kb ^ swzr));
    acc2[0] = __builtin_amdgcn_mfma_f32_16x16x32_bf16(a, b0, acc2[0], 0, 0, 0);
    acc2[1] = __builtin_amdgcn_mfma_f32_16x16x32_bf16(a, b1, acc2[1], 0, 0, 0);
  }
  int h0 = w * 16 + jo;
  float4 b2 = *(const float4*)(b_n2 + h0);
  char* xnb = inb;  // alias
#pragma unroll
  for (int nt = 0; nt < 2; ++nt) {
    int nd = nt * 16 + lr;
    int node = n0 + nd;
    float4 xn = make_float4(0.f, 0.f, 0.f, 0.f);
    if (node < N) {
      float4 xo = *(const float4*)(x + (size_t)node * 64 + h0);
      xn.x = xo.x + acc2[nt][0] + b2.x;
      xn.y = xo.y + acc2[nt][1] + b2.y;
      xn.z = xo.z + acc2[nt][2] + b2.z;
      xn.w = xo.w + acc2[nt][3] + b2.w;
      *(float4*)(x + (size_t)node * 64 + h0) = xn;
    }
    unsigned lo = (unsigned)f2bf(xn.x) | ((unsigned)f2bf(xn.y) << 16);
    unsigned hi = (unsigned)f2bf(xn.z) | ((unsigned)f2bf(xn.w) << 16);
    *(uint2*)(xnb + nd * 128 + ((h0 * 2) ^ ((nd & 7) << 4))) = make_uint2(lo, hi);
  }
  __syncthreads();

  // ---- stage 3: y_next = Welb @ x_new^T (bf16 out) ----
  if (want_y) {
    f32x4 acc3[2] = {{0.f, 0.f, 0.f, 0.f}, {0.f, 0.f, 0.f, 0.f}};
    const unsigned short* W3p = Welb + (w * 16 + lr) * 64 + lk8;
#pragma unroll
    for (int ks = 0; ks < 2; ++ks) {
      short8 a = *(const short8*)(W3p + ks * 32);
      int kb = ks * 64 + lk8 * 2;
      short8 b0 = *(const short8*)(xnb + lr * 128 + (kb ^ swzr));
      short8 b1 = *(const short8*)(xnb + (16 + lr) * 128 + (kb ^ swzr));
      acc3[0] = __builtin_amdgcn_mfma_f32_16x16x32_bf16(a, b0, acc3[0], 0, 0, 0);
      acc3[1] = __builtin_amdgcn_mfma_f32_16x16x32_bf16(a, b1, acc3[1], 0, 0, 0);
    }
    int o0 = w * 16 + jo;
#pragma unroll
    for (int nt = 0; nt < 2; ++nt) {
      int node = n0 + nt * 16 + lr;
      if (node < N) {
        unsigned lo = (unsigned)f2bf(acc3[nt][0]) | ((unsigned)f2bf(acc3[nt][1]) << 16);
        unsigned hi = (unsigned)f2bf(acc3[nt][2]) | ((unsigned)f2bf(acc3[nt][3]) << 16);
        *(uint2*)(y_bf + (size_t)node * 64 + o0) = make_uint2(lo, hi);
      }
    }
  }
}

__device__ __forceinline__ unsigned enc_ordered(float f) {
  unsigned u = __float_as_uint(f);
  return (u >> 31) ? ~u : (u | 0x80000000u);
}

// per-graph max of x (batch sorted)
__global__ __launch_bounds__(256) void k_xu(const float* __restrict__ x,
                                            const int* __restrict__ batch,
                                            unsigned* __restrict__ xu_enc, int N) {
  int lane = threadIdx.x & 63;
  int gg = blockIdx.x * 4 + (threadIdx.x >> 6);
  int nstart = gg * 64;
  if (nstart >= N) return;
  int nend = min(nstart + 64, N);
  int cur = batch[nstart];
  float m = -__builtin_huge_valf();
  for (int n = nstart; n < nend; ++n) {
    int b = batch[n];
    if (b != cur) {
      atomicMax(&xu_enc[cur * 64 + lane], enc_ordered(m));
      cur = b;
      m = -__builtin_huge_valf();
    }
    m = fmaxf(m, x[(size_t)n * 64 + lane]);
  }
  atomicMax(&xu_enc[cur * 64 + lane], enc_ordered(m));
}

// per-graph: u update, LSTM, reset xu_enc
__global__ __launch_bounds__(64) void k_graph(unsigned* __restrict__ xu_enc,
                                              float* __restrict__ u,
                                              const float* __restrict__ W_gl,
                                              const float* __restrict__ b_gl,
                                              const float* __restrict__ W_ih,
                                              const float* __restrict__ b_ih,
                                              const float* __restrict__ b_hh,
                                              float* __restrict__ c_out) {
  __shared__ float xu_s[64], us[64], un[64];
  int g = blockIdx.x, h = threadIdx.x;
  unsigned Ev = xu_enc[g * 64 + h];
  float f = (Ev & 0x80000000u) ? __uint_as_float(Ev & 0x7FFFFFFFu) : __uint_as_float(~Ev);
  if (!isfinite(f)) f = 0.f;
  xu_s[h] = f;
  float uo = u[g * 64 + h];
  us[h] = uo;
  __syncthreads();
  float pre = b_gl[h];
  for (int k = 0; k < 64; ++k) pre += xu_s[k] * W_gl[h * 128 + k];
  for (int k = 0; k < 64; ++k) pre += us[k] * W_gl[h * 128 + 64 + k];
  float unew = uo + fmaxf(pre, 0.f);
  un[h] = unew;
  __syncthreads();
  float gi = b_ih[h] + b_hh[h];
  float gg = b_ih[128 + h] + b_hh[128 + h];
  float go = b_ih[192 + h] + b_hh[192 + h];
  for (int k = 0; k < 64; ++k) {
    float uv = un[k];
    gi += uv * W_ih[h * 64 + k];
    gg += uv * W_ih[(128 + h) * 64 + k];
    go += uv * W_ih[(192 + h) * 64 + k];
  }
  float cc = (1.f / (1.f + expf(-gi))) * tanhf(gg);
  float u2v = (1.f / (1.f + expf(-go))) * tanhf(cc);
  c_out[g * 64 + h] = cc;
  u[g * 64 + h] = u2v;
  xu_enc[g * 64 + h] = 0x007FFFFFu;  // reset for next layer / next call
}

__global__ __launch_bounds__(256) void k_out(const float* __restrict__ x,
                                             const float* __restrict__ Wo0,
                                             const float* __restrict__ bo0,
                                             const float* __restrict__ Wo1,
                                             const float* __restrict__ bo1,
                                             float* __restrict__ out, int N) {
  int lane = threadIdx.x & 63;
  int n = blockIdx.x * 4 + (threadIdx.x >> 6);
  if (n >= N) return;
  float xv = x[(size_t)n * 64 + lane];
  float s0 = xv * Wo0[lane];
  float s1 = xv * Wo1[lane];
  for (int off = 32; off > 0; off >>= 1) {
    s0 += __shfl_down(s0, off);
    s1 += __shfl_down(s1, off);
  }
  if (lane == 0) {
    out[n] = s0 + bo0[0];
    out[N + n] = s1 + bo1[0];
  }
}

extern "C" void kernel_launch(void* const* d_in, const int* in_sizes, int n_in,
                              void* d_out, int out_size, void* d_ws, size_t ws_size,
                              hipStream_t stream) {
  const float* v0 = (const float*)d_in[0];
  const float* v1 = (const float*)d_in[1];
  const float* dist = (const float*)d_in[2];
  const int* eidx = (const int*)d_in[3];
  const int* batch = (const int*)d_in[4];
  const float* wte = (const float*)d_in[6];
  const float* Wi0 = (const float*)d_in[7];
  const float* bi0 = (const float*)d_in[8];
  const float* Wi1 = (const float*)d_in[9];
  const float* bi1 = (const float*)d_in[10];
  const float* Wo0 = (const float*)d_in[11];
  const float* bo0 = (const float*)d_in[12];
  const float* Wo1 = (const float*)d_in[13];
  const float* bo1 = (const float*)d_in[14];
  const float* W_edge = (const float*)d_in[15];
  const float* b_edge = (const float*)d_in[16];
  const float* W_el = (const float*)d_in[17];
  const float* b_el = (const float*)d_in[18];
  const float* W_n1 = (const float*)d_in[19];
  const float* b_n1 = (const float*)d_in[20];
  const float* W_n2 = (const float*)d_in[21];
  const float* b_n2 = (const float*)d_in[22];
  const float* W_gl = (const float*)d_in[23];
  const float* b_gl = (const float*)d_in[24];
  const float* W_ih = (const float*)d_in[25];
  const float* b_ih = (const float*)d_in[27];
  const float* b_hh = (const float*)d_in[28];

  const int N = in_sizes[0];
  const int E = in_sizes[2];
  const int NH = N * 64;
  const int NB512 = (N + 511) / 512;

  float* ws = (float*)d_ws;
  float* x = ws;                                   // NH
  float* u = x + NH;                               // 4096
  unsigned* xu_enc = (unsigned*)(u + 4096);        // 4096
  float* p = (float*)(xu_enc + 4096);
  float* q = p + 64;
  float* c0 = q + 64;
  float* c1 = c0 + 64;
  float* c2 = c1 + 64;
  unsigned short* W1b = (unsigned short*)(c2 + 64);  // 49152
  unsigned short* W2b = W1b + 49152;                 // 16384
  unsigned short* Welb = W2b + 16384;                // 4096
  unsigned short* y_bf = Welb + 4096;                // NH
  unsigned short* agg_bf = y_bf + NH;                // NH
  int* deg = (int*)(agg_bf + NH);                    // N
  int* off = deg + N;                                // N
  int* cur = off + N;                                // N
  int* bsum = cur + N;                               // 128
  uint2* spack = (uint2*)(bsum + 128);               // E

  float* outp = (float*)d_out;

  hipMemsetAsync(deg, 0, (size_t)N * sizeof(int), stream);
  hipMemsetAsync(cur, 0, (size_t)N * sizeof(int), stream);

  k_prep_pq<<<1, 64, 0, stream>>>(W_el, b_el, W_edge, b_edge, wte, Wi0, bi0, Wi1, bi1,
                                  p, q, c0, c1, c2);
  k_prep2<<<304, 256, 0, stream>>>(u, xu_enc, W1b, W2b, Welb, W_n1, W_n2, W_el);
  k_xinit<<<(NH + 255) / 256, 256, 0, stream>>>(v0, v1, wte, Wi0, bi0, Wi1, bi1,
                                                c0, c1, c2, x, y_bf, N);
  k_hist<<<(E + 255) / 256, 256, 0, stream>>>(eidx, deg, E);
  k_scan1<<<NB512, 256, 0, stream>>>(deg, off, bsum, N);
  k_scan2<<<1, 128, 0, stream>>>(bsum, NB512);
  k_scan3<<<(N + 255) / 256, 256, 0, stream>>>(off, bsum, N);
  k_scatter<<<(E + 255) / 256, 256, 0, stream>>>(eidx, dist, off, cur, spack, E);

  for (int l = 0; l < 4; ++l) {
    k_edge2<<<(N + 3) / 4, 256, 0, stream>>>(off, spack, y_bf, p, q, agg_bf, N);
    k_node<<<(N + 31) / 32, 256, 0, stream>>>(agg_bf, x, y_bf, batch, u, W1b, W2b, Welb,
                                              b_n1, b_n2, N, (l < 3) ? 1 : 0);
    k_xu<<<(N + 255) / 256, 256, 0, stream>>>(x, batch, xu_enc, N);
    k_graph<<<64, 64, 0, stream>>>(xu_enc, u, W_gl, b_gl, W_ih, b_ih, b_hh,
                                   outp + 2 * N + l * 4096);
  }
  k_out<<<(N + 3) / 4, 256, 0, stream>>>(x, Wo0, bo0, Wo1, bo1, outp, N);
}

// Round 4
// 483.842 us; speedup vs baseline: 2.2344x; 1.0625x over previous
//
#include <hip/hip_runtime.h>

// GraphTemporal: N=50000, E=500000, B=64, H=64, L=4 shared layers.
// Edge MLP algebraically reduced: msg = relu(y[row] + dist*p + q),
//   y = x @ W_el[:, :64].T ; p = W_el[:,64:]@W_edge ; q = W_el[:,64:]@b_edge + b_el
// Edges CSR-sorted by destination once per call -> aggregation has NO atomics.
// y/agg stored bf16. Node MLP + fused next-layer y-GEMM in bf16 MFMA.
// Per-graph max (xu) fused into k_node epilogue (wave shfl reduce + atomicMax).
// Output projection fused into last-layer k_node.

typedef __attribute__((ext_vector_type(8))) short short8;
typedef __attribute__((ext_vector_type(4))) float f32x4;

__device__ __forceinline__ unsigned short f2bf(float f) {
  union { float f; unsigned u; } v; v.f = f;
  unsigned r = v.u + 0x7FFFu + ((v.u >> 16) & 1u);
  return (unsigned short)(r >> 16);
}
__device__ __forceinline__ float bf2f(unsigned short s) {
  return __uint_as_float((unsigned)s << 16);
}
__device__ __forceinline__ unsigned enc_ordered(float f) {
  unsigned u = __float_as_uint(f);
  return (u >> 31) ? ~u : (u | 0x80000000u);
}

// p,q (edge affine), c0..c2 (closed-form layer-0 y): 64 threads
__global__ void k_prep_pq(const float* __restrict__ W_el, const float* __restrict__ b_el,
                          const float* __restrict__ W_edge, const float* __restrict__ b_edge,
                          const float* __restrict__ wte,
                          const float* __restrict__ Wi0, const float* __restrict__ bi0,
                          const float* __restrict__ Wi1, const float* __restrict__ bi1,
                          float* __restrict__ p, float* __restrict__ q,
                          float* __restrict__ c0, float* __restrict__ c1,
                          float* __restrict__ c2) {
  int h = threadIdx.x;
  float pp = 0.f, qq = 0.f, s0 = 0.f, s1 = 0.f, s2 = 0.f;
  for (int k = 0; k < 64; ++k) {
    float w2 = W_el[h * 128 + 64 + k];
    pp += w2 * W_edge[k];
    qq += w2 * b_edge[k];
    float w1 = W_el[h * 128 + k];
    float base = wte[k] + wte[64 + k] + bi0[k] + bi1[k];
    s0 += w1 * base;
    s1 += w1 * Wi0[k];
    s2 += w1 * Wi1[k];
  }
  p[h] = pp; q[h] = qq + b_el[h];
  c0[h] = s0; c1[h] = s1; c2[h] = s2;
}

// u=0, xu_enc=enc(-inf), bf16 weights, zero deg/cur
__global__ void k_prep2(float* __restrict__ u, unsigned* __restrict__ xu_enc,
                        unsigned short* __restrict__ W1b, unsigned short* __restrict__ W2b,
                        unsigned short* __restrict__ Welb,
                        const float* __restrict__ W_n1, const float* __restrict__ W_n2,
                        const float* __restrict__ W_el,
                        int* __restrict__ deg, int* __restrict__ cur, int N) {
  int gt = blockIdx.x * 256 + threadIdx.x;
  if (gt < 4096) {
    u[gt] = 0.f;
  } else if (gt < 8192) {
    xu_enc[gt - 4096] = 0x007FFFFFu;  // enc(-inf)
  } else if (gt < 8192 + 49152) {
    int i = gt - 8192;                 // W_n1 [256][192]
    W1b[i] = f2bf(W_n1[i]);
  } else if (gt < 8192 + 49152 + 16384) {
    int i = gt - 57344;                // W_n2 [64][256]
    W2b[i] = f2bf(W_n2[i]);
  } else if (gt < 77824) {
    int i = gt - 73728;                // W_el[:, :64] compact stride 64
    Welb[i] = f2bf(W_el[(i >> 6) * 128 + (i & 63)]);
  } else if (gt < 77824 + N) {
    deg[gt - 77824] = 0;
  } else if (gt < 77824 + 2 * N) {
    cur[gt - 77824 - N] = 0;
  }
}

// x init + closed-form y0 (bf16)
__global__ void k_xinit(const float* __restrict__ v0, const float* __restrict__ v1,
                        const float* __restrict__ wte,
                        const float* __restrict__ Wi0, const float* __restrict__ bi0,
                        const float* __restrict__ Wi1, const float* __restrict__ bi1,
                        const float* __restrict__ c0, const float* __restrict__ c1,
                        const float* __restrict__ c2,
                        float* __restrict__ x, unsigned short* __restrict__ y_bf, int N) {
  int idx = blockIdx.x * 256 + threadIdx.x;
  if (idx >= N * 64) return;
  int n = idx >> 6, h = idx & 63;
  float a = v0[n], b = v1[n];
  x[idx] = wte[h] + wte[64 + h] + bi0[h] + bi1[h] + a * Wi0[h] + b * Wi1[h];
  y_bf[idx] = f2bf(c0[h] + a * c1[h] + b * c2[h]);
}

// ---- CSR build (once per call) ----
__global__ __launch_bounds__(256) void k_hist(const int* __restrict__ eidx,
                                              int* __restrict__ deg, int E) {
  int e = blockIdx.x * 256 + threadIdx.x;
  if (e < E) atomicAdd(&deg[eidx[E + e]], 1);
}

__global__ __launch_bounds__(256) void k_scan1(const int* __restrict__ deg,
                                               int* __restrict__ off,
                                               int* __restrict__ bsum, int N) {
  __shared__ int s[256];
  int b = blockIdx.x, t = threadIdx.x;
  int i0 = b * 512 + t * 2;
  int v0 = (i0 < N) ? deg[i0] : 0;
  int v1 = (i0 + 1 < N) ? deg[i0 + 1] : 0;
  int sum = v0 + v1;
  s[t] = sum;
  __syncthreads();
  for (int d = 1; d < 256; d <<= 1) {
    int val = (t >= d) ? s[t - d] : 0;
    __syncthreads();
    s[t] += val;
    __syncthreads();
  }
  int excl = s[t] - sum;
  if (i0 < N) off[i0] = excl + v0;
  if (i0 + 1 < N) off[i0 + 1] = excl + v0 + v1;
  if (t == 255) bsum[b] = s[t];
}

__global__ void k_scan2(int* __restrict__ bsum, int nb) {
  __shared__ int s[128];
  int t = threadIdx.x;
  int v = (t < nb) ? bsum[t] : 0;
  s[t] = v;
  __syncthreads();
  for (int d = 1; d < 128; d <<= 1) {
    int val = (t >= d) ? s[t - d] : 0;
    __syncthreads();
    s[t] += val;
    __syncthreads();
  }
  if (t < nb) bsum[t] = s[t] - v;
}

__global__ __launch_bounds__(256) void k_scan3(int* __restrict__ off,
                                               const int* __restrict__ bsum, int N) {
  int i = blockIdx.x * 256 + threadIdx.x;
  if (i < N) off[i] += bsum[i >> 9];
}

__global__ __launch_bounds__(256) void k_scatter(const int* __restrict__ eidx,
                                                 const float* __restrict__ dist,
                                                 const int* __restrict__ off,
                                                 int* __restrict__ cur,
                                                 uint2* __restrict__ spack, int E) {
  int e = blockIdx.x * 256 + threadIdx.x;
  if (e >= E) return;
  int c = eidx[E + e];
  int base = (c == 0) ? 0 : off[c - 1];
  int pos = base + atomicAdd(&cur[c], 1);
  spack[pos] = make_uint2((unsigned)eidx[e], __float_as_uint(dist[e]));
}

// ---- per-layer: CSR aggregation, unroll-2, no atomics; agg out bf16 ----
__global__ __launch_bounds__(256) void k_edge2(const int* __restrict__ off,
                                               const uint2* __restrict__ spack,
                                               const unsigned short* __restrict__ y_bf,
                                               const float* __restrict__ p,
                                               const float* __restrict__ q,
                                               unsigned short* __restrict__ agg_bf, int N) {
  int lane = threadIdx.x & 63;
  int c = blockIdx.x * 4 + (threadIdx.x >> 6);
  if (c >= N) return;
  int s = (c == 0) ? 0 : off[c - 1];
  int eend = off[c];
  float pv = p[lane], qv = q[lane];
  float m0 = 0.f, m1 = 0.f;  // relu >= 0, empty segment -> 0
  int e = s;
  for (; e + 2 <= eend; e += 2) {
    uint2 a = spack[e];
    uint2 b = spack[e + 1];
    float ya = bf2f(y_bf[(size_t)a.x * 64 + lane]);
    float yb = bf2f(y_bf[(size_t)b.x * 64 + lane]);
    m0 = fmaxf(m0, fmaf(__uint_as_float(a.y), pv, ya + qv));
    m1 = fmaxf(m1, fmaf(__uint_as_float(b.y), pv, yb + qv));
  }
  if (e < eend) {
    uint2 a = spack[e];
    float ya = bf2f(y_bf[(size_t)a.x * 64 + lane]);
    m0 = fmaxf(m0, fmaf(__uint_as_float(a.y), pv, ya + qv));
  }
  agg_bf[(size_t)c * 64 + lane] = f2bf(fmaxf(m0, m1));
}

// Node MLP (MFMA): in=[agg|x|u[batch]] K=192 -> h1=relu(.+b_n1) (O=256)
//   x += h1 @ W_n2.T + b_n2
//   mode 1: y_next = Welb @ x_new^T (bf16);  mode 2 (last): fused out-proj, no x store
//   always: xu_enc atomicMax(enc(x_new)) with wave-level pre-reduce
__global__ __launch_bounds__(256) void k_node(
    const unsigned short* __restrict__ agg_bf, float* __restrict__ x,
    unsigned short* __restrict__ y_bf,
    const int* __restrict__ batch, const float* __restrict__ u,
    const unsigned short* __restrict__ W1b, const unsigned short* __restrict__ W2b,
    const unsigned short* __restrict__ Welb,
    const float* __restrict__ b_n1, const float* __restrict__ b_n2,
    unsigned* __restrict__ xu_enc,
    const float* __restrict__ Wo0, const float* __restrict__ bo0,
    const float* __restrict__ Wo1, const float* __restrict__ bo1,
    float* __restrict__ outp,
    int N, int mode) {
  __shared__ __align__(16) char inb[32 * 384];  // [32][192] bf16 (xnb aliases)
  __shared__ __align__(16) char h1T[32 * 512];  // [32][256] bf16 (ow aliases)
  __shared__ int sgb[32];
  int t = threadIdx.x;
  int n0 = blockIdx.x * 32;

  // ---- stage inputs bf16, XOR-swizzled: [agg | x | u[batch]] ----
  {
    int nd = t >> 3, ko = t & 7;  // 32 nodes x 8 16B-chunks
    int node = n0 + nd;
    int swz = (nd & 7) << 4;
    char* row = inb + nd * 384;
    uint4 av = make_uint4(0, 0, 0, 0);
    float4 xa = make_float4(0.f, 0.f, 0.f, 0.f), xb = xa, ua = xa, ub = xa;
    if (node < N) {
      av = *(const uint4*)(agg_bf + (size_t)node * 64 + ko * 8);
      const float4* x4 = (const float4*)x;
      xa = x4[node * 16 + ko * 2];
      xb = x4[node * 16 + ko * 2 + 1];
      int g = batch[node];
      const float4* u4 = (const float4*)u;
      ua = u4[g * 16 + ko * 2];
      ub = u4[g * 16 + ko * 2 + 1];
    }
    if (t < 32) sgb[t] = batch[min(n0 + t, N - 1)];
    *(uint4*)(row + ((ko * 16) ^ swz)) = av;
    uint4 xv, uv;
    xv.x = f2bf(xa.x) | ((unsigned)f2bf(xa.y) << 16);
    xv.y = f2bf(xa.z) | ((unsigned)f2bf(xa.w) << 16);
    xv.z = f2bf(xb.x) | ((unsigned)f2bf(xb.y) << 16);
    xv.w = f2bf(xb.z) | ((unsigned)f2bf(xb.w) << 16);
    *(uint4*)(row + ((128 + ko * 16) ^ swz)) = xv;
    uv.x = f2bf(ua.x) | ((unsigned)f2bf(ua.y) << 16);
    uv.y = f2bf(ua.z) | ((unsigned)f2bf(ua.w) << 16);
    uv.z = f2bf(ub.x) | ((unsigned)f2bf(ub.y) << 16);
    uv.w = f2bf(ub.z) | ((unsigned)f2bf(ub.w) << 16);
    *(uint4*)(row + ((256 + ko * 16) ^ swz)) = uv;
  }
  __syncthreads();

  int l = t & 63, w = t >> 6;
  int lr = l & 15;
  int lk8 = (l >> 4) << 3;
  int jo = (l >> 4) << 2;
  int swzr = (lr & 7) << 4;

  // ---- stage 1: h1 = relu(W1 @ in^T + b_n1) ----
  f32x4 acc[4][2];
#pragma unroll
  for (int ot = 0; ot < 4; ++ot)
#pragma unroll
    for (int nt = 0; nt < 2; ++nt) acc[ot][nt] = (f32x4){0.f, 0.f, 0.f, 0.f};
  const unsigned short* W1p = W1b + (w * 64 + lr) * 192 + lk8;
#pragma unroll
  for (int ks = 0; ks < 6; ++ks) {
    int kb = ks * 64 + lk8 * 2;
    short8 b0 = *(const short8*)(inb + lr * 384 + (kb ^ swzr));
    short8 b1 = *(const short8*)(inb + (16 + lr) * 384 + (kb ^ swzr));
#pragma unroll
    for (int ot = 0; ot < 4; ++ot) {
      short8 a = *(const short8*)(W1p + ot * (16 * 192) + ks * 32);
      acc[ot][0] = __builtin_amdgcn_mfma_f32_16x16x32_bf16(a, b0, acc[ot][0], 0, 0, 0);
      acc[ot][1] = __builtin_amdgcn_mfma_f32_16x16x32_bf16(a, b1, acc[ot][1], 0, 0, 0);
    }
  }
#pragma unroll
  for (int ot = 0; ot < 4; ++ot) {
    int o = w * 64 + ot * 16 + jo;
    float4 bs = *(const float4*)(b_n1 + o);
#pragma unroll
    for (int nt = 0; nt < 2; ++nt) {
      int nd = nt * 16 + lr;
      unsigned lo = (unsigned)f2bf(fmaxf(acc[ot][nt][0] + bs.x, 0.f)) |
                    ((unsigned)f2bf(fmaxf(acc[ot][nt][1] + bs.y, 0.f)) << 16);
      unsigned hi = (unsigned)f2bf(fmaxf(acc[ot][nt][2] + bs.z, 0.f)) |
                    ((unsigned)f2bf(fmaxf(acc[ot][nt][3] + bs.w, 0.f)) << 16);
      *(uint2*)(h1T + nd * 512 + ((o * 2) ^ ((nd & 7) << 4))) = make_uint2(lo, hi);
    }
  }
  __syncthreads();

  // ---- stage 2: x_new = x + W2 @ h1^T + b_n2 ----
  f32x4 acc2[2] = {{0.f, 0.f, 0.f, 0.f}, {0.f, 0.f, 0.f, 0.f}};
  const unsigned short* W2p = W2b + (w * 16 + lr) * 256 + lk8;
#pragma unroll
  for (int ks = 0; ks < 8; ++ks) {
    short8 a = *(const short8*)(W2p + ks * 32);
    int kb = ks * 64 + lk8 * 2;
    short8 b0 = *(const short8*)(h1T + lr * 512 + (kb ^ swzr));
    short8 b1 = *(const short8*)(h1T + (16 + lr) * 512 + (kb ^ swzr));
    acc2[0] = __builtin_amdgcn_mfma_f32_16x16x32_bf16(a, b0, acc2[0], 0, 0, 0);
    acc2[1] = __builtin_amdgcn_mfma_f32_16x16x32_bf16(a, b1, acc2[1], 0, 0, 0);
  }
  int h0 = w * 16 + jo;
  float4 b2 = *(const float4*)(b_n2 + h0);
  char* xnb = inb;  // alias
  float4 xn[2];
#pragma unroll
  for (int nt = 0; nt < 2; ++nt) {
    int nd = nt * 16 + lr;
    int node = n0 + nd;
    xn[nt] = make_float4(0.f, 0.f, 0.f, 0.f);
    if (node < N) {
      float4 xo = *(const float4*)(x + (size_t)node * 64 + h0);
      xn[nt].x = xo.x + acc2[nt][0] + b2.x;
      xn[nt].y = xo.y + acc2[nt][1] + b2.y;
      xn[nt].z = xo.z + acc2[nt][2] + b2.z;
      xn[nt].w = xo.w + acc2[nt][3] + b2.w;
      if (mode != 2) *(float4*)(x + (size_t)node * 64 + h0) = xn[nt];
    }
    if (mode == 1) {
      unsigned lo = (unsigned)f2bf(xn[nt].x) | ((unsigned)f2bf(xn[nt].y) << 16);
      unsigned hi = (unsigned)f2bf(xn[nt].z) | ((unsigned)f2bf(xn[nt].w) << 16);
      *(uint2*)(xnb + nd * 128 + ((h0 * 2) ^ ((nd & 7) << 4))) = make_uint2(lo, hi);
    }
  }

  // ---- fused xu: per-graph max of x_new ----
  {
    bool uni = (n0 + 31 < N) && (sgb[0] == sgb[31]);
    if (uni) {
      float mx0 = fmaxf(xn[0].x, xn[1].x);
      float mx1 = fmaxf(xn[0].y, xn[1].y);
      float mx2 = fmaxf(xn[0].z, xn[1].z);
      float mx3 = fmaxf(xn[0].w, xn[1].w);
#pragma unroll
      for (int msk = 1; msk <= 8; msk <<= 1) {
        mx0 = fmaxf(mx0, __shfl_xor(mx0, msk));
        mx1 = fmaxf(mx1, __shfl_xor(mx1, msk));
        mx2 = fmaxf(mx2, __shfl_xor(mx2, msk));
        mx3 = fmaxf(mx3, __shfl_xor(mx3, msk));
      }
      if (lr == 0) {
        unsigned* xe = xu_enc + sgb[0] * 64 + h0;
        atomicMax(xe + 0, enc_ordered(mx0));
        atomicMax(xe + 1, enc_ordered(mx1));
        atomicMax(xe + 2, enc_ordered(mx2));
        atomicMax(xe + 3, enc_ordered(mx3));
      }
    } else {
#pragma unroll
      for (int nt = 0; nt < 2; ++nt) {
        int nd = nt * 16 + lr;
        if (n0 + nd < N) {
          unsigned* xe = xu_enc + sgb[nd] * 64 + h0;
          atomicMax(xe + 0, enc_ordered(xn[nt].x));
          atomicMax(xe + 1, enc_ordered(xn[nt].y));
          atomicMax(xe + 2, enc_ordered(xn[nt].z));
          atomicMax(xe + 3, enc_ordered(xn[nt].w));
        }
      }
    }
  }
  __syncthreads();

  if (mode == 1) {
    // ---- stage 3: y_next = Welb @ x_new^T (bf16 out) ----
    f32x4 acc3[2] = {{0.f, 0.f, 0.f, 0.f}, {0.f, 0.f, 0.f, 0.f}};
    const unsigned short* W3p = Welb + (w * 16 + lr) * 64 + lk8;
#pragma unroll
    for (int ks = 0; ks < 2; ++ks) {
      short8 a = *(const short8*)(W3p + ks * 32);
      int kb = ks * 64 + lk8 * 2;
      short8 b0 = *(const short8*)(xnb + lr * 128 + (kb ^ swzr));
      short8 b1 = *(const short8*)(xnb + (16 + lr) * 128 + (kb ^ swzr));
      acc3[0] = __builtin_amdgcn_mfma_f32_16x16x32_bf16(a, b0, acc3[0], 0, 0, 0);
      acc3[1] = __builtin_amdgcn_mfma_f32_16x16x32_bf16(a, b1, acc3[1], 0, 0, 0);
    }
    int o0 = w * 16 + jo;
#pragma unroll
    for (int nt = 0; nt < 2; ++nt) {
      int node = n0 + nt * 16 + lr;
      if (node < N) {
        unsigned lo = (unsigned)f2bf(acc3[nt][0]) | ((unsigned)f2bf(acc3[nt][1]) << 16);
        unsigned hi = (unsigned)f2bf(acc3[nt][2]) | ((unsigned)f2bf(acc3[nt][3]) << 16);
        *(uint2*)(y_bf + (size_t)node * 64 + o0) = make_uint2(lo, hi);
      }
    }
  } else if (mode == 2) {
    // ---- fused output projection: out0/out1 = x_new . Wo0/Wo1 + b ----
    float4 w0 = *(const float4*)(Wo0 + h0);
    float4 w1 = *(const float4*)(Wo1 + h0);
    float* ow = (float*)h1T;  // [4 waves][2 outs][32 nodes]
#pragma unroll
    for (int nt = 0; nt < 2; ++nt) {
      float p0 = xn[nt].x * w0.x + xn[nt].y * w0.y + xn[nt].z * w0.z + xn[nt].w * w0.w;
      float p1 = xn[nt].x * w1.x + xn[nt].y * w1.y + xn[nt].z * w1.z + xn[nt].w * w1.w;
      p0 += __shfl_xor(p0, 16); p0 += __shfl_xor(p0, 32);
      p1 += __shfl_xor(p1, 16); p1 += __shfl_xor(p1, 32);
      if (l < 16) {
        ow[w * 64 + 0 + nt * 16 + lr] = p0;
        ow[w * 64 + 32 + nt * 16 + lr] = p1;
      }
    }
    __syncthreads();
    if (t < 64) {
      int oi = t >> 5, nd = t & 31;
      int node = n0 + nd;
      if (node < N) {
        float v = ow[0 * 64 + oi * 32 + nd] + ow[1 * 64 + oi * 32 + nd] +
                  ow[2 * 64 + oi * 32 + nd] + ow[3 * 64 + oi * 32 + nd];
        v += (oi ? bo1[0] : bo0[0]);
        outp[(size_t)oi * N + node] = v;
      }
    }
  }
}

// per-graph: u update, LSTM, reset xu_enc
__global__ __launch_bounds__(64) void k_graph(unsigned* __restrict__ xu_enc,
                                              float* __restrict__ u,
                                              const float* __restrict__ W_gl,
                                              const float* __restrict__ b_gl,
                                              const float* __restrict__ W_ih,
                                              const float* __restrict__ b_ih,
                                              const float* __restrict__ b_hh,
                                              float* __restrict__ c_out) {
  __shared__ float xu_s[64], us[64], un[64];
  int g = blockIdx.x, h = threadIdx.x;
  unsigned Ev = xu_enc[g * 64 + h];
  float f = (Ev & 0x80000000u) ? __uint_as_float(Ev & 0x7FFFFFFFu) : __uint_as_float(~Ev);
  if (!isfinite(f)) f = 0.f;
  xu_s[h] = f;
  float uo = u[g * 64 + h];
  us[h] = uo;
  __syncthreads();
  float pre = b_gl[h];
  for (int k = 0; k < 64; ++k) pre += xu_s[k] * W_gl[h * 128 + k];
  for (int k = 0; k < 64; ++k) pre += us[k] * W_gl[h * 128 + 64 + k];
  float unew = uo + fmaxf(pre, 0.f);
  un[h] = unew;
  __syncthreads();
  float gi = b_ih[h] + b_hh[h];
  float gg = b_ih[128 + h] + b_hh[128 + h];
  float go = b_ih[192 + h] + b_hh[192 + h];
  for (int k = 0; k < 64; ++k) {
    float uv = un[k];
    gi += uv * W_ih[h * 64 + k];
    gg += uv * W_ih[(128 + h) * 64 + k];
    go += uv * W_ih[(192 + h) * 64 + k];
  }
  float cc = (1.f / (1.f + expf(-gi))) * tanhf(gg);
  float u2v = (1.f / (1.f + expf(-go))) * tanhf(cc);
  c_out[g * 64 + h] = cc;
  u[g * 64 + h] = u2v;
  xu_enc[g * 64 + h] = 0x007FFFFFu;  // reset for next layer / next call
}

extern "C" void kernel_launch(void* const* d_in, const int* in_sizes, int n_in,
                              void* d_out, int out_size, void* d_ws, size_t ws_size,
                              hipStream_t stream) {
  const float* v0 = (const float*)d_in[0];
  const float* v1 = (const float*)d_in[1];
  const float* dist = (const float*)d_in[2];
  const int* eidx = (const int*)d_in[3];
  const int* batch = (const int*)d_in[4];
  const float* wte = (const float*)d_in[6];
  const float* Wi0 = (const float*)d_in[7];
  const float* bi0 = (const float*)d_in[8];
  const float* Wi1 = (const float*)d_in[9];
  const float* bi1 = (const float*)d_in[10];
  const float* Wo0 = (const float*)d_in[11];
  const float* bo0 = (const float*)d_in[12];
  const float* Wo1 = (const float*)d_in[13];
  const float* bo1 = (const float*)d_in[14];
  const float* W_edge = (const float*)d_in[15];
  const float* b_edge = (const float*)d_in[16];
  const float* W_el = (const float*)d_in[17];
  const float* b_el = (const float*)d_in[18];
  const float* W_n1 = (const float*)d_in[19];
  const float* b_n1 = (const float*)d_in[20];
  const float* W_n2 = (const float*)d_in[21];
  const float* b_n2 = (const float*)d_in[22];
  const float* W_gl = (const float*)d_in[23];
  const float* b_gl = (const float*)d_in[24];
  const float* W_ih = (const float*)d_in[25];
  const float* b_ih = (const float*)d_in[27];
  const float* b_hh = (const float*)d_in[28];

  const int N = in_sizes[0];
  const int E = in_sizes[2];
  const int NH = N * 64;
  const int NB512 = (N + 511) / 512;

  float* ws = (float*)d_ws;
  float* x = ws;                                   // NH
  float* u = x + NH;                               // 4096
  unsigned* xu_enc = (unsigned*)(u + 4096);        // 4096
  float* p = (float*)(xu_enc + 4096);
  float* q = p + 64;
  float* c0 = q + 64;
  float* c1 = c0 + 64;
  float* c2 = c1 + 64;
  unsigned short* W1b = (unsigned short*)(c2 + 64);  // 49152
  unsigned short* W2b = W1b + 49152;                 // 16384
  unsigned short* Welb = W2b + 16384;                // 4096
  unsigned short* y_bf = Welb + 4096;                // NH
  unsigned short* agg_bf = y_bf + NH;                // NH
  int* deg = (int*)(agg_bf + NH);                    // N
  int* off = deg + N;                                // N
  int* cur = off + N;                                // N
  int* bsum = cur + N;                               // 128
  uint2* spack = (uint2*)(bsum + 128);               // E

  float* outp = (float*)d_out;

  k_prep_pq<<<1, 64, 0, stream>>>(W_el, b_el, W_edge, b_edge, wte, Wi0, bi0, Wi1, bi1,
                                  p, q, c0, c1, c2);
  k_prep2<<<(77824 + 2 * N + 255) / 256, 256, 0, stream>>>(u, xu_enc, W1b, W2b, Welb,
                                                           W_n1, W_n2, W_el, deg, cur, N);
  k_xinit<<<(NH + 255) / 256, 256, 0, stream>>>(v0, v1, wte, Wi0, bi0, Wi1, bi1,
                                                c0, c1, c2, x, y_bf, N);
  k_hist<<<(E + 255) / 256, 256, 0, stream>>>(eidx, deg, E);
  k_scan1<<<NB512, 256, 0, stream>>>(deg, off, bsum, N);
  k_scan2<<<1, 128, 0, stream>>>(bsum, NB512);
  k_scan3<<<(N + 255) / 256, 256, 0, stream>>>(off, bsum, N);
  k_scatter<<<(E + 255) / 256, 256, 0, stream>>>(eidx, dist, off, cur, spack, E);

  for (int l = 0; l < 4; ++l) {
    k_edge2<<<(N + 3) / 4, 256, 0, stream>>>(off, spack, y_bf, p, q, agg_bf, N);
    k_node<<<(N + 31) / 32, 256, 0, stream>>>(agg_bf, x, y_bf, batch, u, W1b, W2b, Welb,
                                              b_n1, b_n2, xu_enc, Wo0, bo0, Wo1, bo1,
                                              outp, N, (l < 3) ? 1 : 2);
    k_graph<<<64, 64, 0, stream>>>(xu_enc, u, W_gl, b_gl, W_ih, b_ih, b_hh,
                                   outp + 2 * N + l * 4096);
  }
}

// Round 5
// 439.423 us; speedup vs baseline: 2.4602x; 1.1011x over previous
//
#include <hip/hip_runtime.h>

// GraphTemporal: N=50000, E=500000, B=64, H=64, L=4 shared layers.
// msg = relu(y[row] + dist*p + q), y = x @ W_el[:, :64].T (closed-form at layer 0)
// Edges CSR-sorted by destination once per call; edge aggregation FUSED into
// k_node stage 0 (LDS atomicMax on fp32 tile, no global atomics, no agg buffer).
// Per-graph max via disjoint per-block scratch (bmaxA/B) reduced in k_graph;
// global atomicMax only as a fallback for >2-graphs-per-block (never in practice).

typedef __attribute__((ext_vector_type(8))) short short8;
typedef __attribute__((ext_vector_type(4))) float f32x4;

__device__ __forceinline__ unsigned short f2bf(float f) {
  union { float f; unsigned u; } v; v.f = f;
  unsigned r = v.u + 0x7FFFu + ((v.u >> 16) & 1u);
  return (unsigned short)(r >> 16);
}
__device__ __forceinline__ float bf2f(unsigned short s) {
  return __uint_as_float((unsigned)s << 16);
}
__device__ __forceinline__ unsigned enc_ordered(float f) {
  unsigned u = __float_as_uint(f);
  return (u >> 31) ? ~u : (u | 0x80000000u);
}

// p,q (edge affine), c0..c2 (closed-form layer-0 y): 64 threads
__global__ void k_prep_pq(const float* __restrict__ W_el, const float* __restrict__ b_el,
                          const float* __restrict__ W_edge, const float* __restrict__ b_edge,
                          const float* __restrict__ wte,
                          const float* __restrict__ Wi0, const float* __restrict__ bi0,
                          const float* __restrict__ Wi1, const float* __restrict__ bi1,
                          float* __restrict__ p, float* __restrict__ q,
                          float* __restrict__ c0, float* __restrict__ c1,
                          float* __restrict__ c2) {
  int h = threadIdx.x;
  float pp = 0.f, qq = 0.f, s0 = 0.f, s1 = 0.f, s2 = 0.f;
  for (int k = 0; k < 64; ++k) {
    float w2 = W_el[h * 128 + 64 + k];
    pp += w2 * W_edge[k];
    qq += w2 * b_edge[k];
    float w1 = W_el[h * 128 + k];
    float base = wte[k] + wte[64 + k] + bi0[k] + bi1[k];
    s0 += w1 * base;
    s1 += w1 * Wi0[k];
    s2 += w1 * Wi1[k];
  }
  p[h] = pp; q[h] = qq + b_el[h];
  c0[h] = s0; c1[h] = s1; c2[h] = s2;
}

// u=0, xu_enc=enc(-inf), bf16 weights, zero deg/cur, init gstart/gend
__global__ void k_prep2(float* __restrict__ u, unsigned* __restrict__ xu_enc,
                        unsigned short* __restrict__ W1b, unsigned short* __restrict__ W2b,
                        unsigned short* __restrict__ Welb,
                        const float* __restrict__ W_n1, const float* __restrict__ W_n2,
                        const float* __restrict__ W_el,
                        int* __restrict__ deg, int* __restrict__ cur,
                        int* __restrict__ gstart, int* __restrict__ gend, int N) {
  int gt = blockIdx.x * 256 + threadIdx.x;
  if (gt < 4096) {
    u[gt] = 0.f;
  } else if (gt < 8192) {
    xu_enc[gt - 4096] = 0x007FFFFFu;  // enc(-inf)
  } else if (gt < 8192 + 49152) {
    int i = gt - 8192;                 // W_n1 [256][192]
    W1b[i] = f2bf(W_n1[i]);
  } else if (gt < 8192 + 49152 + 16384) {
    int i = gt - 57344;                // W_n2 [64][256]
    W2b[i] = f2bf(W_n2[i]);
  } else if (gt < 77824) {
    int i = gt - 73728;                // W_el[:, :64] compact stride 64
    Welb[i] = f2bf(W_el[(i >> 6) * 128 + (i & 63)]);
  } else if (gt < 77824 + N) {
    deg[gt - 77824] = 0;
  } else if (gt < 77824 + 2 * N) {
    cur[gt - 77824 - N] = 0;
  } else if (gt < 77824 + 2 * N + 64) {
    gstart[gt - 77824 - 2 * N] = N;    // atomicMin target
  } else if (gt < 77824 + 2 * N + 128) {
    gend[gt - 77824 - 2 * N - 64] = 0; // atomicMax target
  }
}

// x init + closed-form y0 (bf16) + graph node-range detection
__global__ void k_xinit(const float* __restrict__ v0, const float* __restrict__ v1,
                        const float* __restrict__ wte,
                        const float* __restrict__ Wi0, const float* __restrict__ bi0,
                        const float* __restrict__ Wi1, const float* __restrict__ bi1,
                        const float* __restrict__ c0, const float* __restrict__ c1,
                        const float* __restrict__ c2, const int* __restrict__ batch,
                        int* __restrict__ gstart, int* __restrict__ gend,
                        float* __restrict__ x, unsigned short* __restrict__ y_bf, int N) {
  int idx = blockIdx.x * 256 + threadIdx.x;
  if (idx >= N * 64) return;
  int n = idx >> 6, h = idx & 63;
  float a = v0[n], b = v1[n];
  x[idx] = wte[h] + wte[64 + h] + bi0[h] + bi1[h] + a * Wi0[h] + b * Wi1[h];
  y_bf[idx] = f2bf(c0[h] + a * c1[h] + b * c2[h]);
  if (h == 0) {
    int bg = batch[n];
    if (n == 0 || batch[n - 1] != bg) atomicMin(&gstart[bg], n);
    if (n == N - 1 || batch[n + 1] != bg) atomicMax(&gend[bg], n + 1);
  }
}

// ---- CSR build (once per call) ----
__global__ __launch_bounds__(256) void k_hist(const int* __restrict__ eidx,
                                              int* __restrict__ deg, int E) {
  int e = blockIdx.x * 256 + threadIdx.x;
  if (e < E) atomicAdd(&deg[eidx[E + e]], 1);
}

__global__ __launch_bounds__(256) void k_scan1(const int* __restrict__ deg,
                                               int* __restrict__ off,
                                               int* __restrict__ bsum, int N) {
  __shared__ int s[256];
  int b = blockIdx.x, t = threadIdx.x;
  int i0 = b * 512 + t * 2;
  int v0 = (i0 < N) ? deg[i0] : 0;
  int v1 = (i0 + 1 < N) ? deg[i0 + 1] : 0;
  int sum = v0 + v1;
  s[t] = sum;
  __syncthreads();
  for (int d = 1; d < 256; d <<= 1) {
    int val = (t >= d) ? s[t - d] : 0;
    __syncthreads();
    s[t] += val;
    __syncthreads();
  }
  int excl = s[t] - sum;
  if (i0 < N) off[i0] = excl + v0;
  if (i0 + 1 < N) off[i0 + 1] = excl + v0 + v1;
  if (t == 255) bsum[b] = s[t];
}

__global__ void k_scan2(int* __restrict__ bsum, int nb) {
  __shared__ int s[128];
  int t = threadIdx.x;
  int v = (t < nb) ? bsum[t] : 0;
  s[t] = v;
  __syncthreads();
  for (int d = 1; d < 128; d <<= 1) {
    int val = (t >= d) ? s[t - d] : 0;
    __syncthreads();
    s[t] += val;
    __syncthreads();
  }
  if (t < nb) bsum[t] = s[t] - v;
}

__global__ __launch_bounds__(256) void k_scan3(int* __restrict__ off,
                                               const int* __restrict__ bsum, int N) {
  int i = blockIdx.x * 256 + threadIdx.x;
  if (i < N) off[i] += bsum[i >> 9];
}

__global__ __launch_bounds__(256) void k_scatter(const int* __restrict__ eidx,
                                                 const float* __restrict__ dist,
                                                 const int* __restrict__ off,
                                                 int* __restrict__ cur,
                                                 uint2* __restrict__ spack,
                                                 unsigned char* __restrict__ colb, int E) {
  int e = blockIdx.x * 256 + threadIdx.x;
  if (e >= E) return;
  int c = eidx[E + e];
  int base = (c == 0) ? 0 : off[c - 1];
  int pos = base + atomicAdd(&cur[c], 1);
  spack[pos] = make_uint2((unsigned)eidx[e], __float_as_uint(dist[e]));
  colb[pos] = (unsigned char)(c & 31);
}

// Fused per-layer kernel: edge-agg (LDS) + node MLP (MFMA) + xu partials
//   stage 0: agg[32][64] = segment-max over CSR edges (LDS atomicMax, fp32)
//   stage 1: h1 = relu(W1 @ [agg|x|u[batch]]^T + b_n1)   (K=192, O=256)
//   stage 2: x_new = x + W2 @ h1^T + b_n2
//   mode 1: y_next = Welb @ x_new^T (bf16) ; mode 2 (last): fused out-proj
//   epilogue: per-block per-graph max -> bmaxA/B scratch (no global atomics)
__global__ __launch_bounds__(256) void k_node(
    const int* __restrict__ off, const uint2* __restrict__ spack,
    const unsigned char* __restrict__ colb,
    const float* __restrict__ p, const float* __restrict__ q,
    float* __restrict__ x, unsigned short* __restrict__ y_bf,
    const int* __restrict__ batch, const float* __restrict__ u,
    const unsigned short* __restrict__ W1b, const unsigned short* __restrict__ W2b,
    const unsigned short* __restrict__ Welb,
    const float* __restrict__ b_n1, const float* __restrict__ b_n2,
    unsigned* __restrict__ xu_enc,
    float* __restrict__ bmaxA, float* __restrict__ bmaxB,
    int* __restrict__ bgidA, int* __restrict__ bgidB,
    const float* __restrict__ Wo0, const float* __restrict__ bo0,
    const float* __restrict__ Wo1, const float* __restrict__ bo1,
    float* __restrict__ outp,
    int N, int mode) {
  __shared__ __align__(16) char inb[32 * 384];  // [32][192] bf16 (xnb aliases)
  __shared__ __align__(16) char h1T[32 * 512];  // [32][256] bf16 (aggT/ow alias)
  __shared__ int sgb[32];
  int t = threadIdx.x;
  int n0 = blockIdx.x * 32;
  int lane = t & 63, wv = t >> 6;

  // ---- issue x/u/batch loads early (regs) ----
  int nd_s = t >> 3, ko = t & 7;  // 32 nodes x 8 16B-chunks
  int node_s = n0 + nd_s;
  float4 xa = make_float4(0.f, 0.f, 0.f, 0.f), xb = xa, ua = xa, ub = xa;
  if (node_s < N) {
    const float4* x4 = (const float4*)x;
    xa = x4[node_s * 16 + ko * 2];
    xb = x4[node_s * 16 + ko * 2 + 1];
    int g = batch[node_s];
    const float4* u4 = (const float4*)u;
    ua = u4[g * 16 + ko * 2];
    ub = u4[g * 16 + ko * 2 + 1];
  }
  if (t < 32) sgb[t] = batch[min(n0 + t, N - 1)];
  float pv = p[lane], qv = q[lane];

  // ---- zero agg tile (aliases h1T) ----
  int* aggi = (int*)h1T;  // [32][64] fp32-as-int, msg >= 0
#pragma unroll
  for (int i = 0; i < 8; ++i) aggi[t + i * 256] = 0;

  // ---- write x/u sections of inb (disjoint from aggT) ----
  {
    int swz = (nd_s & 7) << 4;
    char* row = inb + nd_s * 384;
    uint4 xv, uv;
    xv.x = f2bf(xa.x) | ((unsigned)f2bf(xa.y) << 16);
    xv.y = f2bf(xa.z) | ((unsigned)f2bf(xa.w) << 16);
    xv.z = f2bf(xb.x) | ((unsigned)f2bf(xb.y) << 16);
    xv.w = f2bf(xb.z) | ((unsigned)f2bf(xb.w) << 16);
    *(uint4*)(row + ((128 + ko * 16) ^ swz)) = xv;
    uv.x = f2bf(ua.x) | ((unsigned)f2bf(ua.y) << 16);
    uv.y = f2bf(ua.z) | ((unsigned)f2bf(ua.w) << 16);
    uv.z = f2bf(ub.x) | ((unsigned)f2bf(ub.y) << 16);
    uv.w = f2bf(ub.z) | ((unsigned)f2bf(ub.w) << 16);
    *(uint4*)(row + ((256 + ko * 16) ^ swz)) = uv;
  }
  __syncthreads();

  // ---- stage 0: edge aggregation over block's CSR range ----
  {
    int ebase = (n0 == 0) ? 0 : off[n0 - 1];
    int eend = off[min(n0 + 31, N - 1)];
    int e = ebase + wv;
    for (; e + 12 < eend; e += 16) {
      uint2 s0 = spack[e], s1 = spack[e + 4], s2 = spack[e + 8], s3 = spack[e + 12];
      int q0 = colb[e], q1 = colb[e + 4], q2 = colb[e + 8], q3 = colb[e + 12];
      float y0 = bf2f(y_bf[(size_t)s0.x * 64 + lane]);
      float y1 = bf2f(y_bf[(size_t)s1.x * 64 + lane]);
      float y2 = bf2f(y_bf[(size_t)s2.x * 64 + lane]);
      float y3 = bf2f(y_bf[(size_t)s3.x * 64 + lane]);
      atomicMax(&aggi[q0 * 64 + lane], __float_as_int(fmaxf(fmaf(__uint_as_float(s0.y), pv, y0 + qv), 0.f)));
      atomicMax(&aggi[q1 * 64 + lane], __float_as_int(fmaxf(fmaf(__uint_as_float(s1.y), pv, y1 + qv), 0.f)));
      atomicMax(&aggi[q2 * 64 + lane], __float_as_int(fmaxf(fmaf(__uint_as_float(s2.y), pv, y2 + qv), 0.f)));
      atomicMax(&aggi[q3 * 64 + lane], __float_as_int(fmaxf(fmaf(__uint_as_float(s3.y), pv, y3 + qv), 0.f)));
    }
    for (; e < eend; e += 4) {
      uint2 s0 = spack[e];
      int q0 = colb[e];
      float y0 = bf2f(y_bf[(size_t)s0.x * 64 + lane]);
      atomicMax(&aggi[q0 * 64 + lane], __float_as_int(fmaxf(fmaf(__uint_as_float(s0.y), pv, y0 + qv), 0.f)));
    }
  }
  __syncthreads();

  // ---- agg tile -> inb bf16 (swizzled) ----
  {
    int swz = (nd_s & 7) << 4;
    const float4* ag4 = (const float4*)(h1T);  // aggT fp32
    float4 aa = ag4[nd_s * 16 + ko * 2];
    float4 ab = ag4[nd_s * 16 + ko * 2 + 1];
    uint4 av;
    av.x = f2bf(aa.x) | ((unsigned)f2bf(aa.y) << 16);
    av.y = f2bf(aa.z) | ((unsigned)f2bf(aa.w) << 16);
    av.z = f2bf(ab.x) | ((unsigned)f2bf(ab.y) << 16);
    av.w = f2bf(ab.z) | ((unsigned)f2bf(ab.w) << 16);
    *(uint4*)(inb + nd_s * 384 + ((ko * 16) ^ swz)) = av;
  }
  __syncthreads();

  int lr = lane & 15;
  int lk8 = (lane >> 4) << 3;
  int jo = (lane >> 4) << 2;
  int swzr = (lr & 7) << 4;
  int w = wv;

  // ---- stage 1: h1 = relu(W1 @ in^T + b_n1) ----
  f32x4 acc[4][2];
#pragma unroll
  for (int ot = 0; ot < 4; ++ot)
#pragma unroll
    for (int nt = 0; nt < 2; ++nt) acc[ot][nt] = (f32x4){0.f, 0.f, 0.f, 0.f};
  const unsigned short* W1p = W1b + (w * 64 + lr) * 192 + lk8;
#pragma unroll
  for (int ks = 0; ks < 6; ++ks) {
    int kb = ks * 64 + lk8 * 2;
    short8 b0 = *(const short8*)(inb + lr * 384 + (kb ^ swzr));
    short8 b1 = *(const short8*)(inb + (16 + lr) * 384 + (kb ^ swzr));
#pragma unroll
    for (int ot = 0; ot < 4; ++ot) {
      short8 a = *(const short8*)(W1p + ot * (16 * 192) + ks * 32);
      acc[ot][0] = __builtin_amdgcn_mfma_f32_16x16x32_bf16(a, b0, acc[ot][0], 0, 0, 0);
      acc[ot][1] = __builtin_amdgcn_mfma_f32_16x16x32_bf16(a, b1, acc[ot][1], 0, 0, 0);
    }
  }
  __syncthreads();  // aggT fully read; safe to overwrite h1T
#pragma unroll
  for (int ot = 0; ot < 4; ++ot) {
    int o = w * 64 + ot * 16 + jo;
    float4 bs = *(const float4*)(b_n1 + o);
#pragma unroll
    for (int nt = 0; nt < 2; ++nt) {
      int nd = nt * 16 + lr;
      unsigned lo = (unsigned)f2bf(fmaxf(acc[ot][nt][0] + bs.x, 0.f)) |
                    ((unsigned)f2bf(fmaxf(acc[ot][nt][1] + bs.y, 0.f)) << 16);
      unsigned hi = (unsigned)f2bf(fmaxf(acc[ot][nt][2] + bs.z, 0.f)) |
                    ((unsigned)f2bf(fmaxf(acc[ot][nt][3] + bs.w, 0.f)) << 16);
      *(uint2*)(h1T + nd * 512 + ((o * 2) ^ ((nd & 7) << 4))) = make_uint2(lo, hi);
    }
  }
  __syncthreads();

  // ---- stage 2: x_new = x + W2 @ h1^T + b_n2 ----
  f32x4 acc2[2] = {{0.f, 0.f, 0.f, 0.f}, {0.f, 0.f, 0.f, 0.f}};
  const unsigned short* W2p = W2b + (w * 16 + lr) * 256 + lk8;
#pragma unroll
  for (int ks = 0; ks < 8; ++ks) {
    short8 a = *(const short8*)(W2p + ks * 32);
    int kb = ks * 64 + lk8 * 2;
    short8 b0 = *(const short8*)(h1T + lr * 512 + (kb ^ swzr));
    short8 b1 = *(const short8*)(h1T + (16 + lr) * 512 + (kb ^ swzr));
    acc2[0] = __builtin_amdgcn_mfma_f32_16x16x32_bf16(a, b0, acc2[0], 0, 0, 0);
    acc2[1] = __builtin_amdgcn_mfma_f32_16x16x32_bf16(a, b1, acc2[1], 0, 0, 0);
  }
  int h0 = w * 16 + jo;
  float4 b2 = *(const float4*)(b_n2 + h0);
  char* xnb = inb;  // alias
  float4 xn[2];
#pragma unroll
  for (int nt = 0; nt < 2; ++nt) {
    int nd = nt * 16 + lr;
    int node = n0 + nd;
    xn[nt] = make_float4(0.f, 0.f, 0.f, 0.f);
    if (node < N) {
      float4 xo = *(const float4*)(x + (size_t)node * 64 + h0);
      xn[nt].x = xo.x + acc2[nt][0] + b2.x;
      xn[nt].y = xo.y + acc2[nt][1] + b2.y;
      xn[nt].z = xo.z + acc2[nt][2] + b2.z;
      xn[nt].w = xo.w + acc2[nt][3] + b2.w;
      if (mode != 2) *(float4*)(x + (size_t)node * 64 + h0) = xn[nt];
    }
    if (mode == 1) {
      unsigned lo = (unsigned)f2bf(xn[nt].x) | ((unsigned)f2bf(xn[nt].y) << 16);
      unsigned hi = (unsigned)f2bf(xn[nt].z) | ((unsigned)f2bf(xn[nt].w) << 16);
      *(uint2*)(xnb + nd * 128 + ((h0 * 2) ^ ((nd & 7) << 4))) = make_uint2(lo, hi);
    }
  }

  // ---- per-graph max partials -> disjoint scratch (no global atomics) ----
  {
    const float NEG = -__builtin_huge_valf();
    int gA = sgb[0], gB = sgb[31];
    float a0 = NEG, a1 = NEG, a2 = NEG, a3 = NEG;
    float e0 = NEG, e1 = NEG, e2 = NEG, e3 = NEG;
#pragma unroll
    for (int nt = 0; nt < 2; ++nt) {
      int nd = nt * 16 + lr;
      if (n0 + nd < N) {
        int g = sgb[nd];
        if (g == gA) {
          a0 = fmaxf(a0, xn[nt].x); a1 = fmaxf(a1, xn[nt].y);
          a2 = fmaxf(a2, xn[nt].z); a3 = fmaxf(a3, xn[nt].w);
        } else if (g == gB) {
          e0 = fmaxf(e0, xn[nt].x); e1 = fmaxf(e1, xn[nt].y);
          e2 = fmaxf(e2, xn[nt].z); e3 = fmaxf(e3, xn[nt].w);
        } else {  // >2 graphs in block: rare fallback
          unsigned* xe = xu_enc + g * 64 + h0;
          atomicMax(xe + 0, enc_ordered(xn[nt].x));
          atomicMax(xe + 1, enc_ordered(xn[nt].y));
          atomicMax(xe + 2, enc_ordered(xn[nt].z));
          atomicMax(xe + 3, enc_ordered(xn[nt].w));
        }
      }
    }
#pragma unroll
    for (int msk = 1; msk <= 8; msk <<= 1) {
      a0 = fmaxf(a0, __shfl_xor(a0, msk)); a1 = fmaxf(a1, __shfl_xor(a1, msk));
      a2 = fmaxf(a2, __shfl_xor(a2, msk)); a3 = fmaxf(a3, __shfl_xor(a3, msk));
      e0 = fmaxf(e0, __shfl_xor(e0, msk)); e1 = fmaxf(e1, __shfl_xor(e1, msk));
      e2 = fmaxf(e2, __shfl_xor(e2, msk)); e3 = fmaxf(e3, __shfl_xor(e3, msk));
    }
    if (lr == 0) {
      size_t base = (size_t)blockIdx.x * 64 + h0;
      bmaxA[base + 0] = a0; bmaxA[base + 1] = a1;
      bmaxA[base + 2] = a2; bmaxA[base + 3] = a3;
      bmaxB[base + 0] = e0; bmaxB[base + 1] = e1;
      bmaxB[base + 2] = e2; bmaxB[base + 3] = e3;
    }
    if (t == 0) {
      bgidA[blockIdx.x] = gA;
      bgidB[blockIdx.x] = (gB == gA) ? -1 : gB;
    }
  }
  __syncthreads();

  if (mode == 1) {
    // ---- stage 3: y_next = Welb @ x_new^T (bf16 out) ----
    f32x4 acc3[2] = {{0.f, 0.f, 0.f, 0.f}, {0.f, 0.f, 0.f, 0.f}};
    const unsigned short* W3p = Welb + (w * 16 + lr) * 64 + lk8;
#pragma unroll
    for (int ks = 0; ks < 2; ++ks) {
      short8 a = *(const short8*)(W3p + ks * 32);
      int kb = ks * 64 + lk8 * 2;
      short8 b0 = *(const short8*)(xnb + lr * 128 + (kb ^ swzr));
      short8 b1 = *(const short8*)(xnb + (16 + lr) * 128 + (kb ^ swzr));
      acc3[0] = __builtin_amdgcn_mfma_f32_16x16x32_bf16(a, b0, acc3[0], 0, 0, 0);
      acc3[1] = __builtin_amdgcn_mfma_f32_16x16x32_bf16(a, b1, acc3[1], 0, 0, 0);
    }
    int o0 = w * 16 + jo;
#pragma unroll
    for (int nt = 0; nt < 2; ++nt) {
      int node = n0 + nt * 16 + lr;
      if (node < N) {
        unsigned lo = (unsigned)f2bf(acc3[nt][0]) | ((unsigned)f2bf(acc3[nt][1]) << 16);
        unsigned hi = (unsigned)f2bf(acc3[nt][2]) | ((unsigned)f2bf(acc3[nt][3]) << 16);
        *(uint2*)(y_bf + (size_t)node * 64 + o0) = make_uint2(lo, hi);
      }
    }
  } else if (mode == 2) {
    // ---- fused output projection ----
    float4 w0 = *(const float4*)(Wo0 + h0);
    float4 w1 = *(const float4*)(Wo1 + h0);
    float* ow = (float*)h1T;  // [4 waves][2 outs][32 nodes]
#pragma unroll
    for (int nt = 0; nt < 2; ++nt) {
      float p0 = xn[nt].x * w0.x + xn[nt].y * w0.y + xn[nt].z * w0.z + xn[nt].w * w0.w;
      float p1 = xn[nt].x * w1.x + xn[nt].y * w1.y + xn[nt].z * w1.z + xn[nt].w * w1.w;
      p0 += __shfl_xor(p0, 16); p0 += __shfl_xor(p0, 32);
      p1 += __shfl_xor(p1, 16); p1 += __shfl_xor(p1, 32);
      if (lane < 16) {
        ow[w * 64 + 0 + nt * 16 + lr] = p0;
        ow[w * 64 + 32 + nt * 16 + lr] = p1;
      }
    }
    __syncthreads();
    if (t < 64) {
      int oi = t >> 5, nd = t & 31;
      int node = n0 + nd;
      if (node < N) {
        float v = ow[0 * 64 + oi * 32 + nd] + ow[1 * 64 + oi * 32 + nd] +
                  ow[2 * 64 + oi * 32 + nd] + ow[3 * 64 + oi * 32 + nd];
        v += (oi ? bo1[0] : bo0[0]);
        outp[(size_t)oi * N + node] = v;
      }
    }
  }
}

// per-graph: reduce block partials, u update, LSTM, reset xu_enc fallback
__global__ __launch_bounds__(64) void k_graph(const int* __restrict__ gstart,
                                              const int* __restrict__ gend,
                                              const float* __restrict__ bmaxA,
                                              const float* __restrict__ bmaxB,
                                              const int* __restrict__ bgidA,
                                              const int* __restrict__ bgidB,
                                              unsigned* __restrict__ xu_enc,
                                              float* __restrict__ u,
                                              const float* __restrict__ W_gl,
                                              const float* __restrict__ b_gl,
                                              const float* __restrict__ W_ih,
                                              const float* __restrict__ b_ih,
                                              const float* __restrict__ b_hh,
                                              float* __restrict__ c_out) {
  __shared__ float xu_s[64], us[64], un[64];
  int g = blockIdx.x, h = threadIdx.x;
  float m = -__builtin_huge_valf();
  int gs = gstart[g], ge = gend[g];
  if (gs < ge) {
    int bs = gs >> 5, be = (ge - 1) >> 5;
    for (int b = bs; b <= be; ++b) {
      if (bgidA[b] == g) m = fmaxf(m, bmaxA[(size_t)b * 64 + h]);
      if (bgidB[b] == g) m = fmaxf(m, bmaxB[(size_t)b * 64 + h]);
    }
  }
  {  // fallback decode + reset
    unsigned Ev = xu_enc[g * 64 + h];
    float fd = (Ev & 0x80000000u) ? __uint_as_float(Ev & 0x7FFFFFFFu)
                                  : __uint_as_float(~Ev);
    m = fmaxf(m, fd);
    xu_enc[g * 64 + h] = 0x007FFFFFu;
  }
  float f = isfinite(m) ? m : 0.f;
  xu_s[h] = f;
  float uo = u[g * 64 + h];
  us[h] = uo;
  __syncthreads();
  float pre = b_gl[h];
  for (int k = 0; k < 64; ++k) pre += xu_s[k] * W_gl[h * 128 + k];
  for (int k = 0; k < 64; ++k) pre += us[k] * W_gl[h * 128 + 64 + k];
  float unew = uo + fmaxf(pre, 0.f);
  un[h] = unew;
  __syncthreads();
  float gi = b_ih[h] + b_hh[h];
  float gg = b_ih[128 + h] + b_hh[128 + h];
  float go = b_ih[192 + h] + b_hh[192 + h];
  for (int k = 0; k < 64; ++k) {
    float uv = un[k];
    gi += uv * W_ih[h * 64 + k];
    gg += uv * W_ih[(128 + h) * 64 + k];
    go += uv * W_ih[(192 + h) * 64 + k];
  }
  float cc = (1.f / (1.f + expf(-gi))) * tanhf(gg);
  float u2v = (1.f / (1.f + expf(-go))) * tanhf(cc);
  c_out[g * 64 + h] = cc;
  u[g * 64 + h] = u2v;
}

extern "C" void kernel_launch(void* const* d_in, const int* in_sizes, int n_in,
                              void* d_out, int out_size, void* d_ws, size_t ws_size,
                              hipStream_t stream) {
  const float* v0 = (const float*)d_in[0];
  const float* v1 = (const float*)d_in[1];
  const float* dist = (const float*)d_in[2];
  const int* eidx = (const int*)d_in[3];
  const int* batch = (const int*)d_in[4];
  const float* wte = (const float*)d_in[6];
  const float* Wi0 = (const float*)d_in[7];
  const float* bi0 = (const float*)d_in[8];
  const float* Wi1 = (const float*)d_in[9];
  const float* bi1 = (const float*)d_in[10];
  const float* Wo0 = (const float*)d_in[11];
  const float* bo0 = (const float*)d_in[12];
  const float* Wo1 = (const float*)d_in[13];
  const float* bo1 = (const float*)d_in[14];
  const float* W_edge = (const float*)d_in[15];
  const float* b_edge = (const float*)d_in[16];
  const float* W_el = (const float*)d_in[17];
  const float* b_el = (const float*)d_in[18];
  const float* W_n1 = (const float*)d_in[19];
  const float* b_n1 = (const float*)d_in[20];
  const float* W_n2 = (const float*)d_in[21];
  const float* b_n2 = (const float*)d_in[22];
  const float* W_gl = (const float*)d_in[23];
  const float* b_gl = (const float*)d_in[24];
  const float* W_ih = (const float*)d_in[25];
  const float* b_ih = (const float*)d_in[27];
  const float* b_hh = (const float*)d_in[28];

  const int N = in_sizes[0];
  const int E = in_sizes[2];
  const int NH = N * 64;
  const int NB512 = (N + 511) / 512;
  const int nblk = (N + 31) / 32;

  float* ws = (float*)d_ws;
  float* x = ws;                                   // NH
  float* u = x + NH;                               // 4096
  unsigned* xu_enc = (unsigned*)(u + 4096);        // 4096
  float* p = (float*)(xu_enc + 4096);
  float* q = p + 64;
  float* c0 = q + 64;
  float* c1 = c0 + 64;
  float* c2 = c1 + 64;
  unsigned short* W1b = (unsigned short*)(c2 + 64);  // 49152
  unsigned short* W2b = W1b + 49152;                 // 16384
  unsigned short* Welb = W2b + 16384;                // 4096
  unsigned short* y_bf = Welb + 4096;                // NH
  int* deg = (int*)(y_bf + NH);                      // N
  int* off = deg + N;                                // N
  int* cur = off + N;                                // N
  int* bsum = cur + N;                               // 128
  int* gstart = bsum + 128;                          // 64
  int* gend = gstart + 64;                           // 64
  int* bgidA = gend + 64;                            // nblk
  int* bgidB = bgidA + nblk;                         // nblk
  float* bmaxA = (float*)(bgidB + nblk);             // nblk*64
  float* bmaxB = bmaxA + (size_t)nblk * 64;          // nblk*64
  unsigned char* colb = (unsigned char*)(bmaxB + (size_t)nblk * 64);  // E
  uint2* spack = (uint2*)(((size_t)(colb + E) + 15) & ~(size_t)15);   // E

  float* outp = (float*)d_out;

  k_prep_pq<<<1, 64, 0, stream>>>(W_el, b_el, W_edge, b_edge, wte, Wi0, bi0, Wi1, bi1,
                                  p, q, c0, c1, c2);
  k_prep2<<<(77824 + 2 * N + 128 + 255) / 256, 256, 0, stream>>>(
      u, xu_enc, W1b, W2b, Welb, W_n1, W_n2, W_el, deg, cur, gstart, gend, N);
  k_xinit<<<(NH + 255) / 256, 256, 0, stream>>>(v0, v1, wte, Wi0, bi0, Wi1, bi1,
                                                c0, c1, c2, batch, gstart, gend,
                                                x, y_bf, N);
  k_hist<<<(E + 255) / 256, 256, 0, stream>>>(eidx, deg, E);
  k_scan1<<<NB512, 256, 0, stream>>>(deg, off, bsum, N);
  k_scan2<<<1, 128, 0, stream>>>(bsum, NB512);
  k_scan3<<<(N + 255) / 256, 256, 0, stream>>>(off, bsum, N);
  k_scatter<<<(E + 255) / 256, 256, 0, stream>>>(eidx, dist, off, cur, spack, colb, E);

  for (int l = 0; l < 4; ++l) {
    k_node<<<nblk, 256, 0, stream>>>(off, spack, colb, p, q, x, y_bf, batch, u,
                                     W1b, W2b, Welb, b_n1, b_n2, xu_enc,
                                     bmaxA, bmaxB, bgidA, bgidB,
                                     Wo0, bo0, Wo1, bo1, outp, N, (l < 3) ? 1 : 2);
    k_graph<<<64, 64, 0, stream>>>(gstart, gend, bmaxA, bmaxB, bgidA, bgidB,
                                   xu_enc, u, W_gl, b_gl, W_ih, b_ih, b_hh,
                                   outp + 2 * N + l * 4096);
  }
}

// Round 6
// 422.022 us; speedup vs baseline: 2.5617x; 1.0412x over previous
//
#include <hip/hip_runtime.h>

// GraphTemporal: N=50000, E=500000, B=64, H=64, L=4 shared layers.
// msg = relu(y[row] + dist*p + q), y = x @ W_el[:, :64].T (closed-form at layer 0)
// Edges CSR-sorted by destination; edge aggregation fused into k_node stage 0:
//   spack chunks staged to LDS (coalesced), contiguous per-wave ranges with
//   register running-max (CSR-sorted => rare LDS atomicMax flushes).
// spack.x packs row (bits 0-26) | col-in-block (bits 27-31).
// Per-graph max via disjoint per-block scratch (bmaxA/B) reduced in k_graph.

typedef __attribute__((ext_vector_type(8))) short short8;
typedef __attribute__((ext_vector_type(4))) float f32x4;

__device__ __forceinline__ unsigned short f2bf(float f) {
  union { float f; unsigned u; } v; v.f = f;
  unsigned r = v.u + 0x7FFFu + ((v.u >> 16) & 1u);
  return (unsigned short)(r >> 16);
}
__device__ __forceinline__ float bf2f(unsigned short s) {
  return __uint_as_float((unsigned)s << 16);
}
__device__ __forceinline__ unsigned enc_ordered(float f) {
  unsigned u = __float_as_uint(f);
  return (u >> 31) ? ~u : (u | 0x80000000u);
}

// p,q (edge affine), c0..c2 (closed-form layer-0 y): 64 threads
__global__ void k_prep_pq(const float* __restrict__ W_el, const float* __restrict__ b_el,
                          const float* __restrict__ W_edge, const float* __restrict__ b_edge,
                          const float* __restrict__ wte,
                          const float* __restrict__ Wi0, const float* __restrict__ bi0,
                          const float* __restrict__ Wi1, const float* __restrict__ bi1,
                          float* __restrict__ p, float* __restrict__ q,
                          float* __restrict__ c0, float* __restrict__ c1,
                          float* __restrict__ c2) {
  int h = threadIdx.x;
  float pp = 0.f, qq = 0.f, s0 = 0.f, s1 = 0.f, s2 = 0.f;
  for (int k = 0; k < 64; ++k) {
    float w2 = W_el[h * 128 + 64 + k];
    pp += w2 * W_edge[k];
    qq += w2 * b_edge[k];
    float w1 = W_el[h * 128 + k];
    float base = wte[k] + wte[64 + k] + bi0[k] + bi1[k];
    s0 += w1 * base;
    s1 += w1 * Wi0[k];
    s2 += w1 * Wi1[k];
  }
  p[h] = pp; q[h] = qq + b_el[h];
  c0[h] = s0; c1[h] = s1; c2[h] = s2;
}

// u=0, xu_enc=enc(-inf), bf16 weights, zero deg/cur, init gstart/gend
__global__ void k_prep2(float* __restrict__ u, unsigned* __restrict__ xu_enc,
                        unsigned short* __restrict__ W1b, unsigned short* __restrict__ W2b,
                        unsigned short* __restrict__ Welb,
                        const float* __restrict__ W_n1, const float* __restrict__ W_n2,
                        const float* __restrict__ W_el,
                        int* __restrict__ deg, int* __restrict__ cur,
                        int* __restrict__ gstart, int* __restrict__ gend, int N) {
  int gt = blockIdx.x * 256 + threadIdx.x;
  if (gt < 4096) {
    u[gt] = 0.f;
  } else if (gt < 8192) {
    xu_enc[gt - 4096] = 0x007FFFFFu;  // enc(-inf)
  } else if (gt < 8192 + 49152) {
    int i = gt - 8192;                 // W_n1 [256][192]
    W1b[i] = f2bf(W_n1[i]);
  } else if (gt < 8192 + 49152 + 16384) {
    int i = gt - 57344;                // W_n2 [64][256]
    W2b[i] = f2bf(W_n2[i]);
  } else if (gt < 77824) {
    int i = gt - 73728;                // W_el[:, :64] compact stride 64
    Welb[i] = f2bf(W_el[(i >> 6) * 128 + (i & 63)]);
  } else if (gt < 77824 + N) {
    deg[gt - 77824] = 0;
  } else if (gt < 77824 + 2 * N) {
    cur[gt - 77824 - N] = 0;
  } else if (gt < 77824 + 2 * N + 64) {
    gstart[gt - 77824 - 2 * N] = N;    // atomicMin target
  } else if (gt < 77824 + 2 * N + 128) {
    gend[gt - 77824 - 2 * N - 64] = 0; // atomicMax target
  }
}

// x init + closed-form y0 (bf16) + graph node-range detection
__global__ void k_xinit(const float* __restrict__ v0, const float* __restrict__ v1,
                        const float* __restrict__ wte,
                        const float* __restrict__ Wi0, const float* __restrict__ bi0,
                        const float* __restrict__ Wi1, const float* __restrict__ bi1,
                        const float* __restrict__ c0, const float* __restrict__ c1,
                        const float* __restrict__ c2, const int* __restrict__ batch,
                        int* __restrict__ gstart, int* __restrict__ gend,
                        float* __restrict__ x, unsigned short* __restrict__ y_bf, int N) {
  int idx = blockIdx.x * 256 + threadIdx.x;
  if (idx >= N * 64) return;
  int n = idx >> 6, h = idx & 63;
  float a = v0[n], b = v1[n];
  x[idx] = wte[h] + wte[64 + h] + bi0[h] + bi1[h] + a * Wi0[h] + b * Wi1[h];
  y_bf[idx] = f2bf(c0[h] + a * c1[h] + b * c2[h]);
  if (h == 0) {
    int bg = batch[n];
    if (n == 0 || batch[n - 1] != bg) atomicMin(&gstart[bg], n);
    if (n == N - 1 || batch[n + 1] != bg) atomicMax(&gend[bg], n + 1);
  }
}

// ---- CSR build (once per call) ----
__global__ __launch_bounds__(256) void k_hist(const int* __restrict__ eidx,
                                              int* __restrict__ deg, int E) {
  int e = blockIdx.x * 256 + threadIdx.x;
  if (e < E) atomicAdd(&deg[eidx[E + e]], 1);
}

__global__ __launch_bounds__(256) void k_scan1(const int* __restrict__ deg,
                                               int* __restrict__ off,
                                               int* __restrict__ bsum, int N) {
  __shared__ int s[256];
  int b = blockIdx.x, t = threadIdx.x;
  int i0 = b * 512 + t * 2;
  int v0 = (i0 < N) ? deg[i0] : 0;
  int v1 = (i0 + 1 < N) ? deg[i0 + 1] : 0;
  int sum = v0 + v1;
  s[t] = sum;
  __syncthreads();
  for (int d = 1; d < 256; d <<= 1) {
    int val = (t >= d) ? s[t - d] : 0;
    __syncthreads();
    s[t] += val;
    __syncthreads();
  }
  int excl = s[t] - sum;
  if (i0 < N) off[i0] = excl + v0;
  if (i0 + 1 < N) off[i0 + 1] = excl + v0 + v1;
  if (t == 255) bsum[b] = s[t];
}

__global__ void k_scan2(int* __restrict__ bsum, int nb) {
  __shared__ int s[128];
  int t = threadIdx.x;
  int v = (t < nb) ? bsum[t] : 0;
  s[t] = v;
  __syncthreads();
  for (int d = 1; d < 128; d <<= 1) {
    int val = (t >= d) ? s[t - d] : 0;
    __syncthreads();
    s[t] += val;
    __syncthreads();
  }
  if (t < nb) bsum[t] = s[t] - v;
}

__global__ __launch_bounds__(256) void k_scan3(int* __restrict__ off,
                                               const int* __restrict__ bsum, int N) {
  int i = blockIdx.x * 256 + threadIdx.x;
  if (i < N) off[i] += bsum[i >> 9];
}

// spack.x = row | (col&31)<<27 ; spack.y = dist bits
__global__ __launch_bounds__(256) void k_scatter(const int* __restrict__ eidx,
                                                 const float* __restrict__ dist,
                                                 const int* __restrict__ off,
                                                 int* __restrict__ cur,
                                                 uint2* __restrict__ spack, int E) {
  int e = blockIdx.x * 256 + threadIdx.x;
  if (e >= E) return;
  int c = eidx[E + e];
  int base = (c == 0) ? 0 : off[c - 1];
  int pos = base + atomicAdd(&cur[c], 1);
  spack[pos] = make_uint2((unsigned)eidx[e] | ((unsigned)(c & 31) << 27),
                          __float_as_uint(dist[e]));
}

// Fused per-layer kernel: edge-agg (LDS) + node MLP (MFMA) + xu partials
__global__ __launch_bounds__(256) void k_node(
    const int* __restrict__ off, const uint2* __restrict__ spack,
    const float* __restrict__ p, const float* __restrict__ q,
    float* __restrict__ x, unsigned short* __restrict__ y_bf,
    const int* __restrict__ batch, const float* __restrict__ u,
    const unsigned short* __restrict__ W1b, const unsigned short* __restrict__ W2b,
    const unsigned short* __restrict__ Welb,
    const float* __restrict__ b_n1, const float* __restrict__ b_n2,
    unsigned* __restrict__ xu_enc,
    float* __restrict__ bmaxA, float* __restrict__ bmaxB,
    int* __restrict__ bgidA, int* __restrict__ bgidB,
    const float* __restrict__ Wo0, const float* __restrict__ bo0,
    const float* __restrict__ Wo1, const float* __restrict__ bo1,
    float* __restrict__ outp,
    int N, int mode) {
  __shared__ __align__(16) char inb[32 * 384];  // [32][192] bf16 (xnb aliases)
  __shared__ __align__(16) char h1T[32 * 512];  // [32][256] bf16 (aggT/ow alias)
  __shared__ uint2 smeta[256];
  __shared__ int sgb[32];
  int t = threadIdx.x;
  int n0 = blockIdx.x * 32;
  int lane = t & 63, wv = t >> 6;

  // ---- issue x/u/batch loads early (regs) ----
  int nd_s = t >> 3, ko = t & 7;  // 32 nodes x 8 16B-chunks
  int node_s = n0 + nd_s;
  float4 xa = make_float4(0.f, 0.f, 0.f, 0.f), xb = xa, ua = xa, ub = xa;
  if (node_s < N) {
    const float4* x4 = (const float4*)x;
    xa = x4[node_s * 16 + ko * 2];
    xb = x4[node_s * 16 + ko * 2 + 1];
    int g = batch[node_s];
    const float4* u4 = (const float4*)u;
    ua = u4[g * 16 + ko * 2];
    ub = u4[g * 16 + ko * 2 + 1];
  }
  if (t < 32) sgb[t] = batch[min(n0 + t, N - 1)];
  float pv = p[lane], qv = q[lane];

  // ---- zero agg tile (aliases h1T) ----
  int* aggi = (int*)h1T;  // [32][64] fp32-as-int, msg >= 0
#pragma unroll
  for (int i = 0; i < 8; ++i) aggi[t + i * 256] = 0;

  // ---- write x/u sections of inb (disjoint from aggT) ----
  {
    int swz = (nd_s & 7) << 4;
    char* row = inb + nd_s * 384;
    uint4 xv, uv;
    xv.x = f2bf(xa.x) | ((unsigned)f2bf(xa.y) << 16);
    xv.y = f2bf(xa.z) | ((unsigned)f2bf(xa.w) << 16);
    xv.z = f2bf(xb.x) | ((unsigned)f2bf(xb.y) << 16);
    xv.w = f2bf(xb.z) | ((unsigned)f2bf(xb.w) << 16);
    *(uint4*)(row + ((128 + ko * 16) ^ swz)) = xv;
    uv.x = f2bf(ua.x) | ((unsigned)f2bf(ua.y) << 16);
    uv.y = f2bf(ua.z) | ((unsigned)f2bf(ua.w) << 16);
    uv.z = f2bf(ub.x) | ((unsigned)f2bf(ub.y) << 16);
    uv.w = f2bf(ub.z) | ((unsigned)f2bf(ub.w) << 16);
    *(uint4*)(row + ((256 + ko * 16) ^ swz)) = uv;
  }
  __syncthreads();

  // ---- stage 0: edge aggregation, LDS-staged meta, register running-max ----
  {
    int ebase = (n0 == 0) ? 0 : off[n0 - 1];
    int eend = off[min(n0 + 31, N - 1)];
    float m = 0.f;
    int ccur = -1;
    for (int cb = ebase; cb < eend; cb += 256) {
      int cnt = min(256, eend - cb);
      if (t < cnt) smeta[t] = spack[cb + t];
      __syncthreads();
      int i = wv * 64;
      int iend = min(i + 64, cnt);
      for (; i + 4 <= iend; i += 4) {
        uint2 e0 = smeta[i], e1 = smeta[i + 1], e2 = smeta[i + 2], e3 = smeta[i + 3];
        float y0 = bf2f(y_bf[(size_t)(e0.x & 0x07FFFFFFu) * 64 + lane]);
        float y1 = bf2f(y_bf[(size_t)(e1.x & 0x07FFFFFFu) * 64 + lane]);
        float y2 = bf2f(y_bf[(size_t)(e2.x & 0x07FFFFFFu) * 64 + lane]);
        float y3 = bf2f(y_bf[(size_t)(e3.x & 0x07FFFFFFu) * 64 + lane]);
        float g0 = fmaxf(fmaf(__uint_as_float(e0.y), pv, y0 + qv), 0.f);
        float g1 = fmaxf(fmaf(__uint_as_float(e1.y), pv, y1 + qv), 0.f);
        float g2 = fmaxf(fmaf(__uint_as_float(e2.y), pv, y2 + qv), 0.f);
        float g3 = fmaxf(fmaf(__uint_as_float(e3.y), pv, y3 + qv), 0.f);
        int c0 = (int)(e0.x >> 27), c1 = (int)(e1.x >> 27);
        int c2 = (int)(e2.x >> 27), c3 = (int)(e3.x >> 27);
        if (c0 != ccur) {
          if (ccur >= 0) atomicMax(&aggi[ccur * 64 + lane], __float_as_int(m));
          ccur = c0; m = g0;
        } else m = fmaxf(m, g0);
        if (c1 != ccur) {
          atomicMax(&aggi[ccur * 64 + lane], __float_as_int(m));
          ccur = c1; m = g1;
        } else m = fmaxf(m, g1);
        if (c2 != ccur) {
          atomicMax(&aggi[ccur * 64 + lane], __float_as_int(m));
          ccur = c2; m = g2;
        } else m = fmaxf(m, g2);
        if (c3 != ccur) {
          atomicMax(&aggi[ccur * 64 + lane], __float_as_int(m));
          ccur = c3; m = g3;
        } else m = fmaxf(m, g3);
      }
      for (; i < iend; ++i) {
        uint2 e0 = smeta[i];
        float y0 = bf2f(y_bf[(size_t)(e0.x & 0x07FFFFFFu) * 64 + lane]);
        float g0 = fmaxf(fmaf(__uint_as_float(e0.y), pv, y0 + qv), 0.f);
        int c0 = (int)(e0.x >> 27);
        if (c0 != ccur) {
          if (ccur >= 0) atomicMax(&aggi[ccur * 64 + lane], __float_as_int(m));
          ccur = c0; m = g0;
        } else m = fmaxf(m, g0);
      }
      __syncthreads();
    }
    if (ccur >= 0) atomicMax(&aggi[ccur * 64 + lane], __float_as_int(m));
  }
  __syncthreads();

  // ---- agg tile -> inb bf16 (swizzled) ----
  {
    int swz = (nd_s & 7) << 4;
    const float4* ag4 = (const float4*)(h1T);  // aggT fp32
    float4 aa = ag4[nd_s * 16 + ko * 2];
    float4 ab = ag4[nd_s * 16 + ko * 2 + 1];
    uint4 av;
    av.x = f2bf(aa.x) | ((unsigned)f2bf(aa.y) << 16);
    av.y = f2bf(aa.z) | ((unsigned)f2bf(aa.w) << 16);
    av.z = f2bf(ab.x) | ((unsigned)f2bf(ab.y) << 16);
    av.w = f2bf(ab.z) | ((unsigned)f2bf(ab.w) << 16);
    *(uint4*)(inb + nd_s * 384 + ((ko * 16) ^ swz)) = av;
  }
  __syncthreads();

  int lr = lane & 15;
  int lk8 = (lane >> 4) << 3;
  int jo = (lane >> 4) << 2;
  int swzr = (lr & 7) << 4;
  int w = wv;

  // ---- stage 1: h1 = relu(W1 @ in^T + b_n1) ----
  f32x4 acc[4][2];
#pragma unroll
  for (int ot = 0; ot < 4; ++ot)
#pragma unroll
    for (int nt = 0; nt < 2; ++nt) acc[ot][nt] = (f32x4){0.f, 0.f, 0.f, 0.f};
  const unsigned short* W1p = W1b + (w * 64 + lr) * 192 + lk8;
#pragma unroll
  for (int ks = 0; ks < 6; ++ks) {
    int kb = ks * 64 + lk8 * 2;
    short8 b0 = *(const short8*)(inb + lr * 384 + (kb ^ swzr));
    short8 b1 = *(const short8*)(inb + (16 + lr) * 384 + (kb ^ swzr));
#pragma unroll
    for (int ot = 0; ot < 4; ++ot) {
      short8 a = *(const short8*)(W1p + ot * (16 * 192) + ks * 32);
      acc[ot][0] = __builtin_amdgcn_mfma_f32_16x16x32_bf16(a, b0, acc[ot][0], 0, 0, 0);
      acc[ot][1] = __builtin_amdgcn_mfma_f32_16x16x32_bf16(a, b1, acc[ot][1], 0, 0, 0);
    }
  }
  __syncthreads();  // aggT fully read; safe to overwrite h1T
#pragma unroll
  for (int ot = 0; ot < 4; ++ot) {
    int o = w * 64 + ot * 16 + jo;
    float4 bs = *(const float4*)(b_n1 + o);
#pragma unroll
    for (int nt = 0; nt < 2; ++nt) {
      int nd = nt * 16 + lr;
      unsigned lo = (unsigned)f2bf(fmaxf(acc[ot][nt][0] + bs.x, 0.f)) |
                    ((unsigned)f2bf(fmaxf(acc[ot][nt][1] + bs.y, 0.f)) << 16);
      unsigned hi = (unsigned)f2bf(fmaxf(acc[ot][nt][2] + bs.z, 0.f)) |
                    ((unsigned)f2bf(fmaxf(acc[ot][nt][3] + bs.w, 0.f)) << 16);
      *(uint2*)(h1T + nd * 512 + ((o * 2) ^ ((nd & 7) << 4))) = make_uint2(lo, hi);
    }
  }
  __syncthreads();

  // ---- stage 2: x_new = x + W2 @ h1^T + b_n2 ----
  f32x4 acc2[2] = {{0.f, 0.f, 0.f, 0.f}, {0.f, 0.f, 0.f, 0.f}};
  const unsigned short* W2p = W2b + (w * 16 + lr) * 256 + lk8;
#pragma unroll
  for (int ks = 0; ks < 8; ++ks) {
    short8 a = *(const short8*)(W2p + ks * 32);
    int kb = ks * 64 + lk8 * 2;
    short8 b0 = *(const short8*)(h1T + lr * 512 + (kb ^ swzr));
    short8 b1 = *(const short8*)(h1T + (16 + lr) * 512 + (kb ^ swzr));
    acc2[0] = __builtin_amdgcn_mfma_f32_16x16x32_bf16(a, b0, acc2[0], 0, 0, 0);
    acc2[1] = __builtin_amdgcn_mfma_f32_16x16x32_bf16(a, b1, acc2[1], 0, 0, 0);
  }
  int h0 = w * 16 + jo;
  float4 b2 = *(const float4*)(b_n2 + h0);
  char* xnb = inb;  // alias
  float4 xn[2];
#pragma unroll
  for (int nt = 0; nt < 2; ++nt) {
    int nd = nt * 16 + lr;
    int node = n0 + nd;
    xn[nt] = make_float4(0.f, 0.f, 0.f, 0.f);
    if (node < N) {
      float4 xo = *(const float4*)(x + (size_t)node * 64 + h0);
      xn[nt].x = xo.x + acc2[nt][0] + b2.x;
      xn[nt].y = xo.y + acc2[nt][1] + b2.y;
      xn[nt].z = xo.z + acc2[nt][2] + b2.z;
      xn[nt].w = xo.w + acc2[nt][3] + b2.w;
      if (mode != 2) *(float4*)(x + (size_t)node * 64 + h0) = xn[nt];
    }
    if (mode == 1) {
      unsigned lo = (unsigned)f2bf(xn[nt].x) | ((unsigned)f2bf(xn[nt].y) << 16);
      unsigned hi = (unsigned)f2bf(xn[nt].z) | ((unsigned)f2bf(xn[nt].w) << 16);
      *(uint2*)(xnb + nd * 128 + ((h0 * 2) ^ ((nd & 7) << 4))) = make_uint2(lo, hi);
    }
  }

  // ---- per-graph max partials -> disjoint scratch (no global atomics) ----
  {
    const float NEG = -__builtin_huge_valf();
    int gA = sgb[0], gB = sgb[31];
    float a0 = NEG, a1 = NEG, a2 = NEG, a3 = NEG;
    float e0 = NEG, e1 = NEG, e2 = NEG, e3 = NEG;
#pragma unroll
    for (int nt = 0; nt < 2; ++nt) {
      int nd = nt * 16 + lr;
      if (n0 + nd < N) {
        int g = sgb[nd];
        if (g == gA) {
          a0 = fmaxf(a0, xn[nt].x); a1 = fmaxf(a1, xn[nt].y);
          a2 = fmaxf(a2, xn[nt].z); a3 = fmaxf(a3, xn[nt].w);
        } else if (g == gB) {
          e0 = fmaxf(e0, xn[nt].x); e1 = fmaxf(e1, xn[nt].y);
          e2 = fmaxf(e2, xn[nt].z); e3 = fmaxf(e3, xn[nt].w);
        } else {  // >2 graphs in block: rare fallback
          unsigned* xe = xu_enc + g * 64 + h0;
          atomicMax(xe + 0, enc_ordered(xn[nt].x));
          atomicMax(xe + 1, enc_ordered(xn[nt].y));
          atomicMax(xe + 2, enc_ordered(xn[nt].z));
          atomicMax(xe + 3, enc_ordered(xn[nt].w));
        }
      }
    }
#pragma unroll
    for (int msk = 1; msk <= 8; msk <<= 1) {
      a0 = fmaxf(a0, __shfl_xor(a0, msk)); a1 = fmaxf(a1, __shfl_xor(a1, msk));
      a2 = fmaxf(a2, __shfl_xor(a2, msk)); a3 = fmaxf(a3, __shfl_xor(a3, msk));
      e0 = fmaxf(e0, __shfl_xor(e0, msk)); e1 = fmaxf(e1, __shfl_xor(e1, msk));
      e2 = fmaxf(e2, __shfl_xor(e2, msk)); e3 = fmaxf(e3, __shfl_xor(e3, msk));
    }
    if (lr == 0) {
      size_t base = (size_t)blockIdx.x * 64 + h0;
      bmaxA[base + 0] = a0; bmaxA[base + 1] = a1;
      bmaxA[base + 2] = a2; bmaxA[base + 3] = a3;
      bmaxB[base + 0] = e0; bmaxB[base + 1] = e1;
      bmaxB[base + 2] = e2; bmaxB[base + 3] = e3;
    }
    if (t == 0) {
      bgidA[blockIdx.x] = gA;
      bgidB[blockIdx.x] = (gB == gA) ? -1 : gB;
    }
  }
  __syncthreads();

  if (mode == 1) {
    // ---- stage 3: y_next = Welb @ x_new^T (bf16 out) ----
    f32x4 acc3[2] = {{0.f, 0.f, 0.f, 0.f}, {0.f, 0.f, 0.f, 0.f}};
    const unsigned short* W3p = Welb + (w * 16 + lr) * 64 + lk8;
#pragma unroll
    for (int ks = 0; ks < 2; ++ks) {
      short8 a = *(const short8*)(W3p + ks * 32);
      int kb = ks * 64 + lk8 * 2;
      short8 b0 = *(const short8*)(xnb + lr * 128 + (kb ^ swzr));
      short8 b1 = *(const short8*)(xnb + (16 + lr) * 128 + (kb ^ swzr));
      acc3[0] = __builtin_amdgcn_mfma_f32_16x16x32_bf16(a, b0, acc3[0], 0, 0, 0);
      acc3[1] = __builtin_amdgcn_mfma_f32_16x16x32_bf16(a, b1, acc3[1], 0, 0, 0);
    }
    int o0 = w * 16 + jo;
#pragma unroll
    for (int nt = 0; nt < 2; ++nt) {
      int node = n0 + nt * 16 + lr;
      if (node < N) {
        unsigned lo = (unsigned)f2bf(acc3[nt][0]) | ((unsigned)f2bf(acc3[nt][1]) << 16);
        unsigned hi = (unsigned)f2bf(acc3[nt][2]) | ((unsigned)f2bf(acc3[nt][3]) << 16);
        *(uint2*)(y_bf + (size_t)node * 64 + o0) = make_uint2(lo, hi);
      }
    }
  } else if (mode == 2) {
    // ---- fused output projection ----
    float4 w0 = *(const float4*)(Wo0 + h0);
    float4 w1 = *(const float4*)(Wo1 + h0);
    float* ow = (float*)h1T;  // [4 waves][2 outs][32 nodes]
#pragma unroll
    for (int nt = 0; nt < 2; ++nt) {
      float p0 = xn[nt].x * w0.x + xn[nt].y * w0.y + xn[nt].z * w0.z + xn[nt].w * w0.w;
      float p1 = xn[nt].x * w1.x + xn[nt].y * w1.y + xn[nt].z * w1.z + xn[nt].w * w1.w;
      p0 += __shfl_xor(p0, 16); p0 += __shfl_xor(p0, 32);
      p1 += __shfl_xor(p1, 16); p1 += __shfl_xor(p1, 32);
      if (lane < 16) {
        ow[w * 64 + 0 + nt * 16 + lr] = p0;
        ow[w * 64 + 32 + nt * 16 + lr] = p1;
      }
    }
    __syncthreads();
    if (t < 64) {
      int oi = t >> 5, nd = t & 31;
      int node = n0 + nd;
      if (node < N) {
        float v = ow[0 * 64 + oi * 32 + nd] + ow[1 * 64 + oi * 32 + nd] +
                  ow[2 * 64 + oi * 32 + nd] + ow[3 * 64 + oi * 32 + nd];
        v += (oi ? bo1[0] : bo0[0]);
        outp[(size_t)oi * N + node] = v;
      }
    }
  }
}

// per-graph: reduce block partials, u update, LSTM, reset xu_enc fallback
__global__ __launch_bounds__(64) void k_graph(const int* __restrict__ gstart,
                                              const int* __restrict__ gend,
                                              const float* __restrict__ bmaxA,
                                              const float* __restrict__ bmaxB,
                                              const int* __restrict__ bgidA,
                                              const int* __restrict__ bgidB,
                                              unsigned* __restrict__ xu_enc,
                                              float* __restrict__ u,
                                              const float* __restrict__ W_gl,
                                              const float* __restrict__ b_gl,
                                              const float* __restrict__ W_ih,
                                              const float* __restrict__ b_ih,
                                              const float* __restrict__ b_hh,
                                              float* __restrict__ c_out) {
  __shared__ float xu_s[64], us[64], un[64];
  int g = blockIdx.x, h = threadIdx.x;
  float m = -__builtin_huge_valf();
  int gs = gstart[g], ge = gend[g];
  if (gs < ge) {
    int bs = gs >> 5, be = (ge - 1) >> 5;
    for (int b = bs; b <= be; ++b) {
      if (bgidA[b] == g) m = fmaxf(m, bmaxA[(size_t)b * 64 + h]);
      if (bgidB[b] == g) m = fmaxf(m, bmaxB[(size_t)b * 64 + h]);
    }
  }
  {  // fallback decode + reset
    unsigned Ev = xu_enc[g * 64 + h];
    float fd = (Ev & 0x80000000u) ? __uint_as_float(Ev & 0x7FFFFFFFu)
                                  : __uint_as_float(~Ev);
    m = fmaxf(m, fd);
    xu_enc[g * 64 + h] = 0x007FFFFFu;
  }
  float f = isfinite(m) ? m : 0.f;
  xu_s[h] = f;
  float uo = u[g * 64 + h];
  us[h] = uo;
  __syncthreads();
  float pre = b_gl[h];
  for (int k = 0; k < 64; ++k) pre += xu_s[k] * W_gl[h * 128 + k];
  for (int k = 0; k < 64; ++k) pre += us[k] * W_gl[h * 128 + 64 + k];
  float unew = uo + fmaxf(pre, 0.f);
  un[h] = unew;
  __syncthreads();
  float gi = b_ih[h] + b_hh[h];
  float gg = b_ih[128 + h] + b_hh[128 + h];
  float go = b_ih[192 + h] + b_hh[192 + h];
  for (int k = 0; k < 64; ++k) {
    float uv = un[k];
    gi += uv * W_ih[h * 64 + k];
    gg += uv * W_ih[(128 + h) * 64 + k];
    go += uv * W_ih[(192 + h) * 64 + k];
  }
  float cc = (1.f / (1.f + expf(-gi))) * tanhf(gg);
  float u2v = (1.f / (1.f + expf(-go))) * tanhf(cc);
  c_out[g * 64 + h] = cc;
  u[g * 64 + h] = u2v;
}

extern "C" void kernel_launch(void* const* d_in, const int* in_sizes, int n_in,
                              void* d_out, int out_size, void* d_ws, size_t ws_size,
                              hipStream_t stream) {
  const float* v0 = (const float*)d_in[0];
  const float* v1 = (const float*)d_in[1];
  const float* dist = (const float*)d_in[2];
  const int* eidx = (const int*)d_in[3];
  const int* batch = (const int*)d_in[4];
  const float* wte = (const float*)d_in[6];
  const float* Wi0 = (const float*)d_in[7];
  const float* bi0 = (const float*)d_in[8];
  const float* Wi1 = (const float*)d_in[9];
  const float* bi1 = (const float*)d_in[10];
  const float* Wo0 = (const float*)d_in[11];
  const float* bo0 = (const float*)d_in[12];
  const float* Wo1 = (const float*)d_in[13];
  const float* bo1 = (const float*)d_in[14];
  const float* W_edge = (const float*)d_in[15];
  const float* b_edge = (const float*)d_in[16];
  const float* W_el = (const float*)d_in[17];
  const float* b_el = (const float*)d_in[18];
  const float* W_n1 = (const float*)d_in[19];
  const float* b_n1 = (const float*)d_in[20];
  const float* W_n2 = (const float*)d_in[21];
  const float* b_n2 = (const float*)d_in[22];
  const float* W_gl = (const float*)d_in[23];
  const float* b_gl = (const float*)d_in[24];
  const float* W_ih = (const float*)d_in[25];
  const float* b_ih = (const float*)d_in[27];
  const float* b_hh = (const float*)d_in[28];

  const int N = in_sizes[0];
  const int E = in_sizes[2];
  const int NH = N * 64;
  const int NB512 = (N + 511) / 512;
  const int nblk = (N + 31) / 32;

  float* ws = (float*)d_ws;
  float* x = ws;                                   // NH
  float* u = x + NH;                               // 4096
  unsigned* xu_enc = (unsigned*)(u + 4096);        // 4096
  float* p = (float*)(xu_enc + 4096);
  float* q = p + 64;
  float* c0 = q + 64;
  float* c1 = c0 + 64;
  float* c2 = c1 + 64;
  unsigned short* W1b = (unsigned short*)(c2 + 64);  // 49152
  unsigned short* W2b = W1b + 49152;                 // 16384
  unsigned short* Welb = W2b + 16384;                // 4096
  unsigned short* y_bf = Welb + 4096;                // NH
  int* deg = (int*)(y_bf + NH);                      // N
  int* off = deg + N;                                // N
  int* cur = off + N;                                // N
  int* bsum = cur + N;                               // 128
  int* gstart = bsum + 128;                          // 64
  int* gend = gstart + 64;                           // 64
  int* bgidA = gend + 64;                            // nblk
  int* bgidB = bgidA + nblk;                         // nblk
  float* bmaxA = (float*)(bgidB + nblk);             // nblk*64
  float* bmaxB = bmaxA + (size_t)nblk * 64;          // nblk*64
  uint2* spack = (uint2*)(((size_t)(bmaxB + (size_t)nblk * 64) + 15) & ~(size_t)15);  // E

  float* outp = (float*)d_out;

  k_prep_pq<<<1, 64, 0, stream>>>(W_el, b_el, W_edge, b_edge, wte, Wi0, bi0, Wi1, bi1,
                                  p, q, c0, c1, c2);
  k_prep2<<<(77824 + 2 * N + 128 + 255) / 256, 256, 0, stream>>>(
      u, xu_enc, W1b, W2b, Welb, W_n1, W_n2, W_el, deg, cur, gstart, gend, N);
  k_xinit<<<(NH + 255) / 256, 256, 0, stream>>>(v0, v1, wte, Wi0, bi0, Wi1, bi1,
                                                c0, c1, c2, batch, gstart, gend,
                                                x, y_bf, N);
  k_hist<<<(E + 255) / 256, 256, 0, stream>>>(eidx, deg, E);
  k_scan1<<<NB512, 256, 0, stream>>>(deg, off, bsum, N);
  k_scan2<<<1, 128, 0, stream>>>(bsum, NB512);
  k_scan3<<<(N + 255) / 256, 256, 0, stream>>>(off, bsum, N);
  k_scatter<<<(E + 255) / 256, 256, 0, stream>>>(eidx, dist, off, cur, spack, E);

  for (int l = 0; l < 4; ++l) {
    k_node<<<nblk, 256, 0, stream>>>(off, spack, p, q, x, y_bf, batch, u,
                                     W1b, W2b, Welb, b_n1, b_n2, xu_enc,
                                     bmaxA, bmaxB, bgidA, bgidB,
                                     Wo0, bo0, Wo1, bo1, outp, N, (l < 3) ? 1 : 2);
    k_graph<<<64, 64, 0, stream>>>(gstart, gend, bmaxA, bmaxB, bgidA, bgidB,
                                   xu_enc, u, W_gl, b_gl, W_ih, b_ih, b_hh,
                                   outp + 2 * N + l * 4096);
  }
}

// Round 7
// 370.530 us; speedup vs baseline: 2.9177x; 1.1390x over previous
//
#include <hip/hip_runtime.h>

// GraphTemporal: N=50000, E=500000, B=64, H=64, L=4 shared layers.
// msg = relu(y[row] + dist*p + q), y = x @ W_el[:, :64].T
// Layer 0: y computed on the fly from v0,v1 (rank-2 closed form) - no y gather.
// Edges CSR-sorted by destination; aggregation fused into k_node stage 0 with
// double-buffered LDS meta chunks, ILP-8 gather, register running-max.
// x read ONCE per block in stage-2 fragment layout (regs), LDS tile built from regs.
// Per-graph max via disjoint per-block scratch reduced in k_graph.

typedef __attribute__((ext_vector_type(8))) short short8;
typedef __attribute__((ext_vector_type(4))) float f32x4;

__device__ __forceinline__ unsigned short f2bf(float f) {
  union { float f; unsigned u; } v; v.f = f;
  unsigned r = v.u + 0x7FFFu + ((v.u >> 16) & 1u);
  return (unsigned short)(r >> 16);
}
__device__ __forceinline__ float bf2f(unsigned short s) {
  return __uint_as_float((unsigned)s << 16);
}
__device__ __forceinline__ unsigned enc_ordered(float f) {
  unsigned u = __float_as_uint(f);
  return (u >> 31) ? ~u : (u | 0x80000000u);
}

// p,q (edge affine), c0..c2 (closed-form layer-0 y): 64 threads
__global__ void k_prep_pq(const float* __restrict__ W_el, const float* __restrict__ b_el,
                          const float* __restrict__ W_edge, const float* __restrict__ b_edge,
                          const float* __restrict__ wte,
                          const float* __restrict__ Wi0, const float* __restrict__ bi0,
                          const float* __restrict__ Wi1, const float* __restrict__ bi1,
                          float* __restrict__ p, float* __restrict__ q,
                          float* __restrict__ c0, float* __restrict__ c1,
                          float* __restrict__ c2) {
  int h = threadIdx.x;
  float pp = 0.f, qq = 0.f, s0 = 0.f, s1 = 0.f, s2 = 0.f;
  for (int k = 0; k < 64; ++k) {
    float w2 = W_el[h * 128 + 64 + k];
    pp += w2 * W_edge[k];
    qq += w2 * b_edge[k];
    float w1 = W_el[h * 128 + k];
    float base = wte[k] + wte[64 + k] + bi0[k] + bi1[k];
    s0 += w1 * base;
    s1 += w1 * Wi0[k];
    s2 += w1 * Wi1[k];
  }
  p[h] = pp; q[h] = qq + b_el[h];
  c0[h] = s0; c1[h] = s1; c2[h] = s2;
}

// fused init: x, graph ranges (unique-writer stores), u=0, xu_enc, bf16 weights, deg/cur=0
__global__ void k_init(const float* __restrict__ v0, const float* __restrict__ v1,
                       const float* __restrict__ wte,
                       const float* __restrict__ Wi0, const float* __restrict__ bi0,
                       const float* __restrict__ Wi1, const float* __restrict__ bi1,
                       const int* __restrict__ batch,
                       int* __restrict__ gstart, int* __restrict__ gend,
                       float* __restrict__ x,
                       float* __restrict__ u, unsigned* __restrict__ xu_enc,
                       unsigned short* __restrict__ W1b, unsigned short* __restrict__ W2b,
                       unsigned short* __restrict__ Welb,
                       const float* __restrict__ W_n1, const float* __restrict__ W_n2,
                       const float* __restrict__ W_el,
                       int* __restrict__ deg, int* __restrict__ cur, int N) {
  int gt = blockIdx.x * 256 + threadIdx.x;
  int NH = N * 64;
  if (gt < NH) {
    int n = gt >> 6, h = gt & 63;
    x[gt] = wte[h] + wte[64 + h] + bi0[h] + bi1[h] + v0[n] * Wi0[h] + v1[n] * Wi1[h];
    if (h == 0) {
      int bg = batch[n];
      if (n == 0 || batch[n - 1] != bg) gstart[bg] = n;
      if (n == N - 1 || batch[n + 1] != bg) gend[bg] = n + 1;
    }
    return;
  }
  int i = gt - NH;
  if (i < 4096) {
    u[i] = 0.f;
  } else if (i < 8192) {
    xu_enc[i - 4096] = 0x007FFFFFu;  // enc(-inf)
  } else if (i < 8192 + 49152) {
    int j = i - 8192;                 // W_n1 [256][192]
    W1b[j] = f2bf(W_n1[j]);
  } else if (i < 8192 + 49152 + 16384) {
    int j = i - 57344;                // W_n2 [64][256]
    W2b[j] = f2bf(W_n2[j]);
  } else if (i < 77824) {
    int j = i - 73728;                // W_el[:, :64] compact stride 64
    Welb[j] = f2bf(W_el[(j >> 6) * 128 + (j & 63)]);
  } else if (i < 77824 + N) {
    deg[i - 77824] = 0;
  } else if (i < 77824 + 2 * N) {
    cur[i - 77824 - N] = 0;
  }
}

// ---- CSR build (once per call) ----
__global__ __launch_bounds__(256) void k_hist(const int* __restrict__ eidx,
                                              int* __restrict__ deg, int E) {
  int e = blockIdx.x * 256 + threadIdx.x;
  if (e < E) atomicAdd(&deg[eidx[E + e]], 1);
}

// per-512-chunk inclusive scan (off stays chunk-local; consumers add bsum)
__global__ __launch_bounds__(256) void k_scan1(const int* __restrict__ deg,
                                               int* __restrict__ off,
                                               int* __restrict__ bsum, int N) {
  __shared__ int s[256];
  int b = blockIdx.x, t = threadIdx.x;
  int i0 = b * 512 + t * 2;
  int v0 = (i0 < N) ? deg[i0] : 0;
  int v1 = (i0 + 1 < N) ? deg[i0 + 1] : 0;
  int sum = v0 + v1;
  s[t] = sum;
  __syncthreads();
  for (int d = 1; d < 256; d <<= 1) {
    int val = (t >= d) ? s[t - d] : 0;
    __syncthreads();
    s[t] += val;
    __syncthreads();
  }
  int excl = s[t] - sum;
  if (i0 < N) off[i0] = excl + v0;
  if (i0 + 1 < N) off[i0 + 1] = excl + v0 + v1;
  if (t == 255) bsum[b] = s[t];
}

// exclusive scan of block sums (nb <= 128)
__global__ void k_scan2(int* __restrict__ bsum, int nb) {
  __shared__ int s[128];
  int t = threadIdx.x;
  int v = (t < nb) ? bsum[t] : 0;
  s[t] = v;
  __syncthreads();
  for (int d = 1; d < 128; d <<= 1) {
    int val = (t >= d) ? s[t - d] : 0;
    __syncthreads();
    s[t] += val;
    __syncthreads();
  }
  if (t < nb) bsum[t] = s[t] - v;
}

// spack.x = row | (col&31)<<27 ; spack.y = dist bits
__global__ __launch_bounds__(256) void k_scatter(const int* __restrict__ eidx,
                                                 const float* __restrict__ dist,
                                                 const int* __restrict__ off,
                                                 const int* __restrict__ bsum,
                                                 int* __restrict__ cur,
                                                 uint2* __restrict__ spack, int E) {
  int e = blockIdx.x * 256 + threadIdx.x;
  if (e >= E) return;
  int c = eidx[E + e];
  int base = (c == 0) ? 0 : (off[c - 1] + bsum[(c - 1) >> 9]);
  int pos = base + atomicAdd(&cur[c], 1);
  spack[pos] = make_uint2((unsigned)eidx[e] | ((unsigned)(c & 31) << 27),
                          __float_as_uint(dist[e]));
}

#define PROC(cc, gg)                                                     \
  do {                                                                   \
    int _c = (int)(cc);                                                  \
    if (_c != ccur) {                                                    \
      if (ccur >= 0) atomicMax(&aggi[ccur * 64 + lane], __float_as_int(m)); \
      ccur = _c; m = (gg);                                               \
    } else m = fmaxf(m, (gg));                                           \
  } while (0)

// Fused per-layer kernel. MODE 0: layer0 (y from v0/v1, write y_next)
//                         MODE 1: mid (y gather, write y_next)
//                         MODE 2: last (y gather, fused out-proj, no x store)
template <int MODE>
__global__ __launch_bounds__(256) void k_node(
    const int* __restrict__ off, const int* __restrict__ bsum,
    const uint2* __restrict__ spack,
    const float* __restrict__ p, const float* __restrict__ q,
    const float* __restrict__ c0, const float* __restrict__ c1,
    const float* __restrict__ c2,
    const float* __restrict__ v0, const float* __restrict__ v1,
    float* __restrict__ x, unsigned short* __restrict__ y_bf,
    const int* __restrict__ batch, const float* __restrict__ u,
    const unsigned short* __restrict__ W1b, const unsigned short* __restrict__ W2b,
    const unsigned short* __restrict__ Welb,
    const float* __restrict__ b_n1, const float* __restrict__ b_n2,
    unsigned* __restrict__ xu_enc,
    float* __restrict__ bmaxA, float* __restrict__ bmaxB,
    int* __restrict__ bgidA, int* __restrict__ bgidB,
    const float* __restrict__ Wo0, const float* __restrict__ bo0,
    const float* __restrict__ Wo1, const float* __restrict__ bo1,
    float* __restrict__ outp, int N) {
  __shared__ __align__(16) char inb[32 * 384];  // [32][192] bf16 (xnb aliases)
  __shared__ __align__(16) char h1T[32 * 512];  // [32][256] bf16 (aggT/ow alias)
  __shared__ uint2 smeta[2][128];
  __shared__ int sgb[32];
  int t = threadIdx.x;
  int n0 = blockIdx.x * 32;
  int lane = t & 63, wv = t >> 6;
  int lr = lane & 15;
  int lk8 = (lane >> 4) << 3;
  int jo = (lane >> 4) << 2;
  int swzr = (lr & 7) << 4;
  int h0 = wv * 16 + jo;

  // ---- x read ONCE in stage-2 fragment layout; u gather; sgb ----
  float4 xo[2];
#pragma unroll
  for (int nt = 0; nt < 2; ++nt) {
    int node = n0 + nt * 16 + lr;
    xo[nt] = (node < N) ? *(const float4*)(x + (size_t)node * 64 + h0)
                        : make_float4(0.f, 0.f, 0.f, 0.f);
  }
  int nd_s = t >> 3, ko = t & 7;
  int node_s = n0 + nd_s;
  float4 ua = make_float4(0.f, 0.f, 0.f, 0.f), ub = ua;
  if (node_s < N) {
    int g = batch[node_s];
    const float4* u4 = (const float4*)u;
    ua = u4[g * 16 + ko * 2];
    ub = u4[g * 16 + ko * 2 + 1];
  }
  if (t < 32) sgb[t] = batch[min(n0 + t, N - 1)];
  float pv = p[lane], qv = q[lane];
  float c0v = 0.f, c1v = 0.f, c2v = 0.f;
  if (MODE == 0) { c0v = c0[lane]; c1v = c1[lane]; c2v = c2[lane]; }

  // ---- zero agg tile (aliases h1T) ----
  int* aggi = (int*)h1T;  // [32][64] fp32-as-int, msg >= 0
#pragma unroll
  for (int i = 0; i < 8; ++i) aggi[t + i * 256] = 0;

  // ---- write x (from regs) and u sections of inb ----
#pragma unroll
  for (int nt = 0; nt < 2; ++nt) {
    int nd = nt * 16 + lr;
    unsigned lo = (unsigned)f2bf(xo[nt].x) | ((unsigned)f2bf(xo[nt].y) << 16);
    unsigned hi = (unsigned)f2bf(xo[nt].z) | ((unsigned)f2bf(xo[nt].w) << 16);
    *(uint2*)(inb + nd * 384 + ((128 + h0 * 2) ^ ((nd & 7) << 4))) = make_uint2(lo, hi);
  }
  {
    int swz = (nd_s & 7) << 4;
    uint4 uv;
    uv.x = f2bf(ua.x) | ((unsigned)f2bf(ua.y) << 16);
    uv.y = f2bf(ua.z) | ((unsigned)f2bf(ua.w) << 16);
    uv.z = f2bf(ub.x) | ((unsigned)f2bf(ub.y) << 16);
    uv.w = f2bf(ub.z) | ((unsigned)f2bf(ub.w) << 16);
    *(uint4*)(inb + nd_s * 384 + ((256 + ko * 16) ^ swz)) = uv;
  }

  // ---- stage 0: edge aggregation, dbuf meta, ILP-8 gather, running-max ----
  {
    int last = min(n0 + 31, N - 1);
    int ebase = (n0 == 0) ? 0 : (off[n0 - 1] + bsum[(n0 - 1) >> 9]);
    int eend = off[last] + bsum[last >> 9];
    int total = eend - ebase;
    int nch = (total + 127) >> 7;
    if (t < 128 && t < total) smeta[0][t] = spack[ebase + t];
    float m = 0.f;
    int ccur = -1;
    __syncthreads();
    for (int c = 0; c < nch; ++c) {
      int cb = c << 7;
      int cnt = min(128, total - cb);
      if (c + 1 < nch) {
        int rem = total - cb - 128;
        if (t < 128 && t < rem) smeta[(c + 1) & 1][t] = spack[ebase + cb + 128 + t];
      }
      const uint2* sm = smeta[c & 1];
      int i = wv * 32;
      int i1 = min(i + 32, cnt);
      for (; i + 8 <= i1; i += 8) {
        uint2 e0 = sm[i], e1 = sm[i + 1], e2 = sm[i + 2], e3 = sm[i + 3];
        uint2 e4 = sm[i + 4], e5 = sm[i + 5], e6 = sm[i + 6], e7 = sm[i + 7];
        float y0, y1, y2, y3, y4, y5, y6, y7;
        if (MODE == 0) {
          int r0 = e0.x & 0x07FFFFFFu, r1 = e1.x & 0x07FFFFFFu;
          int r2 = e2.x & 0x07FFFFFFu, r3 = e3.x & 0x07FFFFFFu;
          int r4 = e4.x & 0x07FFFFFFu, r5 = e5.x & 0x07FFFFFFu;
          int r6 = e6.x & 0x07FFFFFFu, r7 = e7.x & 0x07FFFFFFu;
          y0 = fmaf(v1[r0], c2v, fmaf(v0[r0], c1v, c0v));
          y1 = fmaf(v1[r1], c2v, fmaf(v0[r1], c1v, c0v));
          y2 = fmaf(v1[r2], c2v, fmaf(v0[r2], c1v, c0v));
          y3 = fmaf(v1[r3], c2v, fmaf(v0[r3], c1v, c0v));
          y4 = fmaf(v1[r4], c2v, fmaf(v0[r4], c1v, c0v));
          y5 = fmaf(v1[r5], c2v, fmaf(v0[r5], c1v, c0v));
          y6 = fmaf(v1[r6], c2v, fmaf(v0[r6], c1v, c0v));
          y7 = fmaf(v1[r7], c2v, fmaf(v0[r7], c1v, c0v));
        } else {
          y0 = bf2f(y_bf[(int)((e0.x & 0x07FFFFFFu) << 6) + lane]);
          y1 = bf2f(y_bf[(int)((e1.x & 0x07FFFFFFu) << 6) + lane]);
          y2 = bf2f(y_bf[(int)((e2.x & 0x07FFFFFFu) << 6) + lane]);
          y3 = bf2f(y_bf[(int)((e3.x & 0x07FFFFFFu) << 6) + lane]);
          y4 = bf2f(y_bf[(int)((e4.x & 0x07FFFFFFu) << 6) + lane]);
          y5 = bf2f(y_bf[(int)((e5.x & 0x07FFFFFFu) << 6) + lane]);
          y6 = bf2f(y_bf[(int)((e6.x & 0x07FFFFFFu) << 6) + lane]);
          y7 = bf2f(y_bf[(int)((e7.x & 0x07FFFFFFu) << 6) + lane]);
        }
        float g0 = fmaxf(fmaf(__uint_as_float(e0.y), pv, y0 + qv), 0.f);
        float g1 = fmaxf(fmaf(__uint_as_float(e1.y), pv, y1 + qv), 0.f);
        float g2 = fmaxf(fmaf(__uint_as_float(e2.y), pv, y2 + qv), 0.f);
        float g3 = fmaxf(fmaf(__uint_as_float(e3.y), pv, y3 + qv), 0.f);
        float g4 = fmaxf(fmaf(__uint_as_float(e4.y), pv, y4 + qv), 0.f);
        float g5 = fmaxf(fmaf(__uint_as_float(e5.y), pv, y5 + qv), 0.f);
        float g6 = fmaxf(fmaf(__uint_as_float(e6.y), pv, y6 + qv), 0.f);
        float g7 = fmaxf(fmaf(__uint_as_float(e7.y), pv, y7 + qv), 0.f);
        PROC(e0.x >> 27, g0); PROC(e1.x >> 27, g1);
        PROC(e2.x >> 27, g2); PROC(e3.x >> 27, g3);
        PROC(e4.x >> 27, g4); PROC(e5.x >> 27, g5);
        PROC(e6.x >> 27, g6); PROC(e7.x >> 27, g7);
      }
      for (; i < i1; ++i) {
        uint2 e0 = sm[i];
        float y0;
        if (MODE == 0) {
          int r0 = e0.x & 0x07FFFFFFu;
          y0 = fmaf(v1[r0], c2v, fmaf(v0[r0], c1v, c0v));
        } else {
          y0 = bf2f(y_bf[(int)((e0.x & 0x07FFFFFFu) << 6) + lane]);
        }
        float g0 = fmaxf(fmaf(__uint_as_float(e0.y), pv, y0 + qv), 0.f);
        PROC(e0.x >> 27, g0);
      }
      __syncthreads();
    }
    if (ccur >= 0) atomicMax(&aggi[ccur * 64 + lane], __float_as_int(m));
  }
  __syncthreads();

  // ---- agg tile -> inb bf16 (swizzled) ----
  {
    int swz = (nd_s & 7) << 4;
    const float4* ag4 = (const float4*)(h1T);
    float4 aa = ag4[nd_s * 16 + ko * 2];
    float4 ab = ag4[nd_s * 16 + ko * 2 + 1];
    uint4 av;
    av.x = f2bf(aa.x) | ((unsigned)f2bf(aa.y) << 16);
    av.y = f2bf(aa.z) | ((unsigned)f2bf(aa.w) << 16);
    av.z = f2bf(ab.x) | ((unsigned)f2bf(ab.y) << 16);
    av.w = f2bf(ab.z) | ((unsigned)f2bf(ab.w) << 16);
    *(uint4*)(inb + nd_s * 384 + ((ko * 16) ^ swz)) = av;
  }
  __syncthreads();

  int w = wv;

  // ---- stage 1: h1 = relu(W1 @ in^T + b_n1) ----
  f32x4 acc[4][2];
#pragma unroll
  for (int ot = 0; ot < 4; ++ot)
#pragma unroll
    for (int nt = 0; nt < 2; ++nt) acc[ot][nt] = (f32x4){0.f, 0.f, 0.f, 0.f};
  const unsigned short* W1p = W1b + (w * 64 + lr) * 192 + lk8;
#pragma unroll
  for (int ks = 0; ks < 6; ++ks) {
    int kb = ks * 64 + lk8 * 2;
    short8 b0 = *(const short8*)(inb + lr * 384 + (kb ^ swzr));
    short8 b1 = *(const short8*)(inb + (16 + lr) * 384 + (kb ^ swzr));
#pragma unroll
    for (int ot = 0; ot < 4; ++ot) {
      short8 a = *(const short8*)(W1p + ot * (16 * 192) + ks * 32);
      acc[ot][0] = __builtin_amdgcn_mfma_f32_16x16x32_bf16(a, b0, acc[ot][0], 0, 0, 0);
      acc[ot][1] = __builtin_amdgcn_mfma_f32_16x16x32_bf16(a, b1, acc[ot][1], 0, 0, 0);
    }
  }
  __syncthreads();  // aggT fully read; safe to overwrite h1T
#pragma unroll
  for (int ot = 0; ot < 4; ++ot) {
    int o = w * 64 + ot * 16 + jo;
    float4 bs = *(const float4*)(b_n1 + o);
#pragma unroll
    for (int nt = 0; nt < 2; ++nt) {
      int nd = nt * 16 + lr;
      unsigned lo = (unsigned)f2bf(fmaxf(acc[ot][nt][0] + bs.x, 0.f)) |
                    ((unsigned)f2bf(fmaxf(acc[ot][nt][1] + bs.y, 0.f)) << 16);
      unsigned hi = (unsigned)f2bf(fmaxf(acc[ot][nt][2] + bs.z, 0.f)) |
                    ((unsigned)f2bf(fmaxf(acc[ot][nt][3] + bs.w, 0.f)) << 16);
      *(uint2*)(h1T + nd * 512 + ((o * 2) ^ ((nd & 7) << 4))) = make_uint2(lo, hi);
    }
  }
  __syncthreads();

  // ---- stage 2: x_new = x + W2 @ h1^T + b_n2 (x from regs) ----
  f32x4 acc2[2] = {{0.f, 0.f, 0.f, 0.f}, {0.f, 0.f, 0.f, 0.f}};
  const unsigned short* W2p = W2b + (w * 16 + lr) * 256 + lk8;
#pragma unroll
  for (int ks = 0; ks < 8; ++ks) {
    short8 a = *(const short8*)(W2p + ks * 32);
    int kb = ks * 64 + lk8 * 2;
    short8 b0 = *(const short8*)(h1T + lr * 512 + (kb ^ swzr));
    short8 b1 = *(const short8*)(h1T + (16 + lr) * 512 + (kb ^ swzr));
    acc2[0] = __builtin_amdgcn_mfma_f32_16x16x32_bf16(a, b0, acc2[0], 0, 0, 0);
    acc2[1] = __builtin_amdgcn_mfma_f32_16x16x32_bf16(a, b1, acc2[1], 0, 0, 0);
  }
  float4 b2 = *(const float4*)(b_n2 + h0);
  char* xnb = inb;  // alias
  float4 xn[2];
#pragma unroll
  for (int nt = 0; nt < 2; ++nt) {
    int nd = nt * 16 + lr;
    int node = n0 + nd;
    xn[nt].x = xo[nt].x + acc2[nt][0] + b2.x;
    xn[nt].y = xo[nt].y + acc2[nt][1] + b2.y;
    xn[nt].z = xo[nt].z + acc2[nt][2] + b2.z;
    xn[nt].w = xo[nt].w + acc2[nt][3] + b2.w;
    if (node >= N) xn[nt] = make_float4(0.f, 0.f, 0.f, 0.f);
    if (MODE != 2 && node < N) *(float4*)(x + (size_t)node * 64 + h0) = xn[nt];
    if (MODE != 2) {
      unsigned lo = (unsigned)f2bf(xn[nt].x) | ((unsigned)f2bf(xn[nt].y) << 16);
      unsigned hi = (unsigned)f2bf(xn[nt].z) | ((unsigned)f2bf(xn[nt].w) << 16);
      *(uint2*)(xnb + nd * 128 + ((h0 * 2) ^ ((nd & 7) << 4))) = make_uint2(lo, hi);
    }
  }

  // ---- per-graph max partials -> disjoint scratch ----
  {
    const float NEG = -__builtin_huge_valf();
    int gA = sgb[0], gB = sgb[31];
    float a0 = NEG, a1 = NEG, a2 = NEG, a3 = NEG;
    float e0 = NEG, e1 = NEG, e2 = NEG, e3 = NEG;
#pragma unroll
    for (int nt = 0; nt < 2; ++nt) {
      int nd = nt * 16 + lr;
      if (n0 + nd < N) {
        int g = sgb[nd];
        if (g == gA) {
          a0 = fmaxf(a0, xn[nt].x); a1 = fmaxf(a1, xn[nt].y);
          a2 = fmaxf(a2, xn[nt].z); a3 = fmaxf(a3, xn[nt].w);
        } else if (g == gB) {
          e0 = fmaxf(e0, xn[nt].x); e1 = fmaxf(e1, xn[nt].y);
          e2 = fmaxf(e2, xn[nt].z); e3 = fmaxf(e3, xn[nt].w);
        } else {  // >2 graphs in block: rare fallback
          unsigned* xe = xu_enc + g * 64 + h0;
          atomicMax(xe + 0, enc_ordered(xn[nt].x));
          atomicMax(xe + 1, enc_ordered(xn[nt].y));
          atomicMax(xe + 2, enc_ordered(xn[nt].z));
          atomicMax(xe + 3, enc_ordered(xn[nt].w));
        }
      }
    }
#pragma unroll
    for (int msk = 1; msk <= 8; msk <<= 1) {
      a0 = fmaxf(a0, __shfl_xor(a0, msk)); a1 = fmaxf(a1, __shfl_xor(a1, msk));
      a2 = fmaxf(a2, __shfl_xor(a2, msk)); a3 = fmaxf(a3, __shfl_xor(a3, msk));
      e0 = fmaxf(e0, __shfl_xor(e0, msk)); e1 = fmaxf(e1, __shfl_xor(e1, msk));
      e2 = fmaxf(e2, __shfl_xor(e2, msk)); e3 = fmaxf(e3, __shfl_xor(e3, msk));
    }
    if (lr == 0) {
      size_t base = (size_t)blockIdx.x * 64 + h0;
      bmaxA[base + 0] = a0; bmaxA[base + 1] = a1;
      bmaxA[base + 2] = a2; bmaxA[base + 3] = a3;
      bmaxB[base + 0] = e0; bmaxB[base + 1] = e1;
      bmaxB[base + 2] = e2; bmaxB[base + 3] = e3;
    }
    if (t == 0) {
      bgidA[blockIdx.x] = gA;
      bgidB[blockIdx.x] = (gB == gA) ? -1 : gB;
    }
  }
  __syncthreads();

  if (MODE != 2) {
    // ---- stage 3: y_next = Welb @ x_new^T (bf16 out) ----
    f32x4 acc3[2] = {{0.f, 0.f, 0.f, 0.f}, {0.f, 0.f, 0.f, 0.f}};
    const unsigned short* W3p = Welb + (w * 16 + lr) * 64 + lk8;
#pragma unroll
    for (int ks = 0; ks < 2; ++ks) {
      short8 a = *(const short8*)(W3p + ks * 32);
      int kb = ks * 64 + lk8 * 2;
      short8 b0 = *(const short8*)(xnb + lr * 128 + (kb ^ swzr));
      short8 b1 = *(const short8*)(xnb + (16 + lr) * 128 + (kb ^ swzr));
      acc3[0] = __builtin_amdgcn_mfma_f32_16x16x32_bf16(a, b0, acc3[0], 0, 0, 0);
      acc3[1] = __builtin_amdgcn_mfma_f32_16x16x32_bf16(a, b1, acc3[1], 0, 0, 0);
    }
    int o0 = w * 16 + jo;
#pragma unroll
    for (int nt = 0; nt < 2; ++nt) {
      int node = n0 + nt * 16 + lr;
      if (node < N) {
        unsigned lo = (unsigned)f2bf(acc3[nt][0]) | ((unsigned)f2bf(acc3[nt][1]) << 16);
        unsigned hi = (unsigned)f2bf(acc3[nt][2]) | ((unsigned)f2bf(acc3[nt][3]) << 16);
        *(uint2*)(y_bf + (size_t)node * 64 + o0) = make_uint2(lo, hi);
      }
    }
  } else {
    // ---- fused output projection ----
    float4 w0 = *(const float4*)(Wo0 + h0);
    float4 w1 = *(const float4*)(Wo1 + h0);
    float* ow = (float*)h1T;  // [4 waves][2 outs][32 nodes]
#pragma unroll
    for (int nt = 0; nt < 2; ++nt) {
      float p0 = xn[nt].x * w0.x + xn[nt].y * w0.y + xn[nt].z * w0.z + xn[nt].w * w0.w;
      float p1 = xn[nt].x * w1.x + xn[nt].y * w1.y + xn[nt].z * w1.z + xn[nt].w * w1.w;
      p0 += __shfl_xor(p0, 16); p0 += __shfl_xor(p0, 32);
      p1 += __shfl_xor(p1, 16); p1 += __shfl_xor(p1, 32);
      if (lane < 16) {
        ow[w * 64 + 0 + nt * 16 + lr] = p0;
        ow[w * 64 + 32 + nt * 16 + lr] = p1;
      }
    }
    __syncthreads();
    if (t < 64) {
      int oi = t >> 5, nd = t & 31;
      int node = n0 + nd;
      if (node < N) {
        float v = ow[0 * 64 + oi * 32 + nd] + ow[1 * 64 + oi * 32 + nd] +
                  ow[2 * 64 + oi * 32 + nd] + ow[3 * 64 + oi * 32 + nd];
        v += (oi ? bo1[0] : bo0[0]);
        outp[(size_t)oi * N + node] = v;
      }
    }
  }
}

// per-graph: reduce block partials, u update, LSTM, reset xu_enc fallback
__global__ __launch_bounds__(64) void k_graph(const int* __restrict__ gstart,
                                              const int* __restrict__ gend,
                                              const float* __restrict__ bmaxA,
                                              const float* __restrict__ bmaxB,
                                              const int* __restrict__ bgidA,
                                              const int* __restrict__ bgidB,
                                              unsigned* __restrict__ xu_enc,
                                              float* __restrict__ u,
                                              const float* __restrict__ W_gl,
                                              const float* __restrict__ b_gl,
                                              const float* __restrict__ W_ih,
                                              const float* __restrict__ b_ih,
                                              const float* __restrict__ b_hh,
                                              float* __restrict__ c_out) {
  __shared__ float xu_s[64], us[64], un[64];
  int g = blockIdx.x, h = threadIdx.x;
  float m = -__builtin_huge_valf();
  int gs = gstart[g], ge = gend[g];
  if (gs < ge) {
    int bs = gs >> 5, be = (ge - 1) >> 5;
    for (int b = bs; b <= be; ++b) {
      if (bgidA[b] == g) m = fmaxf(m, bmaxA[(size_t)b * 64 + h]);
      if (bgidB[b] == g) m = fmaxf(m, bmaxB[(size_t)b * 64 + h]);
    }
  }
  {  // fallback decode + reset
    unsigned Ev = xu_enc[g * 64 + h];
    float fd = (Ev & 0x80000000u) ? __uint_as_float(Ev & 0x7FFFFFFFu)
                                  : __uint_as_float(~Ev);
    m = fmaxf(m, fd);
    xu_enc[g * 64 + h] = 0x007FFFFFu;
  }
  float f = isfinite(m) ? m : 0.f;
  xu_s[h] = f;
  float uo = u[g * 64 + h];
  us[h] = uo;
  __syncthreads();
  float pre = b_gl[h];
  for (int k = 0; k < 64; ++k) pre += xu_s[k] * W_gl[h * 128 + k];
  for (int k = 0; k < 64; ++k) pre += us[k] * W_gl[h * 128 + 64 + k];
  float unew = uo + fmaxf(pre, 0.f);
  un[h] = unew;
  __syncthreads();
  float gi = b_ih[h] + b_hh[h];
  float gg = b_ih[128 + h] + b_hh[128 + h];
  float go = b_ih[192 + h] + b_hh[192 + h];
  for (int k = 0; k < 64; ++k) {
    float uv = un[k];
    gi += uv * W_ih[h * 64 + k];
    gg += uv * W_ih[(128 + h) * 64 + k];
    go += uv * W_ih[(192 + h) * 64 + k];
  }
  float cc = (1.f / (1.f + expf(-gi))) * tanhf(gg);
  float u2v = (1.f / (1.f + expf(-go))) * tanhf(cc);
  c_out[g * 64 + h] = cc;
  u[g * 64 + h] = u2v;
}

extern "C" void kernel_launch(void* const* d_in, const int* in_sizes, int n_in,
                              void* d_out, int out_size, void* d_ws, size_t ws_size,
                              hipStream_t stream) {
  const float* v0 = (const float*)d_in[0];
  const float* v1 = (const float*)d_in[1];
  const float* dist = (const float*)d_in[2];
  const int* eidx = (const int*)d_in[3];
  const int* batch = (const int*)d_in[4];
  const float* wte = (const float*)d_in[6];
  const float* Wi0 = (const float*)d_in[7];
  const float* bi0 = (const float*)d_in[8];
  const float* Wi1 = (const float*)d_in[9];
  const float* bi1 = (const float*)d_in[10];
  const float* Wo0 = (const float*)d_in[11];
  const float* bo0 = (const float*)d_in[12];
  const float* Wo1 = (const float*)d_in[13];
  const float* bo1 = (const float*)d_in[14];
  const float* W_edge = (const float*)d_in[15];
  const float* b_edge = (const float*)d_in[16];
  const float* W_el = (const float*)d_in[17];
  const float* b_el = (const float*)d_in[18];
  const float* W_n1 = (const float*)d_in[19];
  const float* b_n1 = (const float*)d_in[20];
  const float* W_n2 = (const float*)d_in[21];
  const float* b_n2 = (const float*)d_in[22];
  const float* W_gl = (const float*)d_in[23];
  const float* b_gl = (const float*)d_in[24];
  const float* W_ih = (const float*)d_in[25];
  const float* b_ih = (const float*)d_in[27];
  const float* b_hh = (const float*)d_in[28];

  const int N = in_sizes[0];
  const int E = in_sizes[2];
  const int NH = N * 64;
  const int NB512 = (N + 511) / 512;
  const int nblk = (N + 31) / 32;

  float* ws = (float*)d_ws;
  float* x = ws;                                   // NH
  float* u = x + NH;                               // 4096
  unsigned* xu_enc = (unsigned*)(u + 4096);        // 4096
  float* p = (float*)(xu_enc + 4096);
  float* q = p + 64;
  float* c0 = q + 64;
  float* c1 = c0 + 64;
  float* c2 = c1 + 64;
  unsigned short* W1b = (unsigned short*)(c2 + 64);  // 49152
  unsigned short* W2b = W1b + 49152;                 // 16384
  unsigned short* Welb = W2b + 16384;                // 4096
  unsigned short* y_bf = Welb + 4096;                // NH
  int* deg = (int*)(y_bf + NH);                      // N
  int* off = deg + N;                                // N
  int* cur = off + N;                                // N
  int* bsum = cur + N;                               // 128
  int* gstart = bsum + 128;                          // 64
  int* gend = gstart + 64;                           // 64
  int* bgidA = gend + 64;                            // nblk
  int* bgidB = bgidA + nblk;                         // nblk
  float* bmaxA = (float*)(bgidB + nblk);             // nblk*64
  float* bmaxB = bmaxA + (size_t)nblk * 64;          // nblk*64
  uint2* spack = (uint2*)(((size_t)(bmaxB + (size_t)nblk * 64) + 15) & ~(size_t)15);  // E

  float* outp = (float*)d_out;

  k_prep_pq<<<1, 64, 0, stream>>>(W_el, b_el, W_edge, b_edge, wte, Wi0, bi0, Wi1, bi1,
                                  p, q, c0, c1, c2);
  k_init<<<(NH + 77824 + 2 * N + 255) / 256, 256, 0, stream>>>(
      v0, v1, wte, Wi0, bi0, Wi1, bi1, batch, gstart, gend, x,
      u, xu_enc, W1b, W2b, Welb, W_n1, W_n2, W_el, deg, cur, N);
  k_hist<<<(E + 255) / 256, 256, 0, stream>>>(eidx, deg, E);
  k_scan1<<<NB512, 256, 0, stream>>>(deg, off, bsum, N);
  k_scan2<<<1, 128, 0, stream>>>(bsum, NB512);
  k_scatter<<<(E + 255) / 256, 256, 0, stream>>>(eidx, dist, off, bsum, cur, spack, E);

  for (int l = 0; l < 4; ++l) {
    if (l == 0) {
      k_node<0><<<nblk, 256, 0, stream>>>(off, bsum, spack, p, q, c0, c1, c2, v0, v1,
                                          x, y_bf, batch, u, W1b, W2b, Welb, b_n1, b_n2,
                                          xu_enc, bmaxA, bmaxB, bgidA, bgidB,
                                          Wo0, bo0, Wo1, bo1, outp, N);
    } else if (l < 3) {
      k_node<1><<<nblk, 256, 0, stream>>>(off, bsum, spack, p, q, c0, c1, c2, v0, v1,
                                          x, y_bf, batch, u, W1b, W2b, Welb, b_n1, b_n2,
                                          xu_enc, bmaxA, bmaxB, bgidA, bgidB,
                                          Wo0, bo0, Wo1, bo1, outp, N);
    } else {
      k_node<2><<<nblk, 256, 0, stream>>>(off, bsum, spack, p, q, c0, c1, c2, v0, v1,
                                          x, y_bf, batch, u, W1b, W2b, Welb, b_n1, b_n2,
                                          xu_enc, bmaxA, bmaxB, bgidA, bgidB,
                                          Wo0, bo0, Wo1, bo1, outp, N);
    }
    k_graph<<<64, 64, 0, stream>>>(gstart, gend, bmaxA, bmaxB, bgidA, bgidB,
                                   xu_enc, u, W_gl, b_gl, W_ih, b_ih, b_hh,
                                   outp + 2 * N + l * 4096);
  }
}

// Round 8
// 337.501 us; speedup vs baseline: 3.2032x; 1.0979x over previous
//
#include <hip/hip_runtime.h>

// GraphTemporal: N=50000, E=500000, B=64, H=64, L=4 shared layers.
// msg = relu(y[row] + dist*p + q), y = x @ W_el[:, :64].T
// Layer 0: y computed on the fly from v0,v1 (rank-2 closed form) - no y gather.
// Edges CSR-sorted by destination; aggregation fused into k_node stage 0:
//   per-wave contiguous edge quarters, wave-private LDS meta slice (reg-dbuf
//   prefetch), ILP-8 y gather, register running-max -> barrier-free stage 0.
// x read ONCE per block in stage-2 fragment layout (regs).
// Per-graph max via disjoint per-block scratch reduced in k_graph (256 thr).

typedef __attribute__((ext_vector_type(8))) short short8;
typedef __attribute__((ext_vector_type(4))) float f32x4;

__device__ __forceinline__ unsigned short f2bf(float f) {
  union { float f; unsigned u; } v; v.f = f;
  unsigned r = v.u + 0x7FFFu + ((v.u >> 16) & 1u);
  return (unsigned short)(r >> 16);
}
__device__ __forceinline__ float bf2f(unsigned short s) {
  return __uint_as_float((unsigned)s << 16);
}
__device__ __forceinline__ unsigned enc_ordered(float f) {
  unsigned u = __float_as_uint(f);
  return (u >> 31) ? ~u : (u | 0x80000000u);
}

// p,q (edge affine), c0..c2 (closed-form layer-0 y): 64 threads
__global__ void k_prep_pq(const float* __restrict__ W_el, const float* __restrict__ b_el,
                          const float* __restrict__ W_edge, const float* __restrict__ b_edge,
                          const float* __restrict__ wte,
                          const float* __restrict__ Wi0, const float* __restrict__ bi0,
                          const float* __restrict__ Wi1, const float* __restrict__ bi1,
                          float* __restrict__ p, float* __restrict__ q,
                          float* __restrict__ c0, float* __restrict__ c1,
                          float* __restrict__ c2) {
  int h = threadIdx.x;
  float pp = 0.f, qq = 0.f, s0 = 0.f, s1 = 0.f, s2 = 0.f;
  for (int k = 0; k < 64; ++k) {
    float w2 = W_el[h * 128 + 64 + k];
    pp += w2 * W_edge[k];
    qq += w2 * b_edge[k];
    float w1 = W_el[h * 128 + k];
    float base = wte[k] + wte[64 + k] + bi0[k] + bi1[k];
    s0 += w1 * base;
    s1 += w1 * Wi0[k];
    s2 += w1 * Wi1[k];
  }
  p[h] = pp; q[h] = qq + b_el[h];
  c0[h] = s0; c1[h] = s1; c2[h] = s2;
}

// fused init: x, graph ranges, u=0, xu_enc, bf16 weights, deg/cur=0
__global__ void k_init(const float* __restrict__ v0, const float* __restrict__ v1,
                       const float* __restrict__ wte,
                       const float* __restrict__ Wi0, const float* __restrict__ bi0,
                       const float* __restrict__ Wi1, const float* __restrict__ bi1,
                       const int* __restrict__ batch,
                       int* __restrict__ gstart, int* __restrict__ gend,
                       float* __restrict__ x,
                       float* __restrict__ u, unsigned* __restrict__ xu_enc,
                       unsigned short* __restrict__ W1b, unsigned short* __restrict__ W2b,
                       unsigned short* __restrict__ Welb,
                       const float* __restrict__ W_n1, const float* __restrict__ W_n2,
                       const float* __restrict__ W_el,
                       int* __restrict__ deg, int* __restrict__ cur, int N) {
  int gt = blockIdx.x * 256 + threadIdx.x;
  int NH = N * 64;
  if (gt < NH) {
    int n = gt >> 6, h = gt & 63;
    x[gt] = wte[h] + wte[64 + h] + bi0[h] + bi1[h] + v0[n] * Wi0[h] + v1[n] * Wi1[h];
    if (h == 0) {
      int bg = batch[n];
      if (n == 0 || batch[n - 1] != bg) gstart[bg] = n;
      if (n == N - 1 || batch[n + 1] != bg) gend[bg] = n + 1;
    }
    return;
  }
  int i = gt - NH;
  if (i < 4096) {
    u[i] = 0.f;
  } else if (i < 8192) {
    xu_enc[i - 4096] = 0x007FFFFFu;  // enc(-inf)
  } else if (i < 8192 + 49152) {
    int j = i - 8192;                 // W_n1 [256][192]
    W1b[j] = f2bf(W_n1[j]);
  } else if (i < 8192 + 49152 + 16384) {
    int j = i - 57344;                // W_n2 [64][256]
    W2b[j] = f2bf(W_n2[j]);
  } else if (i < 77824) {
    int j = i - 73728;                // W_el[:, :64] compact stride 64
    Welb[j] = f2bf(W_el[(j >> 6) * 128 + (j & 63)]);
  } else if (i < 77824 + N) {
    deg[i - 77824] = 0;
  } else if (i < 77824 + 2 * N) {
    cur[i - 77824 - N] = 0;
  }
}

// ---- CSR build (once per call) ----
__global__ __launch_bounds__(256) void k_hist(const int* __restrict__ eidx,
                                              int* __restrict__ deg, int E) {
  int e = blockIdx.x * 256 + threadIdx.x;
  if (e < E) atomicAdd(&deg[eidx[E + e]], 1);
}

// per-512-chunk inclusive scan (off stays chunk-local; consumers add bsum)
__global__ __launch_bounds__(256) void k_scan1(const int* __restrict__ deg,
                                               int* __restrict__ off,
                                               int* __restrict__ bsum, int N) {
  __shared__ int s[256];
  int b = blockIdx.x, t = threadIdx.x;
  int i0 = b * 512 + t * 2;
  int v0 = (i0 < N) ? deg[i0] : 0;
  int v1 = (i0 + 1 < N) ? deg[i0 + 1] : 0;
  int sum = v0 + v1;
  s[t] = sum;
  __syncthreads();
  for (int d = 1; d < 256; d <<= 1) {
    int val = (t >= d) ? s[t - d] : 0;
    __syncthreads();
    s[t] += val;
    __syncthreads();
  }
  int excl = s[t] - sum;
  if (i0 < N) off[i0] = excl + v0;
  if (i0 + 1 < N) off[i0 + 1] = excl + v0 + v1;
  if (t == 255) bsum[b] = s[t];
}

// exclusive scan of block sums (nb <= 128)
__global__ void k_scan2(int* __restrict__ bsum, int nb) {
  __shared__ int s[128];
  int t = threadIdx.x;
  int v = (t < nb) ? bsum[t] : 0;
  s[t] = v;
  __syncthreads();
  for (int d = 1; d < 128; d <<= 1) {
    int val = (t >= d) ? s[t - d] : 0;
    __syncthreads();
    s[t] += val;
    __syncthreads();
  }
  if (t < nb) bsum[t] = s[t] - v;
}

// spack.x = row | (col&31)<<27 ; spack.y = dist bits
__global__ __launch_bounds__(256) void k_scatter(const int* __restrict__ eidx,
                                                 const float* __restrict__ dist,
                                                 const int* __restrict__ off,
                                                 const int* __restrict__ bsum,
                                                 int* __restrict__ cur,
                                                 uint2* __restrict__ spack, int E) {
  int e = blockIdx.x * 256 + threadIdx.x;
  if (e >= E) return;
  int c = eidx[E + e];
  int base = (c == 0) ? 0 : (off[c - 1] + bsum[(c - 1) >> 9]);
  int pos = base + atomicAdd(&cur[c], 1);
  spack[pos] = make_uint2((unsigned)eidx[e] | ((unsigned)(c & 31) << 27),
                          __float_as_uint(dist[e]));
}

#define PROC(cc, gg)                                                     \
  do {                                                                   \
    int _c = (int)(cc);                                                  \
    if (_c != ccur) {                                                    \
      if (ccur >= 0) atomicMax(&aggi[ccur * 64 + lane], __float_as_int(m)); \
      ccur = _c; m = (gg);                                               \
    } else m = fmaxf(m, (gg));                                           \
  } while (0)

// Fused per-layer kernel. MODE 0: layer0 (y from v0/v1, write y_next)
//                         MODE 1: mid (y gather, write y_next)
//                         MODE 2: last (y gather, fused out-proj, no x store)
template <int MODE>
__global__ __launch_bounds__(256) void k_node(
    const int* __restrict__ off, const int* __restrict__ bsum,
    const uint2* __restrict__ spack,
    const float* __restrict__ p, const float* __restrict__ q,
    const float* __restrict__ c0, const float* __restrict__ c1,
    const float* __restrict__ c2,
    const float* __restrict__ v0, const float* __restrict__ v1,
    float* __restrict__ x, unsigned short* __restrict__ y_bf,
    const int* __restrict__ batch, const float* __restrict__ u,
    const unsigned short* __restrict__ W1b, const unsigned short* __restrict__ W2b,
    const unsigned short* __restrict__ Welb,
    const float* __restrict__ b_n1, const float* __restrict__ b_n2,
    unsigned* __restrict__ xu_enc,
    float* __restrict__ bmaxA, float* __restrict__ bmaxB,
    int* __restrict__ bgidA, int* __restrict__ bgidB,
    const float* __restrict__ Wo0, const float* __restrict__ bo0,
    const float* __restrict__ Wo1, const float* __restrict__ bo1,
    float* __restrict__ outp, int N) {
  __shared__ __align__(16) char inb[32 * 384];  // [32][192] bf16 (xnb aliases)
  __shared__ __align__(16) char h1T[32 * 512];  // [32][256] bf16 (aggT/ow alias)
  __shared__ uint2 smeta[256];                  // 4 waves x 64 private slices
  __shared__ int sgb[32];
  int t = threadIdx.x;
  int n0 = blockIdx.x * 32;
  int lane = t & 63, wv = t >> 6;
  int lr = lane & 15;
  int lk8 = (lane >> 4) << 3;
  int jo = (lane >> 4) << 2;
  int swzr = (lr & 7) << 4;
  int h0 = wv * 16 + jo;

  // ---- x read ONCE in stage-2 fragment layout; u gather; sgb ----
  float4 xo[2];
#pragma unroll
  for (int nt = 0; nt < 2; ++nt) {
    int node = n0 + nt * 16 + lr;
    xo[nt] = (node < N) ? *(const float4*)(x + (size_t)node * 64 + h0)
                        : make_float4(0.f, 0.f, 0.f, 0.f);
  }
  int nd_s = t >> 3, ko = t & 7;
  int node_s = n0 + nd_s;
  float4 ua = make_float4(0.f, 0.f, 0.f, 0.f), ub = ua;
  if (node_s < N) {
    int g = batch[node_s];
    const float4* u4 = (const float4*)u;
    ua = u4[g * 16 + ko * 2];
    ub = u4[g * 16 + ko * 2 + 1];
  }
  if (t < 32) sgb[t] = batch[min(n0 + t, N - 1)];
  float pv = p[lane], qv = q[lane];
  float c0v = 0.f, c1v = 0.f, c2v = 0.f;
  if (MODE == 0) { c0v = c0[lane]; c1v = c1[lane]; c2v = c2[lane]; }

  // ---- zero agg tile (aliases h1T) ----
  int* aggi = (int*)h1T;  // [32][64] fp32-as-int, msg >= 0
#pragma unroll
  for (int i = 0; i < 8; ++i) aggi[t + i * 256] = 0;

  // ---- write x (from regs) and u sections of inb ----
#pragma unroll
  for (int nt = 0; nt < 2; ++nt) {
    int nd = nt * 16 + lr;
    unsigned lo = (unsigned)f2bf(xo[nt].x) | ((unsigned)f2bf(xo[nt].y) << 16);
    unsigned hi = (unsigned)f2bf(xo[nt].z) | ((unsigned)f2bf(xo[nt].w) << 16);
    *(uint2*)(inb + nd * 384 + ((128 + h0 * 2) ^ ((nd & 7) << 4))) = make_uint2(lo, hi);
  }
  {
    int swz = (nd_s & 7) << 4;
    uint4 uv;
    uv.x = f2bf(ua.x) | ((unsigned)f2bf(ua.y) << 16);
    uv.y = f2bf(ua.z) | ((unsigned)f2bf(ua.w) << 16);
    uv.z = f2bf(ub.x) | ((unsigned)f2bf(ub.y) << 16);
    uv.w = f2bf(ub.z) | ((unsigned)f2bf(ub.w) << 16);
    *(uint4*)(inb + nd_s * 384 + ((256 + ko * 16) ^ swz)) = uv;
  }
  __syncthreads();  // aggi zeroed before any wave aggregates

  // ---- stage 0: BARRIER-FREE per-wave edge aggregation ----
  {
    int last = min(n0 + 31, N - 1);
    int ebase = (n0 == 0) ? 0 : (off[n0 - 1] + bsum[(n0 - 1) >> 9]);
    int eend = off[last] + bsum[last >> 9];
    int total = eend - ebase;
    int q4 = total >> 2;
    int wb = ebase + wv * q4;
    int we = (wv == 3) ? eend : (wb + q4);
    uint2* sm = smeta + wv * 64;   // wave-private slice
    const unsigned short* ybl = y_bf + lane;
    float m = 0.f;
    int ccur = -1;
    uint2 r = make_uint2(0u, 0u);
    if (wb < we) {
      int cnt = min(64, we - wb);
      if (lane < cnt) r = spack[wb + lane];
    }
    for (int cb = wb; cb < we; cb += 64) {
      int ccnt = min(64, we - cb);
      sm[lane] = r;
      int nb = cb + 64;
      if (nb < we) {
        int ncnt = we - nb;
        if (lane < ncnt) r = spack[nb + lane];  // prefetch next chunk to regs
      }
      int i = 0;
      for (; i + 8 <= ccnt; i += 8) {
        uint2 e0 = sm[i], e1 = sm[i + 1], e2 = sm[i + 2], e3 = sm[i + 3];
        uint2 e4 = sm[i + 4], e5 = sm[i + 5], e6 = sm[i + 6], e7 = sm[i + 7];
        float y0, y1, y2, y3, y4, y5, y6, y7;
        if (MODE == 0) {
          int r0 = e0.x & 0x07FFFFFFu, r1 = e1.x & 0x07FFFFFFu;
          int r2 = e2.x & 0x07FFFFFFu, r3 = e3.x & 0x07FFFFFFu;
          int r4 = e4.x & 0x07FFFFFFu, r5 = e5.x & 0x07FFFFFFu;
          int r6 = e6.x & 0x07FFFFFFu, r7 = e7.x & 0x07FFFFFFu;
          y0 = fmaf(v1[r0], c2v, fmaf(v0[r0], c1v, c0v));
          y1 = fmaf(v1[r1], c2v, fmaf(v0[r1], c1v, c0v));
          y2 = fmaf(v1[r2], c2v, fmaf(v0[r2], c1v, c0v));
          y3 = fmaf(v1[r3], c2v, fmaf(v0[r3], c1v, c0v));
          y4 = fmaf(v1[r4], c2v, fmaf(v0[r4], c1v, c0v));
          y5 = fmaf(v1[r5], c2v, fmaf(v0[r5], c1v, c0v));
          y6 = fmaf(v1[r6], c2v, fmaf(v0[r6], c1v, c0v));
          y7 = fmaf(v1[r7], c2v, fmaf(v0[r7], c1v, c0v));
        } else {
          y0 = bf2f(ybl[(int)((e0.x & 0x07FFFFFFu) << 6)]);
          y1 = bf2f(ybl[(int)((e1.x & 0x07FFFFFFu) << 6)]);
          y2 = bf2f(ybl[(int)((e2.x & 0x07FFFFFFu) << 6)]);
          y3 = bf2f(ybl[(int)((e3.x & 0x07FFFFFFu) << 6)]);
          y4 = bf2f(ybl[(int)((e4.x & 0x07FFFFFFu) << 6)]);
          y5 = bf2f(ybl[(int)((e5.x & 0x07FFFFFFu) << 6)]);
          y6 = bf2f(ybl[(int)((e6.x & 0x07FFFFFFu) << 6)]);
          y7 = bf2f(ybl[(int)((e7.x & 0x07FFFFFFu) << 6)]);
        }
        float g0 = fmaxf(fmaf(__uint_as_float(e0.y), pv, y0 + qv), 0.f);
        float g1 = fmaxf(fmaf(__uint_as_float(e1.y), pv, y1 + qv), 0.f);
        float g2 = fmaxf(fmaf(__uint_as_float(e2.y), pv, y2 + qv), 0.f);
        float g3 = fmaxf(fmaf(__uint_as_float(e3.y), pv, y3 + qv), 0.f);
        float g4 = fmaxf(fmaf(__uint_as_float(e4.y), pv, y4 + qv), 0.f);
        float g5 = fmaxf(fmaf(__uint_as_float(e5.y), pv, y5 + qv), 0.f);
        float g6 = fmaxf(fmaf(__uint_as_float(e6.y), pv, y6 + qv), 0.f);
        float g7 = fmaxf(fmaf(__uint_as_float(e7.y), pv, y7 + qv), 0.f);
        PROC(e0.x >> 27, g0); PROC(e1.x >> 27, g1);
        PROC(e2.x >> 27, g2); PROC(e3.x >> 27, g3);
        PROC(e4.x >> 27, g4); PROC(e5.x >> 27, g5);
        PROC(e6.x >> 27, g6); PROC(e7.x >> 27, g7);
      }
      for (; i < ccnt; ++i) {
        uint2 e0 = sm[i];
        float y0;
        if (MODE == 0) {
          int r0 = e0.x & 0x07FFFFFFu;
          y0 = fmaf(v1[r0], c2v, fmaf(v0[r0], c1v, c0v));
        } else {
          y0 = bf2f(ybl[(int)((e0.x & 0x07FFFFFFu) << 6)]);
        }
        float g0 = fmaxf(fmaf(__uint_as_float(e0.y), pv, y0 + qv), 0.f);
        PROC(e0.x >> 27, g0);
      }
    }
    if (ccur >= 0) atomicMax(&aggi[ccur * 64 + lane], __float_as_int(m));
  }
  __syncthreads();

  // ---- agg tile -> inb bf16 (swizzled) ----
  {
    int swz = (nd_s & 7) << 4;
    const float4* ag4 = (const float4*)(h1T);
    float4 aa = ag4[nd_s * 16 + ko * 2];
    float4 ab = ag4[nd_s * 16 + ko * 2 + 1];
    uint4 av;
    av.x = f2bf(aa.x) | ((unsigned)f2bf(aa.y) << 16);
    av.y = f2bf(aa.z) | ((unsigned)f2bf(aa.w) << 16);
    av.z = f2bf(ab.x) | ((unsigned)f2bf(ab.y) << 16);
    av.w = f2bf(ab.z) | ((unsigned)f2bf(ab.w) << 16);
    *(uint4*)(inb + nd_s * 384 + ((ko * 16) ^ swz)) = av;
  }
  __syncthreads();

  int w = wv;

  // ---- stage 1: h1 = relu(W1 @ in^T + b_n1) ----
  f32x4 acc[4][2];
#pragma unroll
  for (int ot = 0; ot < 4; ++ot)
#pragma unroll
    for (int nt = 0; nt < 2; ++nt) acc[ot][nt] = (f32x4){0.f, 0.f, 0.f, 0.f};
  const unsigned short* W1p = W1b + (w * 64 + lr) * 192 + lk8;
#pragma unroll
  for (int ks = 0; ks < 6; ++ks) {
    int kb = ks * 64 + lk8 * 2;
    short8 b0 = *(const short8*)(inb + lr * 384 + (kb ^ swzr));
    short8 b1 = *(const short8*)(inb + (16 + lr) * 384 + (kb ^ swzr));
#pragma unroll
    for (int ot = 0; ot < 4; ++ot) {
      short8 a = *(const short8*)(W1p + ot * (16 * 192) + ks * 32);
      acc[ot][0] = __builtin_amdgcn_mfma_f32_16x16x32_bf16(a, b0, acc[ot][0], 0, 0, 0);
      acc[ot][1] = __builtin_amdgcn_mfma_f32_16x16x32_bf16(a, b1, acc[ot][1], 0, 0, 0);
    }
  }
  __syncthreads();  // aggT fully read; safe to overwrite h1T
#pragma unroll
  for (int ot = 0; ot < 4; ++ot) {
    int o = w * 64 + ot * 16 + jo;
    float4 bs = *(const float4*)(b_n1 + o);
#pragma unroll
    for (int nt = 0; nt < 2; ++nt) {
      int nd = nt * 16 + lr;
      unsigned lo = (unsigned)f2bf(fmaxf(acc[ot][nt][0] + bs.x, 0.f)) |
                    ((unsigned)f2bf(fmaxf(acc[ot][nt][1] + bs.y, 0.f)) << 16);
      unsigned hi = (unsigned)f2bf(fmaxf(acc[ot][nt][2] + bs.z, 0.f)) |
                    ((unsigned)f2bf(fmaxf(acc[ot][nt][3] + bs.w, 0.f)) << 16);
      *(uint2*)(h1T + nd * 512 + ((o * 2) ^ ((nd & 7) << 4))) = make_uint2(lo, hi);
    }
  }
  __syncthreads();

  // ---- stage 2: x_new = x + W2 @ h1^T + b_n2 (x from regs) ----
  f32x4 acc2[2] = {{0.f, 0.f, 0.f, 0.f}, {0.f, 0.f, 0.f, 0.f}};
  const unsigned short* W2p = W2b + (w * 16 + lr) * 256 + lk8;
#pragma unroll
  for (int ks = 0; ks < 8; ++ks) {
    short8 a = *(const short8*)(W2p + ks * 32);
    int kb = ks * 64 + lk8 * 2;
    short8 b0 = *(const short8*)(h1T + lr * 512 + (kb ^ swzr));
    short8 b1 = *(const short8*)(h1T + (16 + lr) * 512 + (kb ^ swzr));
    acc2[0] = __builtin_amdgcn_mfma_f32_16x16x32_bf16(a, b0, acc2[0], 0, 0, 0);
    acc2[1] = __builtin_amdgcn_mfma_f32_16x16x32_bf16(a, b1, acc2[1], 0, 0, 0);
  }
  float4 b2 = *(const float4*)(b_n2 + h0);
  char* xnb = inb;  // alias
  float4 xn[2];
#pragma unroll
  for (int nt = 0; nt < 2; ++nt) {
    int nd = nt * 16 + lr;
    int node = n0 + nd;
    xn[nt].x = xo[nt].x + acc2[nt][0] + b2.x;
    xn[nt].y = xo[nt].y + acc2[nt][1] + b2.y;
    xn[nt].z = xo[nt].z + acc2[nt][2] + b2.z;
    xn[nt].w = xo[nt].w + acc2[nt][3] + b2.w;
    if (node >= N) xn[nt] = make_float4(0.f, 0.f, 0.f, 0.f);
    if (MODE != 2 && node < N) *(float4*)(x + (size_t)node * 64 + h0) = xn[nt];
    if (MODE != 2) {
      unsigned lo = (unsigned)f2bf(xn[nt].x) | ((unsigned)f2bf(xn[nt].y) << 16);
      unsigned hi = (unsigned)f2bf(xn[nt].z) | ((unsigned)f2bf(xn[nt].w) << 16);
      *(uint2*)(xnb + nd * 128 + ((h0 * 2) ^ ((nd & 7) << 4))) = make_uint2(lo, hi);
    }
  }

  // ---- per-graph max partials -> disjoint scratch ----
  {
    const float NEG = -__builtin_huge_valf();
    int gA = sgb[0], gB = sgb[31];
    float a0 = NEG, a1 = NEG, a2 = NEG, a3 = NEG;
    float e0 = NEG, e1 = NEG, e2 = NEG, e3 = NEG;
#pragma unroll
    for (int nt = 0; nt < 2; ++nt) {
      int nd = nt * 16 + lr;
      if (n0 + nd < N) {
        int g = sgb[nd];
        if (g == gA) {
          a0 = fmaxf(a0, xn[nt].x); a1 = fmaxf(a1, xn[nt].y);
          a2 = fmaxf(a2, xn[nt].z); a3 = fmaxf(a3, xn[nt].w);
        } else if (g == gB) {
          e0 = fmaxf(e0, xn[nt].x); e1 = fmaxf(e1, xn[nt].y);
          e2 = fmaxf(e2, xn[nt].z); e3 = fmaxf(e3, xn[nt].w);
        } else {  // >2 graphs in block: rare fallback
          unsigned* xe = xu_enc + g * 64 + h0;
          atomicMax(xe + 0, enc_ordered(xn[nt].x));
          atomicMax(xe + 1, enc_ordered(xn[nt].y));
          atomicMax(xe + 2, enc_ordered(xn[nt].z));
          atomicMax(xe + 3, enc_ordered(xn[nt].w));
        }
      }
    }
#pragma unroll
    for (int msk = 1; msk <= 8; msk <<= 1) {
      a0 = fmaxf(a0, __shfl_xor(a0, msk)); a1 = fmaxf(a1, __shfl_xor(a1, msk));
      a2 = fmaxf(a2, __shfl_xor(a2, msk)); a3 = fmaxf(a3, __shfl_xor(a3, msk));
      e0 = fmaxf(e0, __shfl_xor(e0, msk)); e1 = fmaxf(e1, __shfl_xor(e1, msk));
      e2 = fmaxf(e2, __shfl_xor(e2, msk)); e3 = fmaxf(e3, __shfl_xor(e3, msk));
    }
    if (lr == 0) {
      size_t base = (size_t)blockIdx.x * 64 + h0;
      bmaxA[base + 0] = a0; bmaxA[base + 1] = a1;
      bmaxA[base + 2] = a2; bmaxA[base + 3] = a3;
      bmaxB[base + 0] = e0; bmaxB[base + 1] = e1;
      bmaxB[base + 2] = e2; bmaxB[base + 3] = e3;
    }
    if (t == 0) {
      bgidA[blockIdx.x] = gA;
      bgidB[blockIdx.x] = (gB == gA) ? -1 : gB;
    }
  }
  __syncthreads();

  if (MODE != 2) {
    // ---- stage 3: y_next = Welb @ x_new^T (bf16 out) ----
    f32x4 acc3[2] = {{0.f, 0.f, 0.f, 0.f}, {0.f, 0.f, 0.f, 0.f}};
    const unsigned short* W3p = Welb + (w * 16 + lr) * 64 + lk8;
#pragma unroll
    for (int ks = 0; ks < 2; ++ks) {
      short8 a = *(const short8*)(W3p + ks * 32);
      int kb = ks * 64 + lk8 * 2;
      short8 b0 = *(const short8*)(xnb + lr * 128 + (kb ^ swzr));
      short8 b1 = *(const short8*)(xnb + (16 + lr) * 128 + (kb ^ swzr));
      acc3[0] = __builtin_amdgcn_mfma_f32_16x16x32_bf16(a, b0, acc3[0], 0, 0, 0);
      acc3[1] = __builtin_amdgcn_mfma_f32_16x16x32_bf16(a, b1, acc3[1], 0, 0, 0);
    }
    int o0 = w * 16 + jo;
#pragma unroll
    for (int nt = 0; nt < 2; ++nt) {
      int node = n0 + nt * 16 + lr;
      if (node < N) {
        unsigned lo = (unsigned)f2bf(acc3[nt][0]) | ((unsigned)f2bf(acc3[nt][1]) << 16);
        unsigned hi = (unsigned)f2bf(acc3[nt][2]) | ((unsigned)f2bf(acc3[nt][3]) << 16);
        *(uint2*)(y_bf + (size_t)node * 64 + o0) = make_uint2(lo, hi);
      }
    }
  } else {
    // ---- fused output projection ----
    float4 w0 = *(const float4*)(Wo0 + h0);
    float4 w1 = *(const float4*)(Wo1 + h0);
    float* ow = (float*)h1T;  // [4 waves][2 outs][32 nodes]
#pragma unroll
    for (int nt = 0; nt < 2; ++nt) {
      float p0 = xn[nt].x * w0.x + xn[nt].y * w0.y + xn[nt].z * w0.z + xn[nt].w * w0.w;
      float p1 = xn[nt].x * w1.x + xn[nt].y * w1.y + xn[nt].z * w1.z + xn[nt].w * w1.w;
      p0 += __shfl_xor(p0, 16); p0 += __shfl_xor(p0, 32);
      p1 += __shfl_xor(p1, 16); p1 += __shfl_xor(p1, 32);
      if (lane < 16) {
        ow[w * 64 + 0 + nt * 16 + lr] = p0;
        ow[w * 64 + 32 + nt * 16 + lr] = p1;
      }
    }
    __syncthreads();
    if (t < 64) {
      int oi = t >> 5, nd = t & 31;
      int node = n0 + nd;
      if (node < N) {
        float v = ow[0 * 64 + oi * 32 + nd] + ow[1 * 64 + oi * 32 + nd] +
                  ow[2 * 64 + oi * 32 + nd] + ow[3 * 64 + oi * 32 + nd];
        v += (oi ? bo1[0] : bo0[0]);
        outp[(size_t)oi * N + node] = v;
      }
    }
  }
}

// per-graph (256 threads): parallel partial-reduce + split-K GEMVs + LSTM
__global__ __launch_bounds__(256) void k_graph(const int* __restrict__ gstart,
                                               const int* __restrict__ gend,
                                               const float* __restrict__ bmaxA,
                                               const float* __restrict__ bmaxB,
                                               const int* __restrict__ bgidA,
                                               const int* __restrict__ bgidB,
                                               unsigned* __restrict__ xu_enc,
                                               float* __restrict__ u,
                                               const float* __restrict__ W_gl,
                                               const float* __restrict__ b_gl,
                                               const float* __restrict__ W_ih,
                                               const float* __restrict__ b_ih,
                                               const float* __restrict__ b_hh,
                                               float* __restrict__ c_out) {
  __shared__ float red[4][3][64];
  __shared__ float xu_s[64], us[64], un[64];
  int g = blockIdx.x;
  int t = threadIdx.x, h = t & 63, qd = t >> 6;
  const float NEG = -__builtin_huge_valf();

  // strided block-partial reduce across 4 waves
  float m = NEG;
  int gs = gstart[g], ge = gend[g];
  if (gs < ge) {
    int bs = gs >> 5, be = (ge - 1) >> 5;
    for (int b = bs + qd; b <= be; b += 4) {
      if (bgidA[b] == g) m = fmaxf(m, bmaxA[(size_t)b * 64 + h]);
      if (bgidB[b] == g) m = fmaxf(m, bmaxB[(size_t)b * 64 + h]);
    }
  }
  red[qd][0][h] = m;
  __syncthreads();
  if (qd == 0) {
    m = fmaxf(fmaxf(red[0][0][h], red[1][0][h]), fmaxf(red[2][0][h], red[3][0][h]));
    unsigned Ev = xu_enc[g * 64 + h];  // fallback decode + reset
    float fd = (Ev & 0x80000000u) ? __uint_as_float(Ev & 0x7FFFFFFFu)
                                  : __uint_as_float(~Ev);
    m = fmaxf(m, fd);
    xu_enc[g * 64 + h] = 0x007FFFFFu;
    xu_s[h] = isfinite(m) ? m : 0.f;
    us[h] = u[g * 64 + h];
  }
  __syncthreads();

  // W_gl GEMV split-K: pre[h] = b_gl[h] + [xu|us] . W_gl[h]
  float pre = 0.f;
  {
    const float* Wrow = W_gl + h * 128 + qd * 32;
    const float* src = (qd < 2) ? (xu_s + qd * 32) : (us + (qd - 2) * 32);
#pragma unroll 8
    for (int k = 0; k < 32; ++k) pre += src[k] * Wrow[k];
  }
  red[qd][0][h] = pre;
  __syncthreads();
  if (qd == 0) {
    float prs = red[0][0][h] + red[1][0][h] + red[2][0][h] + red[3][0][h] + b_gl[h];
    un[h] = us[h] + fmaxf(prs, 0.f);
  }
  __syncthreads();

  // LSTM gates split-K (16 each over 4 waves)
  float gi = 0.f, gg = 0.f, go = 0.f;
#pragma unroll 4
  for (int k = qd * 16; k < qd * 16 + 16; ++k) {
    float uv = un[k];
    gi += uv * W_ih[h * 64 + k];
    gg += uv * W_ih[(128 + h) * 64 + k];
    go += uv * W_ih[(192 + h) * 64 + k];
  }
  red[qd][0][h] = gi; red[qd][1][h] = gg; red[qd][2][h] = go;
  __syncthreads();
  if (qd == 0) {
    gi = red[0][0][h] + red[1][0][h] + red[2][0][h] + red[3][0][h] + b_ih[h] + b_hh[h];
    gg = red[0][1][h] + red[1][1][h] + red[2][1][h] + red[3][1][h] +
         b_ih[128 + h] + b_hh[128 + h];
    go = red[0][2][h] + red[1][2][h] + red[2][2][h] + red[3][2][h] +
         b_ih[192 + h] + b_hh[192 + h];
    float cc = (1.f / (1.f + expf(-gi))) * tanhf(gg);
    float u2v = (1.f / (1.f + expf(-go))) * tanhf(cc);
    c_out[g * 64 + h] = cc;
    u[g * 64 + h] = u2v;
  }
}

extern "C" void kernel_launch(void* const* d_in, const int* in_sizes, int n_in,
                              void* d_out, int out_size, void* d_ws, size_t ws_size,
                              hipStream_t stream) {
  const float* v0 = (const float*)d_in[0];
  const float* v1 = (const float*)d_in[1];
  const float* dist = (const float*)d_in[2];
  const int* eidx = (const int*)d_in[3];
  const int* batch = (const int*)d_in[4];
  const float* wte = (const float*)d_in[6];
  const float* Wi0 = (const float*)d_in[7];
  const float* bi0 = (const float*)d_in[8];
  const float* Wi1 = (const float*)d_in[9];
  const float* bi1 = (const float*)d_in[10];
  const float* Wo0 = (const float*)d_in[11];
  const float* bo0 = (const float*)d_in[12];
  const float* Wo1 = (const float*)d_in[13];
  const float* bo1 = (const float*)d_in[14];
  const float* W_edge = (const float*)d_in[15];
  const float* b_edge = (const float*)d_in[16];
  const float* W_el = (const float*)d_in[17];
  const float* b_el = (const float*)d_in[18];
  const float* W_n1 = (const float*)d_in[19];
  const float* b_n1 = (const float*)d_in[20];
  const float* W_n2 = (const float*)d_in[21];
  const float* b_n2 = (const float*)d_in[22];
  const float* W_gl = (const float*)d_in[23];
  const float* b_gl = (const float*)d_in[24];
  const float* W_ih = (const float*)d_in[25];
  const float* b_ih = (const float*)d_in[27];
  const float* b_hh = (const float*)d_in[28];

  const int N = in_sizes[0];
  const int E = in_sizes[2];
  const int NH = N * 64;
  const int NB512 = (N + 511) / 512;
  const int nblk = (N + 31) / 32;

  float* ws = (float*)d_ws;
  float* x = ws;                                   // NH
  float* u = x + NH;                               // 4096
  unsigned* xu_enc = (unsigned*)(u + 4096);        // 4096
  float* p = (float*)(xu_enc + 4096);
  float* q = p + 64;
  float* c0 = q + 64;
  float* c1 = c0 + 64;
  float* c2 = c1 + 64;
  unsigned short* W1b = (unsigned short*)(c2 + 64);  // 49152
  unsigned short* W2b = W1b + 49152;                 // 16384
  unsigned short* Welb = W2b + 16384;                // 4096
  unsigned short* y_bf = Welb + 4096;                // NH
  int* deg = (int*)(y_bf + NH);                      // N
  int* off = deg + N;                                // N
  int* cur = off + N;                                // N
  int* bsum = cur + N;                               // 128
  int* gstart = bsum + 128;                          // 64
  int* gend = gstart + 64;                           // 64
  int* bgidA = gend + 64;                            // nblk
  int* bgidB = bgidA + nblk;                         // nblk
  float* bmaxA = (float*)(bgidB + nblk);             // nblk*64
  float* bmaxB = bmaxA + (size_t)nblk * 64;          // nblk*64
  uint2* spack = (uint2*)(((size_t)(bmaxB + (size_t)nblk * 64) + 15) & ~(size_t)15);  // E

  float* outp = (float*)d_out;

  k_prep_pq<<<1, 64, 0, stream>>>(W_el, b_el, W_edge, b_edge, wte, Wi0, bi0, Wi1, bi1,
                                  p, q, c0, c1, c2);
  k_init<<<(NH + 77824 + 2 * N + 255) / 256, 256, 0, stream>>>(
      v0, v1, wte, Wi0, bi0, Wi1, bi1, batch, gstart, gend, x,
      u, xu_enc, W1b, W2b, Welb, W_n1, W_n2, W_el, deg, cur, N);
  k_hist<<<(E + 255) / 256, 256, 0, stream>>>(eidx, deg, E);
  k_scan1<<<NB512, 256, 0, stream>>>(deg, off, bsum, N);
  k_scan2<<<1, 128, 0, stream>>>(bsum, NB512);
  k_scatter<<<(E + 255) / 256, 256, 0, stream>>>(eidx, dist, off, bsum, cur, spack, E);

  for (int l = 0; l < 4; ++l) {
    if (l == 0) {
      k_node<0><<<nblk, 256, 0, stream>>>(off, bsum, spack, p, q, c0, c1, c2, v0, v1,
                                          x, y_bf, batch, u, W1b, W2b, Welb, b_n1, b_n2,
                                          xu_enc, bmaxA, bmaxB, bgidA, bgidB,
                                          Wo0, bo0, Wo1, bo1, outp, N);
    } else if (l < 3) {
      k_node<1><<<nblk, 256, 0, stream>>>(off, bsum, spack, p, q, c0, c1, c2, v0, v1,
                                          x, y_bf, batch, u, W1b, W2b, Welb, b_n1, b_n2,
                                          xu_enc, bmaxA, bmaxB, bgidA, bgidB,
                                          Wo0, bo0, Wo1, bo1, outp, N);
    } else {
      k_node<2><<<nblk, 256, 0, stream>>>(off, bsum, spack, p, q, c0, c1, c2, v0, v1,
                                          x, y_bf, batch, u, W1b, W2b, Welb, b_n1, b_n2,
                                          xu_enc, bmaxA, bmaxB, bgidA, bgidB,
                                          Wo0, bo0, Wo1, bo1, outp, N);
    }
    k_graph<<<64, 256, 0, stream>>>(gstart, gend, bmaxA, bmaxB, bgidA, bgidB,
                                    xu_enc, u, W_gl, b_gl, W_ih, b_ih, b_hh,
                                    outp + 2 * N + l * 4096);
  }
}

// Round 9
// 313.906 us; speedup vs baseline: 3.4440x; 1.0752x over previous
//
#include <hip/hip_runtime.h>

// GraphTemporal: N=50000, E=500000, B=64, H=64, L=4 shared layers.
// msg = relu(y[row] + dist*p + q), y = x @ W_el[:, :64].T
// Layer 0: y computed on the fly from v0,v1 (rank-2 closed form) - no y gather.
// Edges CSR-sorted by destination; aggregation fused into k_node stage 0:
//   DUAL-EDGE half-wave processing (lane 0-31 edge A, 32-63 edge B; dword y
//   loads = 2 bf16 channels/lane), per-wave contiguous edge quarters,
//   wave-private LDS meta slice with reg prefetch, register running-max.
// x read ONCE per block in stage-2 fragment layout (regs).
// Per-graph max via disjoint per-block scratch reduced in k_graph (256 thr).

typedef __attribute__((ext_vector_type(8))) short short8;
typedef __attribute__((ext_vector_type(4))) float f32x4;

__device__ __forceinline__ unsigned short f2bf(float f) {
  union { float f; unsigned u; } v; v.f = f;
  unsigned r = v.u + 0x7FFFu + ((v.u >> 16) & 1u);
  return (unsigned short)(r >> 16);
}
__device__ __forceinline__ float bf2f(unsigned short s) {
  return __uint_as_float((unsigned)s << 16);
}
__device__ __forceinline__ unsigned enc_ordered(float f) {
  unsigned u = __float_as_uint(f);
  return (u >> 31) ? ~u : (u | 0x80000000u);
}

// fused init: x, graph ranges, u=0, xu_enc, bf16 weights, deg/cur=0, p/q/c0..c2
__global__ void k_init(const float* __restrict__ v0, const float* __restrict__ v1,
                       const float* __restrict__ wte,
                       const float* __restrict__ Wi0, const float* __restrict__ bi0,
                       const float* __restrict__ Wi1, const float* __restrict__ bi1,
                       const int* __restrict__ batch,
                       int* __restrict__ gstart, int* __restrict__ gend,
                       float* __restrict__ x,
                       float* __restrict__ u, unsigned* __restrict__ xu_enc,
                       unsigned short* __restrict__ W1b, unsigned short* __restrict__ W2b,
                       unsigned short* __restrict__ Welb,
                       const float* __restrict__ W_n1, const float* __restrict__ W_n2,
                       const float* __restrict__ W_el,
                       const float* __restrict__ b_el,
                       const float* __restrict__ W_edge, const float* __restrict__ b_edge,
                       float* __restrict__ p, float* __restrict__ q,
                       float* __restrict__ c0, float* __restrict__ c1,
                       float* __restrict__ c2,
                       int* __restrict__ deg, int* __restrict__ cur, int N) {
  int gt = blockIdx.x * 256 + threadIdx.x;
  int NH = N * 64;
  if (gt < NH) {
    int n = gt >> 6, h = gt & 63;
    x[gt] = wte[h] + wte[64 + h] + bi0[h] + bi1[h] + v0[n] * Wi0[h] + v1[n] * Wi1[h];
    if (h == 0) {
      int bg = batch[n];
      if (n == 0 || batch[n - 1] != bg) gstart[bg] = n;
      if (n == N - 1 || batch[n + 1] != bg) gend[bg] = n + 1;
    }
    return;
  }
  int i = gt - NH;
  if (i < 4096) {
    u[i] = 0.f;
  } else if (i < 8192) {
    xu_enc[i - 4096] = 0x007FFFFFu;  // enc(-inf)
  } else if (i < 8192 + 49152) {
    int j = i - 8192;                 // W_n1 [256][192]
    W1b[j] = f2bf(W_n1[j]);
  } else if (i < 8192 + 49152 + 16384) {
    int j = i - 57344;                // W_n2 [64][256]
    W2b[j] = f2bf(W_n2[j]);
  } else if (i < 77824) {
    int j = i - 73728;                // W_el[:, :64] compact stride 64
    Welb[j] = f2bf(W_el[(j >> 6) * 128 + (j & 63)]);
  } else if (i < 77824 + N) {
    deg[i - 77824] = 0;
  } else if (i < 77824 + 2 * N) {
    cur[i - 77824 - N] = 0;
  } else if (i < 77824 + 2 * N + 64) {
    int h = i - 77824 - 2 * N;
    float pp = 0.f, qq = 0.f, s0 = 0.f, s1 = 0.f, s2 = 0.f;
    for (int k = 0; k < 64; ++k) {
      float w2 = W_el[h * 128 + 64 + k];
      pp += w2 * W_edge[k];
      qq += w2 * b_edge[k];
      float w1 = W_el[h * 128 + k];
      float base = wte[k] + wte[64 + k] + bi0[k] + bi1[k];
      s0 += w1 * base;
      s1 += w1 * Wi0[k];
      s2 += w1 * Wi1[k];
    }
    p[h] = pp; q[h] = qq + b_el[h];
    c0[h] = s0; c1[h] = s1; c2[h] = s2;
  }
}

// ---- CSR build (once per call) ----
__global__ __launch_bounds__(256) void k_hist(const int* __restrict__ eidx,
                                              int* __restrict__ deg, int E) {
  int e = blockIdx.x * 256 + threadIdx.x;
  if (e < E) atomicAdd(&deg[eidx[E + e]], 1);
}

// per-512-chunk inclusive scan (off stays chunk-local; consumers add bsum)
__global__ __launch_bounds__(256) void k_scan1(const int* __restrict__ deg,
                                               int* __restrict__ off,
                                               int* __restrict__ bsum, int N) {
  __shared__ int s[256];
  int b = blockIdx.x, t = threadIdx.x;
  int i0 = b * 512 + t * 2;
  int v0 = (i0 < N) ? deg[i0] : 0;
  int v1 = (i0 + 1 < N) ? deg[i0 + 1] : 0;
  int sum = v0 + v1;
  s[t] = sum;
  __syncthreads();
  for (int d = 1; d < 256; d <<= 1) {
    int val = (t >= d) ? s[t - d] : 0;
    __syncthreads();
    s[t] += val;
    __syncthreads();
  }
  int excl = s[t] - sum;
  if (i0 < N) off[i0] = excl + v0;
  if (i0 + 1 < N) off[i0 + 1] = excl + v0 + v1;
  if (t == 255) bsum[b] = s[t];
}

// exclusive scan of block sums (nb <= 128)
__global__ void k_scan2(int* __restrict__ bsum, int nb) {
  __shared__ int s[128];
  int t = threadIdx.x;
  int v = (t < nb) ? bsum[t] : 0;
  s[t] = v;
  __syncthreads();
  for (int d = 1; d < 128; d <<= 1) {
    int val = (t >= d) ? s[t - d] : 0;
    __syncthreads();
    s[t] += val;
    __syncthreads();
  }
  if (t < nb) bsum[t] = s[t] - v;
}

// spack.x = row | (col&31)<<27 ; spack.y = dist bits
__global__ __launch_bounds__(256) void k_scatter(const int* __restrict__ eidx,
                                                 const float* __restrict__ dist,
                                                 const int* __restrict__ off,
                                                 const int* __restrict__ bsum,
                                                 int* __restrict__ cur,
                                                 uint2* __restrict__ spack, int E) {
  int e = blockIdx.x * 256 + threadIdx.x;
  if (e >= E) return;
  int c = eidx[E + e];
  int base = (c == 0) ? 0 : (off[c - 1] + bsum[(c - 1) >> 9]);
  int pos = base + atomicAdd(&cur[c], 1);
  spack[pos] = make_uint2((unsigned)eidx[e] | ((unsigned)(c & 31) << 27),
                          __float_as_uint(dist[e]));
}

// Fused per-layer kernel. MODE 0: layer0 (y from v0/v1, write y_next)
//                         MODE 1: mid (y gather, write y_next)
//                         MODE 2: last (y gather, fused out-proj, no x store)
template <int MODE>
__global__ __launch_bounds__(256) void k_node(
    const int* __restrict__ off, const int* __restrict__ bsum,
    const uint2* __restrict__ spack,
    const float* __restrict__ p, const float* __restrict__ q,
    const float* __restrict__ c0, const float* __restrict__ c1,
    const float* __restrict__ c2,
    const float* __restrict__ v0, const float* __restrict__ v1,
    float* __restrict__ x, unsigned short* __restrict__ y_bf,
    const int* __restrict__ batch, const float* __restrict__ u,
    const unsigned short* __restrict__ W1b, const unsigned short* __restrict__ W2b,
    const unsigned short* __restrict__ Welb,
    const float* __restrict__ b_n1, const float* __restrict__ b_n2,
    unsigned* __restrict__ xu_enc,
    float* __restrict__ bmaxA, float* __restrict__ bmaxB,
    int* __restrict__ bgidA, int* __restrict__ bgidB,
    const float* __restrict__ Wo0, const float* __restrict__ bo0,
    const float* __restrict__ Wo1, const float* __restrict__ bo1,
    float* __restrict__ outp, int N) {
  __shared__ __align__(16) char inb[32 * 384];  // [32][192] bf16 (xnb aliases)
  __shared__ __align__(16) char h1T[32 * 512];  // [32][256] bf16 (aggT/ow alias)
  __shared__ uint2 smeta[256];                  // 4 waves x 64 private slices
  __shared__ int sgb[32];
  int t = threadIdx.x;
  int n0 = blockIdx.x * 32;
  int lane = t & 63, wv = t >> 6;
  int lr = lane & 15;
  int lk8 = (lane >> 4) << 3;
  int jo = (lane >> 4) << 2;
  int swzr = (lr & 7) << 4;
  int h0 = wv * 16 + jo;

  // ---- x read ONCE in stage-2 fragment layout; u gather; sgb ----
  float4 xo[2];
#pragma unroll
  for (int nt = 0; nt < 2; ++nt) {
    int node = n0 + nt * 16 + lr;
    xo[nt] = (node < N) ? *(const float4*)(x + (size_t)node * 64 + h0)
                        : make_float4(0.f, 0.f, 0.f, 0.f);
  }
  int nd_s = t >> 3, ko = t & 7;
  int node_s = n0 + nd_s;
  float4 ua = make_float4(0.f, 0.f, 0.f, 0.f), ub = ua;
  if (node_s < N) {
    int g = batch[node_s];
    const float4* u4 = (const float4*)u;
    ua = u4[g * 16 + ko * 2];
    ub = u4[g * 16 + ko * 2 + 1];
  }
  if (t < 32) sgb[t] = batch[min(n0 + t, N - 1)];

  // ---- zero agg tile (aliases h1T) ----
  int* aggi = (int*)h1T;  // [32][64] fp32-as-int, msg >= 0
#pragma unroll
  for (int i = 0; i < 8; ++i) aggi[t + i * 256] = 0;

  // ---- write x (from regs) and u sections of inb ----
#pragma unroll
  for (int nt = 0; nt < 2; ++nt) {
    int nd = nt * 16 + lr;
    unsigned lo = (unsigned)f2bf(xo[nt].x) | ((unsigned)f2bf(xo[nt].y) << 16);
    unsigned hi = (unsigned)f2bf(xo[nt].z) | ((unsigned)f2bf(xo[nt].w) << 16);
    *(uint2*)(inb + nd * 384 + ((128 + h0 * 2) ^ ((nd & 7) << 4))) = make_uint2(lo, hi);
  }
  {
    int swz = (nd_s & 7) << 4;
    uint4 uv;
    uv.x = f2bf(ua.x) | ((unsigned)f2bf(ua.y) << 16);
    uv.y = f2bf(ua.z) | ((unsigned)f2bf(ua.w) << 16);
    uv.z = f2bf(ub.x) | ((unsigned)f2bf(ub.y) << 16);
    uv.w = f2bf(ub.z) | ((unsigned)f2bf(ub.w) << 16);
    *(uint4*)(inb + nd_s * 384 + ((256 + ko * 16) ^ swz)) = uv;
  }
  __syncthreads();  // aggi zeroed before any wave aggregates

  // ---- stage 0: DUAL-EDGE half-wave aggregation (barrier-free) ----
  {
    int last = min(n0 + 31, N - 1);
    int ebase = (n0 == 0) ? 0 : (off[n0 - 1] + bsum[(n0 - 1) >> 9]);
    int eend = off[last] + bsum[last >> 9];
    int total = eend - ebase;
    int q4 = total >> 2;
    int wb = ebase + wv * q4;
    int we = (wv == 3) ? eend : (wb + q4);
    uint2* sm = smeta + wv * 64;   // wave-private slice
    int half = lane >> 5, l31 = lane & 31;
    const unsigned* y32 = (const unsigned*)y_bf + l31;
    float2 p2 = *(const float2*)(p + 2 * l31);
    float2 q2 = *(const float2*)(q + 2 * l31);
    float2 c02 = make_float2(0.f, 0.f), c12 = c02, c22 = c02;
    if (MODE == 0) {
      c02 = *(const float2*)(c0 + 2 * l31);
      c12 = *(const float2*)(c1 + 2 * l31);
      c22 = *(const float2*)(c2 + 2 * l31);
    }
    float m0 = 0.f, m1 = 0.f;
    int ccur = -1;
    uint2 r = make_uint2(0u, 0u);
    if (wb < we) {
      int cnt = min(64, we - wb);
      if (lane < cnt) r = spack[wb + lane];
    }
    for (int cb = wb; cb < we; cb += 64) {
      int ccnt = min(64, we - cb);
      sm[lane] = r;
      int nb = cb + 64;
      if (nb < we) {
        int ncnt = we - nb;
        if (lane < ncnt) r = spack[nb + lane];  // prefetch next chunk
      }
      int nfull = ccnt >> 1;
      int i = 0;
      for (; i + 8 <= nfull; i += 8) {
        uint2 e[8]; unsigned yd[8]; float va[8], vb[8];
#pragma unroll
        for (int k = 0; k < 8; ++k) e[k] = sm[2 * (i + k) + half];
#pragma unroll
        for (int k = 0; k < 8; ++k) {
          unsigned row = e[k].x & 0x07FFFFFFu;
          if (MODE == 0) { va[k] = v0[row]; vb[k] = v1[row]; }
          else yd[k] = y32[row << 5];
        }
#pragma unroll
        for (int k = 0; k < 8; ++k) {
          float y0f, y1f;
          if (MODE == 0) {
            y0f = fmaf(vb[k], c22.x, fmaf(va[k], c12.x, c02.x));
            y1f = fmaf(vb[k], c22.y, fmaf(va[k], c12.y, c02.y));
          } else {
            y0f = __uint_as_float(yd[k] << 16);
            y1f = __uint_as_float(yd[k] & 0xFFFF0000u);
          }
          float d = __uint_as_float(e[k].y);
          float g0 = fmaxf(fmaf(d, p2.x, y0f + q2.x), 0.f);
          float g1 = fmaxf(fmaf(d, p2.y, y1f + q2.y), 0.f);
          int c = (int)(e[k].x >> 27);
          if (c != ccur) {
            if (ccur >= 0) {
              atomicMax(&aggi[ccur * 64 + 2 * l31], __float_as_int(m0));
              atomicMax(&aggi[ccur * 64 + 2 * l31 + 1], __float_as_int(m1));
            }
            ccur = c; m0 = g0; m1 = g1;
          } else { m0 = fmaxf(m0, g0); m1 = fmaxf(m1, g1); }
        }
      }
      for (; 2 * i < ccnt; ++i) {
        int idx = 2 * i + half;
        bool val = idx < ccnt;
        uint2 e = sm[val ? idx : 0];
        unsigned row = e.x & 0x07FFFFFFu;
        float y0f, y1f;
        if (MODE == 0) {
          float a = v0[row], b = v1[row];
          y0f = fmaf(b, c22.x, fmaf(a, c12.x, c02.x));
          y1f = fmaf(b, c22.y, fmaf(a, c12.y, c02.y));
        } else {
          unsigned yd = y32[row << 5];
          y0f = __uint_as_float(yd << 16);
          y1f = __uint_as_float(yd & 0xFFFF0000u);
        }
        float d = __uint_as_float(e.y);
        float g0 = val ? fmaxf(fmaf(d, p2.x, y0f + q2.x), 0.f) : 0.f;
        float g1 = val ? fmaxf(fmaf(d, p2.y, y1f + q2.y), 0.f) : 0.f;
        int c = val ? (int)(e.x >> 27) : ccur;
        if (c != ccur) {
          if (ccur >= 0) {
            atomicMax(&aggi[ccur * 64 + 2 * l31], __float_as_int(m0));
            atomicMax(&aggi[ccur * 64 + 2 * l31 + 1], __float_as_int(m1));
          }
          ccur = c; m0 = g0; m1 = g1;
        } else { m0 = fmaxf(m0, g0); m1 = fmaxf(m1, g1); }
      }
    }
    if (ccur >= 0) {
      atomicMax(&aggi[ccur * 64 + 2 * l31], __float_as_int(m0));
      atomicMax(&aggi[ccur * 64 + 2 * l31 + 1], __float_as_int(m1));
    }
  }
  __syncthreads();

  // ---- agg tile -> inb bf16 (swizzled) ----
  {
    int swz = (nd_s & 7) << 4;
    const float4* ag4 = (const float4*)(h1T);
    float4 aa = ag4[nd_s * 16 + ko * 2];
    float4 ab = ag4[nd_s * 16 + ko * 2 + 1];
    uint4 av;
    av.x = f2bf(aa.x) | ((unsigned)f2bf(aa.y) << 16);
    av.y = f2bf(aa.z) | ((unsigned)f2bf(aa.w) << 16);
    av.z = f2bf(ab.x) | ((unsigned)f2bf(ab.y) << 16);
    av.w = f2bf(ab.z) | ((unsigned)f2bf(ab.w) << 16);
    *(uint4*)(inb + nd_s * 384 + ((ko * 16) ^ swz)) = av;
  }
  __syncthreads();

  int w = wv;

  // ---- stage 1: h1 = relu(W1 @ in^T + b_n1) ----
  f32x4 acc[4][2];
#pragma unroll
  for (int ot = 0; ot < 4; ++ot)
#pragma unroll
    for (int nt = 0; nt < 2; ++nt) acc[ot][nt] = (f32x4){0.f, 0.f, 0.f, 0.f};
  const unsigned short* W1p = W1b + (w * 64 + lr) * 192 + lk8;
#pragma unroll
  for (int ks = 0; ks < 6; ++ks) {
    int kb = ks * 64 + lk8 * 2;
    short8 b0 = *(const short8*)(inb + lr * 384 + (kb ^ swzr));
    short8 b1 = *(const short8*)(inb + (16 + lr) * 384 + (kb ^ swzr));
#pragma unroll
    for (int ot = 0; ot < 4; ++ot) {
      short8 a = *(const short8*)(W1p + ot * (16 * 192) + ks * 32);
      acc[ot][0] = __builtin_amdgcn_mfma_f32_16x16x32_bf16(a, b0, acc[ot][0], 0, 0, 0);
      acc[ot][1] = __builtin_amdgcn_mfma_f32_16x16x32_bf16(a, b1, acc[ot][1], 0, 0, 0);
    }
  }
  __syncthreads();  // aggT fully read; safe to overwrite h1T
#pragma unroll
  for (int ot = 0; ot < 4; ++ot) {
    int o = w * 64 + ot * 16 + jo;
    float4 bs = *(const float4*)(b_n1 + o);
#pragma unroll
    for (int nt = 0; nt < 2; ++nt) {
      int nd = nt * 16 + lr;
      unsigned lo = (unsigned)f2bf(fmaxf(acc[ot][nt][0] + bs.x, 0.f)) |
                    ((unsigned)f2bf(fmaxf(acc[ot][nt][1] + bs.y, 0.f)) << 16);
      unsigned hi = (unsigned)f2bf(fmaxf(acc[ot][nt][2] + bs.z, 0.f)) |
                    ((unsigned)f2bf(fmaxf(acc[ot][nt][3] + bs.w, 0.f)) << 16);
      *(uint2*)(h1T + nd * 512 + ((o * 2) ^ ((nd & 7) << 4))) = make_uint2(lo, hi);
    }
  }
  __syncthreads();

  // ---- stage 2: x_new = x + W2 @ h1^T + b_n2 (x from regs) ----
  f32x4 acc2[2] = {{0.f, 0.f, 0.f, 0.f}, {0.f, 0.f, 0.f, 0.f}};
  const unsigned short* W2p = W2b + (w * 16 + lr) * 256 + lk8;
#pragma unroll
  for (int ks = 0; ks < 8; ++ks) {
    short8 a = *(const short8*)(W2p + ks * 32);
    int kb = ks * 64 + lk8 * 2;
    short8 b0 = *(const short8*)(h1T + lr * 512 + (kb ^ swzr));
    short8 b1 = *(const short8*)(h1T + (16 + lr) * 512 + (kb ^ swzr));
    acc2[0] = __builtin_amdgcn_mfma_f32_16x16x32_bf16(a, b0, acc2[0], 0, 0, 0);
    acc2[1] = __builtin_amdgcn_mfma_f32_16x16x32_bf16(a, b1, acc2[1], 0, 0, 0);
  }
  float4 b2 = *(const float4*)(b_n2 + h0);
  char* xnb = inb;  // alias
  float4 xn[2];
#pragma unroll
  for (int nt = 0; nt < 2; ++nt) {
    int nd = nt * 16 + lr;
    int node = n0 + nd;
    xn[nt].x = xo[nt].x + acc2[nt][0] + b2.x;
    xn[nt].y = xo[nt].y + acc2[nt][1] + b2.y;
    xn[nt].z = xo[nt].z + acc2[nt][2] + b2.z;
    xn[nt].w = xo[nt].w + acc2[nt][3] + b2.w;
    if (node >= N) xn[nt] = make_float4(0.f, 0.f, 0.f, 0.f);
    if (MODE != 2 && node < N) *(float4*)(x + (size_t)node * 64 + h0) = xn[nt];
    if (MODE != 2) {
      unsigned lo = (unsigned)f2bf(xn[nt].x) | ((unsigned)f2bf(xn[nt].y) << 16);
      unsigned hi = (unsigned)f2bf(xn[nt].z) | ((unsigned)f2bf(xn[nt].w) << 16);
      *(uint2*)(xnb + nd * 128 + ((h0 * 2) ^ ((nd & 7) << 4))) = make_uint2(lo, hi);
    }
  }

  // ---- per-graph max partials -> disjoint scratch ----
  {
    const float NEG = -__builtin_huge_valf();
    int gA = sgb[0], gB = sgb[31];
    float a0 = NEG, a1 = NEG, a2 = NEG, a3 = NEG;
    float e0 = NEG, e1 = NEG, e2 = NEG, e3 = NEG;
#pragma unroll
    for (int nt = 0; nt < 2; ++nt) {
      int nd = nt * 16 + lr;
      if (n0 + nd < N) {
        int g = sgb[nd];
        if (g == gA) {
          a0 = fmaxf(a0, xn[nt].x); a1 = fmaxf(a1, xn[nt].y);
          a2 = fmaxf(a2, xn[nt].z); a3 = fmaxf(a3, xn[nt].w);
        } else if (g == gB) {
          e0 = fmaxf(e0, xn[nt].x); e1 = fmaxf(e1, xn[nt].y);
          e2 = fmaxf(e2, xn[nt].z); e3 = fmaxf(e3, xn[nt].w);
        } else {  // >2 graphs in block: rare fallback
          unsigned* xe = xu_enc + g * 64 + h0;
          atomicMax(xe + 0, enc_ordered(xn[nt].x));
          atomicMax(xe + 1, enc_ordered(xn[nt].y));
          atomicMax(xe + 2, enc_ordered(xn[nt].z));
          atomicMax(xe + 3, enc_ordered(xn[nt].w));
        }
      }
    }
#pragma unroll
    for (int msk = 1; msk <= 8; msk <<= 1) {
      a0 = fmaxf(a0, __shfl_xor(a0, msk)); a1 = fmaxf(a1, __shfl_xor(a1, msk));
      a2 = fmaxf(a2, __shfl_xor(a2, msk)); a3 = fmaxf(a3, __shfl_xor(a3, msk));
      e0 = fmaxf(e0, __shfl_xor(e0, msk)); e1 = fmaxf(e1, __shfl_xor(e1, msk));
      e2 = fmaxf(e2, __shfl_xor(e2, msk)); e3 = fmaxf(e3, __shfl_xor(e3, msk));
    }
    if (lr == 0) {
      size_t base = (size_t)blockIdx.x * 64 + h0;
      bmaxA[base + 0] = a0; bmaxA[base + 1] = a1;
      bmaxA[base + 2] = a2; bmaxA[base + 3] = a3;
      bmaxB[base + 0] = e0; bmaxB[base + 1] = e1;
      bmaxB[base + 2] = e2; bmaxB[base + 3] = e3;
    }
    if (t == 0) {
      bgidA[blockIdx.x] = gA;
      bgidB[blockIdx.x] = (gB == gA) ? -1 : gB;
    }
  }
  __syncthreads();

  if (MODE != 2) {
    // ---- stage 3: y_next = Welb @ x_new^T (bf16 out) ----
    f32x4 acc3[2] = {{0.f, 0.f, 0.f, 0.f}, {0.f, 0.f, 0.f, 0.f}};
    const unsigned short* W3p = Welb + (w * 16 + lr) * 64 + lk8;
#pragma unroll
    for (int ks = 0; ks < 2; ++ks) {
      short8 a = *(const short8*)(W3p + ks * 32);
      int kb = ks * 64 + lk8 * 2;
      short8 b0 = *(const short8*)(xnb + lr * 128 + (kb ^ swzr));
      short8 b1 = *(const short8*)(xnb + (16 + lr) * 128 + (kb ^ swzr));
      acc3[0] = __builtin_amdgcn_mfma_f32_16x16x32_bf16(a, b0, acc3[0], 0, 0, 0);
      acc3[1] = __builtin_amdgcn_mfma_f32_16x16x32_bf16(a, b1, acc3[1], 0, 0, 0);
    }
    int o0 = w * 16 + jo;
#pragma unroll
    for (int nt = 0; nt < 2; ++nt) {
      int node = n0 + nt * 16 + lr;
      if (node < N) {
        unsigned lo = (unsigned)f2bf(acc3[nt][0]) | ((unsigned)f2bf(acc3[nt][1]) << 16);
        unsigned hi = (unsigned)f2bf(acc3[nt][2]) | ((unsigned)f2bf(acc3[nt][3]) << 16);
        *(uint2*)(y_bf + (size_t)node * 64 + o0) = make_uint2(lo, hi);
      }
    }
  } else {
    // ---- fused output projection ----
    float4 w0 = *(const float4*)(Wo0 + h0);
    float4 w1 = *(const float4*)(Wo1 + h0);
    float* ow = (float*)h1T;  // [4 waves][2 outs][32 nodes]
#pragma unroll
    for (int nt = 0; nt < 2; ++nt) {
      float p0 = xn[nt].x * w0.x + xn[nt].y * w0.y + xn[nt].z * w0.z + xn[nt].w * w0.w;
      float p1 = xn[nt].x * w1.x + xn[nt].y * w1.y + xn[nt].z * w1.z + xn[nt].w * w1.w;
      p0 += __shfl_xor(p0, 16); p0 += __shfl_xor(p0, 32);
      p1 += __shfl_xor(p1, 16); p1 += __shfl_xor(p1, 32);
      if (lane < 16) {
        ow[w * 64 + 0 + nt * 16 + lr] = p0;
        ow[w * 64 + 32 + nt * 16 + lr] = p1;
      }
    }
    __syncthreads();
    if (t < 64) {
      int oi = t >> 5, nd = t & 31;
      int node = n0 + nd;
      if (node < N) {
        float v = ow[0 * 64 + oi * 32 + nd] + ow[1 * 64 + oi * 32 + nd] +
                  ow[2 * 64 + oi * 32 + nd] + ow[3 * 64 + oi * 32 + nd];
        v += (oi ? bo1[0] : bo0[0]);
        outp[(size_t)oi * N + node] = v;
      }
    }
  }
}

// per-graph (256 threads): parallel partial-reduce + split-K GEMVs + LSTM
__global__ __launch_bounds__(256) void k_graph(const int* __restrict__ gstart,
                                               const int* __restrict__ gend,
                                               const float* __restrict__ bmaxA,
                                               const float* __restrict__ bmaxB,
                                               const int* __restrict__ bgidA,
                                               const int* __restrict__ bgidB,
                                               unsigned* __restrict__ xu_enc,
                                               float* __restrict__ u,
                                               const float* __restrict__ W_gl,
                                               const float* __restrict__ b_gl,
                                               const float* __restrict__ W_ih,
                                               const float* __restrict__ b_ih,
                                               const float* __restrict__ b_hh,
                                               float* __restrict__ c_out) {
  __shared__ float red[4][3][64];
  __shared__ float xu_s[64], us[64], un[64];
  int g = blockIdx.x;
  int t = threadIdx.x, h = t & 63, qd = t >> 6;
  const float NEG = -__builtin_huge_valf();

  // strided block-partial reduce across 4 waves
  float m = NEG;
  int gs = gstart[g], ge = gend[g];
  if (gs < ge) {
    int bs = gs >> 5, be = (ge - 1) >> 5;
    for (int b = bs + qd; b <= be; b += 4) {
      if (bgidA[b] == g) m = fmaxf(m, bmaxA[(size_t)b * 64 + h]);
      if (bgidB[b] == g) m = fmaxf(m, bmaxB[(size_t)b * 64 + h]);
    }
  }
  red[qd][0][h] = m;
  __syncthreads();
  if (qd == 0) {
    m = fmaxf(fmaxf(red[0][0][h], red[1][0][h]), fmaxf(red[2][0][h], red[3][0][h]));
    unsigned Ev = xu_enc[g * 64 + h];  // fallback decode + reset
    float fd = (Ev & 0x80000000u) ? __uint_as_float(Ev & 0x7FFFFFFFu)
                                  : __uint_as_float(~Ev);
    m = fmaxf(m, fd);
    xu_enc[g * 64 + h] = 0x007FFFFFu;
    xu_s[h] = isfinite(m) ? m : 0.f;
    us[h] = u[g * 64 + h];
  }
  __syncthreads();

  // W_gl GEMV split-K: pre[h] = b_gl[h] + [xu|us] . W_gl[h]
  float pre = 0.f;
  {
    const float* Wrow = W_gl + h * 128 + qd * 32;
    const float* src = (qd < 2) ? (xu_s + qd * 32) : (us + (qd - 2) * 32);
#pragma unroll 8
    for (int k = 0; k < 32; ++k) pre += src[k] * Wrow[k];
  }
  red[qd][0][h] = pre;
  __syncthreads();
  if (qd == 0) {
    float prs = red[0][0][h] + red[1][0][h] + red[2][0][h] + red[3][0][h] + b_gl[h];
    un[h] = us[h] + fmaxf(prs, 0.f);
  }
  __syncthreads();

  // LSTM gates split-K (16 each over 4 waves)
  float gi = 0.f, gg = 0.f, go = 0.f;
#pragma unroll 4
  for (int k = qd * 16; k < qd * 16 + 16; ++k) {
    float uv = un[k];
    gi += uv * W_ih[h * 64 + k];
    gg += uv * W_ih[(128 + h) * 64 + k];
    go += uv * W_ih[(192 + h) * 64 + k];
  }
  red[qd][0][h] = gi; red[qd][1][h] = gg; red[qd][2][h] = go;
  __syncthreads();
  if (qd == 0) {
    gi = red[0][0][h] + red[1][0][h] + red[2][0][h] + red[3][0][h] + b_ih[h] + b_hh[h];
    gg = red[0][1][h] + red[1][1][h] + red[2][1][h] + red[3][1][h] +
         b_ih[128 + h] + b_hh[128 + h];
    go = red[0][2][h] + red[1][2][h] + red[2][2][h] + red[3][2][h] +
         b_ih[192 + h] + b_hh[192 + h];
    float cc = (1.f / (1.f + expf(-gi))) * tanhf(gg);
    float u2v = (1.f / (1.f + expf(-go))) * tanhf(cc);
    c_out[g * 64 + h] = cc;
    u[g * 64 + h] = u2v;
  }
}

extern "C" void kernel_launch(void* const* d_in, const int* in_sizes, int n_in,
                              void* d_out, int out_size, void* d_ws, size_t ws_size,
                              hipStream_t stream) {
  const float* v0 = (const float*)d_in[0];
  const float* v1 = (const float*)d_in[1];
  const float* dist = (const float*)d_in[2];
  const int* eidx = (const int*)d_in[3];
  const int* batch = (const int*)d_in[4];
  const float* wte = (const float*)d_in[6];
  const float* Wi0 = (const float*)d_in[7];
  const float* bi0 = (const float*)d_in[8];
  const float* Wi1 = (const float*)d_in[9];
  const float* bi1 = (const float*)d_in[10];
  const float* Wo0 = (const float*)d_in[11];
  const float* bo0 = (const float*)d_in[12];
  const float* Wo1 = (const float*)d_in[13];
  const float* bo1 = (const float*)d_in[14];
  const float* W_edge = (const float*)d_in[15];
  const float* b_edge = (const float*)d_in[16];
  const float* W_el = (const float*)d_in[17];
  const float* b_el = (const float*)d_in[18];
  const float* W_n1 = (const float*)d_in[19];
  const float* b_n1 = (const float*)d_in[20];
  const float* W_n2 = (const float*)d_in[21];
  const float* b_n2 = (const float*)d_in[22];
  const float* W_gl = (const float*)d_in[23];
  const float* b_gl = (const float*)d_in[24];
  const float* W_ih = (const float*)d_in[25];
  const float* b_ih = (const float*)d_in[27];
  const float* b_hh = (const float*)d_in[28];

  const int N = in_sizes[0];
  const int E = in_sizes[2];
  const int NH = N * 64;
  const int NB512 = (N + 511) / 512;
  const int nblk = (N + 31) / 32;

  float* ws = (float*)d_ws;
  float* x = ws;                                   // NH
  float* u = x + NH;                               // 4096
  unsigned* xu_enc = (unsigned*)(u + 4096);        // 4096
  float* p = (float*)(xu_enc + 4096);
  float* q = p + 64;
  float* c0 = q + 64;
  float* c1 = c0 + 64;
  float* c2 = c1 + 64;
  unsigned short* W1b = (unsigned short*)(c2 + 64);  // 49152
  unsigned short* W2b = W1b + 49152;                 // 16384
  unsigned short* Welb = W2b + 16384;                // 4096
  unsigned short* y_bf = Welb + 4096;                // NH
  int* deg = (int*)(y_bf + NH);                      // N
  int* off = deg + N;                                // N
  int* cur = off + N;                                // N
  int* bsum = cur + N;                               // 128
  int* gstart = bsum + 128;                          // 64
  int* gend = gstart + 64;                           // 64
  int* bgidA = gend + 64;                            // nblk
  int* bgidB = bgidA + nblk;                         // nblk
  float* bmaxA = (float*)(bgidB + nblk);             // nblk*64
  float* bmaxB = bmaxA + (size_t)nblk * 64;          // nblk*64
  uint2* spack = (uint2*)(((size_t)(bmaxB + (size_t)nblk * 64) + 15) & ~(size_t)15);  // E

  float* outp = (float*)d_out;

  k_init<<<(NH + 77824 + 2 * N + 64 + 255) / 256, 256, 0, stream>>>(
      v0, v1, wte, Wi0, bi0, Wi1, bi1, batch, gstart, gend, x,
      u, xu_enc, W1b, W2b, Welb, W_n1, W_n2, W_el, b_el, W_edge, b_edge,
      p, q, c0, c1, c2, deg, cur, N);
  k_hist<<<(E + 255) / 256, 256, 0, stream>>>(eidx, deg, E);
  k_scan1<<<NB512, 256, 0, stream>>>(deg, off, bsum, N);
  k_scan2<<<1, 128, 0, stream>>>(bsum, NB512);
  k_scatter<<<(E + 255) / 256, 256, 0, stream>>>(eidx, dist, off, bsum, cur, spack, E);

  for (int l = 0; l < 4; ++l) {
    if (l == 0) {
      k_node<0><<<nblk, 256, 0, stream>>>(off, bsum, spack, p, q, c0, c1, c2, v0, v1,
                                          x, y_bf, batch, u, W1b, W2b, Welb, b_n1, b_n2,
                                          xu_enc, bmaxA, bmaxB, bgidA, bgidB,
                                          Wo0, bo0, Wo1, bo1, outp, N);
    } else if (l < 3) {
      k_node<1><<<nblk, 256, 0, stream>>>(off, bsum, spack, p, q, c0, c1, c2, v0, v1,
                                          x, y_bf, batch, u, W1b, W2b, Welb, b_n1, b_n2,
                                          xu_enc, bmaxA, bmaxB, bgidA, bgidB,
                                          Wo0, bo0, Wo1, bo1, outp, N);
    } else {
      k_node<2><<<nblk, 256, 0, stream>>>(off, bsum, spack, p, q, c0, c1, c2, v0, v1,
                                          x, y_bf, batch, u, W1b, W2b, Welb, b_n1, b_n2,
                                          xu_enc, bmaxA, bmaxB, bgidA, bgidB,
                                          Wo0, bo0, Wo1, bo1, outp, N);
    }
    k_graph<<<64, 256, 0, stream>>>(gstart, gend, bmaxA, bmaxB, bgidA, bgidB,
                                    xu_enc, u, W_gl, b_gl, W_ih, b_ih, b_hh,
                                    outp + 2 * N + l * 4096);
  }
}

// Round 10
// 313.153 us; speedup vs baseline: 3.4523x; 1.0024x over previous
//
#include <hip/hip_runtime.h>

// GraphTemporal: N=50000, E=500000, B=64, H=64, L=4 shared layers.
// msg = relu(y[row] + dist*p + q), y = x @ W_el[:, :64].T
// Layer 0: y AND x computed on the fly from v0,v1 (rank-2 closed form).
// Edges CSR-sorted by destination; aggregation fused into k_node stage 0:
//   QUARTER-WAVE groups (16 lanes/edge, 4 bf16 channels/lane via uint2),
//   contiguous per-group edge ranges, ILP-8, register running-max, no LDS meta.
// Per-graph max via disjoint per-block scratch reduced in k_graph (256 thr).

typedef __attribute__((ext_vector_type(8))) short short8;
typedef __attribute__((ext_vector_type(4))) float f32x4;

__device__ __forceinline__ unsigned short f2bf(float f) {
  union { float f; unsigned u; } v; v.f = f;
  unsigned r = v.u + 0x7FFFu + ((v.u >> 16) & 1u);
  return (unsigned short)(r >> 16);
}
__device__ __forceinline__ float bf2f(unsigned short s) {
  return __uint_as_float((unsigned)s << 16);
}
__device__ __forceinline__ unsigned enc_ordered(float f) {
  unsigned u = __float_as_uint(f);
  return (u >> 31) ? ~u : (u | 0x80000000u);
}

// fused init: graph ranges, u=0, xu_enc, bf16 weights, deg/cur=0, p/q/c0..c2
__global__ void k_init(const float* __restrict__ v0, const float* __restrict__ v1,
                       const float* __restrict__ wte,
                       const float* __restrict__ Wi0, const float* __restrict__ bi0,
                       const float* __restrict__ Wi1, const float* __restrict__ bi1,
                       const int* __restrict__ batch,
                       int* __restrict__ gstart, int* __restrict__ gend,
                       float* __restrict__ u, unsigned* __restrict__ xu_enc,
                       unsigned short* __restrict__ W1b, unsigned short* __restrict__ W2b,
                       unsigned short* __restrict__ Welb,
                       const float* __restrict__ W_n1, const float* __restrict__ W_n2,
                       const float* __restrict__ W_el,
                       const float* __restrict__ b_el,
                       const float* __restrict__ W_edge, const float* __restrict__ b_edge,
                       float* __restrict__ p, float* __restrict__ q,
                       float* __restrict__ c0, float* __restrict__ c1,
                       float* __restrict__ c2,
                       int* __restrict__ deg, int* __restrict__ cur, int N) {
  int i = blockIdx.x * 256 + threadIdx.x;
  if (i < 4096) {
    u[i] = 0.f;
  } else if (i < 8192) {
    xu_enc[i - 4096] = 0x007FFFFFu;  // enc(-inf)
  } else if (i < 8192 + 49152) {
    int j = i - 8192;                 // W_n1 [256][192]
    W1b[j] = f2bf(W_n1[j]);
  } else if (i < 8192 + 49152 + 16384) {
    int j = i - 57344;                // W_n2 [64][256]
    W2b[j] = f2bf(W_n2[j]);
  } else if (i < 77824) {
    int j = i - 73728;                // W_el[:, :64] compact stride 64
    Welb[j] = f2bf(W_el[(j >> 6) * 128 + (j & 63)]);
  } else if (i < 77824 + N) {
    deg[i - 77824] = 0;
  } else if (i < 77824 + 2 * N) {
    cur[i - 77824 - N] = 0;
  } else if (i < 77824 + 3 * N) {
    int n = i - 77824 - 2 * N;        // graph range detection (unique writer)
    int bg = batch[n];
    if (n == 0 || batch[n - 1] != bg) gstart[bg] = n;
    if (n == N - 1 || batch[n + 1] != bg) gend[bg] = n + 1;
  } else if (i < 77824 + 3 * N + 64) {
    int h = i - 77824 - 3 * N;
    float pp = 0.f, qq = 0.f, s0 = 0.f, s1 = 0.f, s2 = 0.f;
    for (int k = 0; k < 64; ++k) {
      float w2 = W_el[h * 128 + 64 + k];
      pp += w2 * W_edge[k];
      qq += w2 * b_edge[k];
      float w1 = W_el[h * 128 + k];
      float base = wte[k] + wte[64 + k] + bi0[k] + bi1[k];
      s0 += w1 * base;
      s1 += w1 * Wi0[k];
      s2 += w1 * Wi1[k];
    }
    p[h] = pp; q[h] = qq + b_el[h];
    c0[h] = s0; c1[h] = s1; c2[h] = s2;
  }
}

// ---- CSR build (once per call) ----
__global__ __launch_bounds__(256) void k_hist(const int* __restrict__ eidx,
                                              int* __restrict__ deg, int E) {
  int e = blockIdx.x * 256 + threadIdx.x;
  if (e < E) atomicAdd(&deg[eidx[E + e]], 1);
}

// per-512-chunk inclusive scan (off stays chunk-local; consumers add bsum)
__global__ __launch_bounds__(256) void k_scan1(const int* __restrict__ deg,
                                               int* __restrict__ off,
                                               int* __restrict__ bsum, int N) {
  __shared__ int s[256];
  int b = blockIdx.x, t = threadIdx.x;
  int i0 = b * 512 + t * 2;
  int v0 = (i0 < N) ? deg[i0] : 0;
  int v1 = (i0 + 1 < N) ? deg[i0 + 1] : 0;
  int sum = v0 + v1;
  s[t] = sum;
  __syncthreads();
  for (int d = 1; d < 256; d <<= 1) {
    int val = (t >= d) ? s[t - d] : 0;
    __syncthreads();
    s[t] += val;
    __syncthreads();
  }
  int excl = s[t] - sum;
  if (i0 < N) off[i0] = excl + v0;
  if (i0 + 1 < N) off[i0 + 1] = excl + v0 + v1;
  if (t == 255) bsum[b] = s[t];
}

// exclusive scan of block sums (nb <= 128)
__global__ void k_scan2(int* __restrict__ bsum, int nb) {
  __shared__ int s[128];
  int t = threadIdx.x;
  int v = (t < nb) ? bsum[t] : 0;
  s[t] = v;
  __syncthreads();
  for (int d = 1; d < 128; d <<= 1) {
    int val = (t >= d) ? s[t - d] : 0;
    __syncthreads();
    s[t] += val;
    __syncthreads();
  }
  if (t < nb) bsum[t] = s[t] - v;
}

// spack.x = row | (col&31)<<27 ; spack.y = dist bits
__global__ __launch_bounds__(256) void k_scatter(const int* __restrict__ eidx,
                                                 const float* __restrict__ dist,
                                                 const int* __restrict__ off,
                                                 const int* __restrict__ bsum,
                                                 int* __restrict__ cur,
                                                 uint2* __restrict__ spack, int E) {
  int e = blockIdx.x * 256 + threadIdx.x;
  if (e >= E) return;
  int c = eidx[E + e];
  int base = (c == 0) ? 0 : (off[c - 1] + bsum[(c - 1) >> 9]);
  int pos = base + atomicAdd(&cur[c], 1);
  spack[pos] = make_uint2((unsigned)eidx[e] | ((unsigned)(c & 31) << 27),
                          __float_as_uint(dist[e]));
}

// Fused per-layer kernel. MODE 0: layer0 (x,y closed form, write y_next)
//                         MODE 1: mid (y gather, write y_next)
//                         MODE 2: last (y gather, fused out-proj, no x store)
template <int MODE>
__global__ __launch_bounds__(256) void k_node(
    const int* __restrict__ off, const int* __restrict__ bsum,
    const uint2* __restrict__ spack,
    const float* __restrict__ p, const float* __restrict__ q,
    const float* __restrict__ c0, const float* __restrict__ c1,
    const float* __restrict__ c2,
    const float* __restrict__ v0, const float* __restrict__ v1,
    const float* __restrict__ wte,
    const float* __restrict__ Wi0, const float* __restrict__ bi0,
    const float* __restrict__ Wi1, const float* __restrict__ bi1,
    float* __restrict__ x, unsigned short* __restrict__ y_bf,
    const int* __restrict__ batch, const float* __restrict__ u,
    const unsigned short* __restrict__ W1b, const unsigned short* __restrict__ W2b,
    const unsigned short* __restrict__ Welb,
    const float* __restrict__ b_n1, const float* __restrict__ b_n2,
    unsigned* __restrict__ xu_enc,
    float* __restrict__ bmaxA, float* __restrict__ bmaxB,
    int* __restrict__ bgidA, int* __restrict__ bgidB,
    const float* __restrict__ Wo0, const float* __restrict__ bo0,
    const float* __restrict__ Wo1, const float* __restrict__ bo1,
    float* __restrict__ outp, int N) {
  __shared__ __align__(16) char inb[32 * 384];  // [32][192] bf16 (xnb aliases)
  __shared__ __align__(16) char h1T[32 * 512];  // [32][256] bf16 (aggT/ow alias)
  __shared__ int sgb[32];
  int t = threadIdx.x;
  int n0 = blockIdx.x * 32;
  int lane = t & 63, wv = t >> 6;
  int lr = lane & 15;
  int lk8 = (lane >> 4) << 3;
  int jo = (lane >> 4) << 2;
  int swzr = (lr & 7) << 4;
  int h0 = wv * 16 + jo;

  // ---- x in stage-2 fragment layout (MODE 0: closed form); u gather; sgb ----
  float4 xo[2];
  if (MODE == 0) {
    float4 wA = *(const float4*)(wte + h0);
    float4 wB = *(const float4*)(wte + 64 + h0);
    float4 bA = *(const float4*)(bi0 + h0);
    float4 bB = *(const float4*)(bi1 + h0);
    float4 w0v = *(const float4*)(Wi0 + h0);
    float4 w1v = *(const float4*)(Wi1 + h0);
    float4 cb = make_float4(wA.x + wB.x + bA.x + bB.x, wA.y + wB.y + bA.y + bB.y,
                            wA.z + wB.z + bA.z + bB.z, wA.w + wB.w + bA.w + bB.w);
#pragma unroll
    for (int nt = 0; nt < 2; ++nt) {
      int node = n0 + nt * 16 + lr;
      float a = (node < N) ? v0[node] : 0.f;
      float b = (node < N) ? v1[node] : 0.f;
      xo[nt].x = cb.x + a * w0v.x + b * w1v.x;
      xo[nt].y = cb.y + a * w0v.y + b * w1v.y;
      xo[nt].z = cb.z + a * w0v.z + b * w1v.z;
      xo[nt].w = cb.w + a * w0v.w + b * w1v.w;
    }
  } else {
#pragma unroll
    for (int nt = 0; nt < 2; ++nt) {
      int node = n0 + nt * 16 + lr;
      xo[nt] = (node < N) ? *(const float4*)(x + (size_t)node * 64 + h0)
                          : make_float4(0.f, 0.f, 0.f, 0.f);
    }
  }
  int nd_s = t >> 3, ko = t & 7;
  int node_s = n0 + nd_s;
  float4 ua = make_float4(0.f, 0.f, 0.f, 0.f), ub = ua;
  if (node_s < N) {
    int g = batch[node_s];
    const float4* u4 = (const float4*)u;
    ua = u4[g * 16 + ko * 2];
    ub = u4[g * 16 + ko * 2 + 1];
  }
  if (t < 32) sgb[t] = batch[min(n0 + t, N - 1)];

  // ---- zero agg tile (aliases h1T) ----
  int* aggi = (int*)h1T;  // [32][64] fp32-as-int, msg >= 0
#pragma unroll
  for (int i = 0; i < 8; ++i) aggi[t + i * 256] = 0;

  // ---- write x (from regs) and u sections of inb ----
#pragma unroll
  for (int nt = 0; nt < 2; ++nt) {
    int nd = nt * 16 + lr;
    unsigned lo = (unsigned)f2bf(xo[nt].x) | ((unsigned)f2bf(xo[nt].y) << 16);
    unsigned hi = (unsigned)f2bf(xo[nt].z) | ((unsigned)f2bf(xo[nt].w) << 16);
    *(uint2*)(inb + nd * 384 + ((128 + h0 * 2) ^ ((nd & 7) << 4))) = make_uint2(lo, hi);
  }
  {
    int swz = (nd_s & 7) << 4;
    uint4 uv;
    uv.x = f2bf(ua.x) | ((unsigned)f2bf(ua.y) << 16);
    uv.y = f2bf(ua.z) | ((unsigned)f2bf(ua.w) << 16);
    uv.z = f2bf(ub.x) | ((unsigned)f2bf(ub.y) << 16);
    uv.w = f2bf(ub.z) | ((unsigned)f2bf(ub.w) << 16);
    *(uint4*)(inb + nd_s * 384 + ((256 + ko * 16) ^ swz)) = uv;
  }
  __syncthreads();  // aggi zeroed before any group aggregates

  // ---- stage 0: QUARTER-WAVE edge aggregation (barrier-free) ----
  {
    int last = min(n0 + 31, N - 1);
    int ebase = (n0 == 0) ? 0 : (off[n0 - 1] + bsum[(n0 - 1) >> 9]);
    int eend = off[last] + bsum[last >> 9];
    int total = eend - ebase;
    int gi16 = (wv << 2) | (lane >> 4);   // 16 contiguous groups
    int ch = lane & 15;                   // channels ch*4..ch*4+3
    int chunk = (total + 15) >> 4;
    int gb = ebase + gi16 * chunk;
    int ge = min(gb + chunk, eend);
    const unsigned short* ybase = y_bf + ch * 4;
    float4 p4 = *(const float4*)(p + ch * 4);
    float4 q4 = *(const float4*)(q + ch * 4);
    float4 c04 = make_float4(0.f, 0.f, 0.f, 0.f), c14 = c04, c24 = c04;
    if (MODE == 0) {
      c04 = *(const float4*)(c0 + ch * 4);
      c14 = *(const float4*)(c1 + ch * 4);
      c24 = *(const float4*)(c2 + ch * 4);
    }
    float4 m4 = make_float4(0.f, 0.f, 0.f, 0.f);
    int ccur = -1;
    int e = gb;
#define FLUSH4()                                                            \
  do {                                                                      \
    atomicMax(&aggi[ccur * 64 + ch * 4 + 0], __float_as_int(m4.x));         \
    atomicMax(&aggi[ccur * 64 + ch * 4 + 1], __float_as_int(m4.y));         \
    atomicMax(&aggi[ccur * 64 + ch * 4 + 2], __float_as_int(m4.z));         \
    atomicMax(&aggi[ccur * 64 + ch * 4 + 3], __float_as_int(m4.w));         \
  } while (0)
    for (; e + 8 <= ge; e += 8) {
      uint2 em[8];
#pragma unroll
      for (int k = 0; k < 8; ++k) em[k] = spack[e + k];
      uint2 yv[8]; float va[8], vb[8];
#pragma unroll
      for (int k = 0; k < 8; ++k) {
        unsigned row = em[k].x & 0x07FFFFFFu;
        if (MODE == 0) { va[k] = v0[row]; vb[k] = v1[row]; }
        else yv[k] = *(const uint2*)(ybase + (size_t)row * 64);
      }
#pragma unroll
      for (int k = 0; k < 8; ++k) {
        float4 y4;
        if (MODE == 0) {
          y4.x = fmaf(vb[k], c24.x, fmaf(va[k], c14.x, c04.x));
          y4.y = fmaf(vb[k], c24.y, fmaf(va[k], c14.y, c04.y));
          y4.z = fmaf(vb[k], c24.z, fmaf(va[k], c14.z, c04.z));
          y4.w = fmaf(vb[k], c24.w, fmaf(va[k], c14.w, c04.w));
        } else {
          y4.x = __uint_as_float(yv[k].x << 16);
          y4.y = __uint_as_float(yv[k].x & 0xFFFF0000u);
          y4.z = __uint_as_float(yv[k].y << 16);
          y4.w = __uint_as_float(yv[k].y & 0xFFFF0000u);
        }
        float d = __uint_as_float(em[k].y);
        float4 g4;
        g4.x = fmaxf(fmaf(d, p4.x, y4.x + q4.x), 0.f);
        g4.y = fmaxf(fmaf(d, p4.y, y4.y + q4.y), 0.f);
        g4.z = fmaxf(fmaf(d, p4.z, y4.z + q4.z), 0.f);
        g4.w = fmaxf(fmaf(d, p4.w, y4.w + q4.w), 0.f);
        int c = (int)(em[k].x >> 27);
        if (c != ccur) {
          if (ccur >= 0) FLUSH4();
          ccur = c; m4 = g4;
        } else {
          m4.x = fmaxf(m4.x, g4.x); m4.y = fmaxf(m4.y, g4.y);
          m4.z = fmaxf(m4.z, g4.z); m4.w = fmaxf(m4.w, g4.w);
        }
      }
    }
    for (; e < ge; ++e) {
      uint2 em = spack[e];
      unsigned row = em.x & 0x07FFFFFFu;
      float4 y4;
      if (MODE == 0) {
        float a = v0[row], b = v1[row];
        y4.x = fmaf(b, c24.x, fmaf(a, c14.x, c04.x));
        y4.y = fmaf(b, c24.y, fmaf(a, c14.y, c04.y));
        y4.z = fmaf(b, c24.z, fmaf(a, c14.z, c04.z));
        y4.w = fmaf(b, c24.w, fmaf(a, c14.w, c04.w));
      } else {
        uint2 yv = *(const uint2*)(ybase + (size_t)row * 64);
        y4.x = __uint_as_float(yv.x << 16);
        y4.y = __uint_as_float(yv.x & 0xFFFF0000u);
        y4.z = __uint_as_float(yv.y << 16);
        y4.w = __uint_as_float(yv.y & 0xFFFF0000u);
      }
      float d = __uint_as_float(em.y);
      float4 g4;
      g4.x = fmaxf(fmaf(d, p4.x, y4.x + q4.x), 0.f);
      g4.y = fmaxf(fmaf(d, p4.y, y4.y + q4.y), 0.f);
      g4.z = fmaxf(fmaf(d, p4.z, y4.z + q4.z), 0.f);
      g4.w = fmaxf(fmaf(d, p4.w, y4.w + q4.w), 0.f);
      int c = (int)(em.x >> 27);
      if (c != ccur) {
        if (ccur >= 0) FLUSH4();
        ccur = c; m4 = g4;
      } else {
        m4.x = fmaxf(m4.x, g4.x); m4.y = fmaxf(m4.y, g4.y);
        m4.z = fmaxf(m4.z, g4.z); m4.w = fmaxf(m4.w, g4.w);
      }
    }
    if (ccur >= 0) FLUSH4();
#undef FLUSH4
  }
  __syncthreads();

  // ---- agg tile -> inb bf16 (swizzled) ----
  {
    int swz = (nd_s & 7) << 4;
    const float4* ag4 = (const float4*)(h1T);
    float4 aa = ag4[nd_s * 16 + ko * 2];
    float4 ab = ag4[nd_s * 16 + ko * 2 + 1];
    uint4 av;
    av.x = f2bf(aa.x) | ((unsigned)f2bf(aa.y) << 16);
    av.y = f2bf(aa.z) | ((unsigned)f2bf(aa.w) << 16);
    av.z = f2bf(ab.x) | ((unsigned)f2bf(ab.y) << 16);
    av.w = f2bf(ab.z) | ((unsigned)f2bf(ab.w) << 16);
    *(uint4*)(inb + nd_s * 384 + ((ko * 16) ^ swz)) = av;
  }
  __syncthreads();

  int w = wv;

  // ---- stage 1: h1 = relu(W1 @ in^T + b_n1) ----
  f32x4 acc[4][2];
#pragma unroll
  for (int ot = 0; ot < 4; ++ot)
#pragma unroll
    for (int nt = 0; nt < 2; ++nt) acc[ot][nt] = (f32x4){0.f, 0.f, 0.f, 0.f};
  const unsigned short* W1p = W1b + (w * 64 + lr) * 192 + lk8;
#pragma unroll
  for (int ks = 0; ks < 6; ++ks) {
    int kb = ks * 64 + lk8 * 2;
    short8 b0 = *(const short8*)(inb + lr * 384 + (kb ^ swzr));
    short8 b1 = *(const short8*)(inb + (16 + lr) * 384 + (kb ^ swzr));
#pragma unroll
    for (int ot = 0; ot < 4; ++ot) {
      short8 a = *(const short8*)(W1p + ot * (16 * 192) + ks * 32);
      acc[ot][0] = __builtin_amdgcn_mfma_f32_16x16x32_bf16(a, b0, acc[ot][0], 0, 0, 0);
      acc[ot][1] = __builtin_amdgcn_mfma_f32_16x16x32_bf16(a, b1, acc[ot][1], 0, 0, 0);
    }
  }
  __syncthreads();  // aggT fully read; safe to overwrite h1T
#pragma unroll
  for (int ot = 0; ot < 4; ++ot) {
    int o = w * 64 + ot * 16 + jo;
    float4 bs = *(const float4*)(b_n1 + o);
#pragma unroll
    for (int nt = 0; nt < 2; ++nt) {
      int nd = nt * 16 + lr;
      unsigned lo = (unsigned)f2bf(fmaxf(acc[ot][nt][0] + bs.x, 0.f)) |
                    ((unsigned)f2bf(fmaxf(acc[ot][nt][1] + bs.y, 0.f)) << 16);
      unsigned hi = (unsigned)f2bf(fmaxf(acc[ot][nt][2] + bs.z, 0.f)) |
                    ((unsigned)f2bf(fmaxf(acc[ot][nt][3] + bs.w, 0.f)) << 16);
      *(uint2*)(h1T + nd * 512 + ((o * 2) ^ ((nd & 7) << 4))) = make_uint2(lo, hi);
    }
  }
  __syncthreads();

  // ---- stage 2: x_new = x + W2 @ h1^T + b_n2 (x from regs) ----
  f32x4 acc2[2] = {{0.f, 0.f, 0.f, 0.f}, {0.f, 0.f, 0.f, 0.f}};
  const unsigned short* W2p = W2b + (w * 16 + lr) * 256 + lk8;
#pragma unroll
  for (int ks = 0; ks < 8; ++ks) {
    short8 a = *(const short8*)(W2p + ks * 32);
    int kb = ks * 64 + lk8 * 2;
    short8 b0 = *(const short8*)(h1T + lr * 512 + (kb ^ swzr));
    short8 b1 = *(const short8*)(h1T + (16 + lr) * 512 + (kb ^ swzr));
    acc2[0] = __builtin_amdgcn_mfma_f32_16x16x32_bf16(a, b0, acc2[0], 0, 0, 0);
    acc2[1] = __builtin_amdgcn_mfma_f32_16x16x32_bf16(a, b1, acc2[1], 0, 0, 0);
  }
  float4 b2 = *(const float4*)(b_n2 + h0);
  char* xnb = inb;  // alias
  float4 xn[2];
#pragma unroll
  for (int nt = 0; nt < 2; ++nt) {
    int nd = nt * 16 + lr;
    int node = n0 + nd;
    xn[nt].x = xo[nt].x + acc2[nt][0] + b2.x;
    xn[nt].y = xo[nt].y + acc2[nt][1] + b2.y;
    xn[nt].z = xo[nt].z + acc2[nt][2] + b2.z;
    xn[nt].w = xo[nt].w + acc2[nt][3] + b2.w;
    if (node >= N) xn[nt] = make_float4(0.f, 0.f, 0.f, 0.f);
    if (MODE != 2 && node < N) *(float4*)(x + (size_t)node * 64 + h0) = xn[nt];
    if (MODE != 2) {
      unsigned lo = (unsigned)f2bf(xn[nt].x) | ((unsigned)f2bf(xn[nt].y) << 16);
      unsigned hi = (unsigned)f2bf(xn[nt].z) | ((unsigned)f2bf(xn[nt].w) << 16);
      *(uint2*)(xnb + nd * 128 + ((h0 * 2) ^ ((nd & 7) << 4))) = make_uint2(lo, hi);
    }
  }

  // ---- per-graph max partials -> disjoint scratch ----
  {
    const float NEG = -__builtin_huge_valf();
    int gA = sgb[0], gB = sgb[31];
    float a0 = NEG, a1 = NEG, a2 = NEG, a3 = NEG;
    float e0 = NEG, e1 = NEG, e2 = NEG, e3 = NEG;
#pragma unroll
    for (int nt = 0; nt < 2; ++nt) {
      int nd = nt * 16 + lr;
      if (n0 + nd < N) {
        int g = sgb[nd];
        if (g == gA) {
          a0 = fmaxf(a0, xn[nt].x); a1 = fmaxf(a1, xn[nt].y);
          a2 = fmaxf(a2, xn[nt].z); a3 = fmaxf(a3, xn[nt].w);
        } else if (g == gB) {
          e0 = fmaxf(e0, xn[nt].x); e1 = fmaxf(e1, xn[nt].y);
          e2 = fmaxf(e2, xn[nt].z); e3 = fmaxf(e3, xn[nt].w);
        } else {  // >2 graphs in block: rare fallback
          unsigned* xe = xu_enc + g * 64 + h0;
          atomicMax(xe + 0, enc_ordered(xn[nt].x));
          atomicMax(xe + 1, enc_ordered(xn[nt].y));
          atomicMax(xe + 2, enc_ordered(xn[nt].z));
          atomicMax(xe + 3, enc_ordered(xn[nt].w));
        }
      }
    }
#pragma unroll
    for (int msk = 1; msk <= 8; msk <<= 1) {
      a0 = fmaxf(a0, __shfl_xor(a0, msk)); a1 = fmaxf(a1, __shfl_xor(a1, msk));
      a2 = fmaxf(a2, __shfl_xor(a2, msk)); a3 = fmaxf(a3, __shfl_xor(a3, msk));
      e0 = fmaxf(e0, __shfl_xor(e0, msk)); e1 = fmaxf(e1, __shfl_xor(e1, msk));
      e2 = fmaxf(e2, __shfl_xor(e2, msk)); e3 = fmaxf(e3, __shfl_xor(e3, msk));
    }
    if (lr == 0) {
      size_t base = (size_t)blockIdx.x * 64 + h0;
      bmaxA[base + 0] = a0; bmaxA[base + 1] = a1;
      bmaxA[base + 2] = a2; bmaxA[base + 3] = a3;
      bmaxB[base + 0] = e0; bmaxB[base + 1] = e1;
      bmaxB[base + 2] = e2; bmaxB[base + 3] = e3;
    }
    if (t == 0) {
      bgidA[blockIdx.x] = gA;
      bgidB[blockIdx.x] = (gB == gA) ? -1 : gB;
    }
  }
  __syncthreads();

  if (MODE != 2) {
    // ---- stage 3: y_next = Welb @ x_new^T (bf16 out) ----
    f32x4 acc3[2] = {{0.f, 0.f, 0.f, 0.f}, {0.f, 0.f, 0.f, 0.f}};
    const unsigned short* W3p = Welb + (w * 16 + lr) * 64 + lk8;
#pragma unroll
    for (int ks = 0; ks < 2; ++ks) {
      short8 a = *(const short8*)(W3p + ks * 32);
      int kb = ks * 64 + lk8 * 2;
      short8 b0 = *(const short8*)(xnb + lr * 128 + (kb ^ swzr));
      short8 b1 = *(const short8*)(xnb + (16 + lr) * 128 + (kb ^ swzr));
      acc3[0] = __builtin_amdgcn_mfma_f32_16x16x32_bf16(a, b0, acc3[0], 0, 0, 0);
      acc3[1] = __builtin_amdgcn_mfma_f32_16x16x32_bf16(a, b1, acc3[1], 0, 0, 0);
    }
    int o0 = w * 16 + jo;
#pragma unroll
    for (int nt = 0; nt < 2; ++nt) {
      int node = n0 + nt * 16 + lr;
      if (node < N) {
        unsigned lo = (unsigned)f2bf(acc3[nt][0]) | ((unsigned)f2bf(acc3[nt][1]) << 16);
        unsigned hi = (unsigned)f2bf(acc3[nt][2]) | ((unsigned)f2bf(acc3[nt][3]) << 16);
        *(uint2*)(y_bf + (size_t)node * 64 + o0) = make_uint2(lo, hi);
      }
    }
  } else {
    // ---- fused output projection ----
    float4 w0 = *(const float4*)(Wo0 + h0);
    float4 w1 = *(const float4*)(Wo1 + h0);
    float* ow = (float*)h1T;  // [4 waves][2 outs][32 nodes]
#pragma unroll
    for (int nt = 0; nt < 2; ++nt) {
      float p0 = xn[nt].x * w0.x + xn[nt].y * w0.y + xn[nt].z * w0.z + xn[nt].w * w0.w;
      float p1 = xn[nt].x * w1.x + xn[nt].y * w1.y + xn[nt].z * w1.z + xn[nt].w * w1.w;
      p0 += __shfl_xor(p0, 16); p0 += __shfl_xor(p0, 32);
      p1 += __shfl_xor(p1, 16); p1 += __shfl_xor(p1, 32);
      if (lane < 16) {
        ow[w * 64 + 0 + nt * 16 + lr] = p0;
        ow[w * 64 + 32 + nt * 16 + lr] = p1;
      }
    }
    __syncthreads();
    if (t < 64) {
      int oi = t >> 5, nd = t & 31;
      int node = n0 + nd;
      if (node < N) {
        float v = ow[0 * 64 + oi * 32 + nd] + ow[1 * 64 + oi * 32 + nd] +
                  ow[2 * 64 + oi * 32 + nd] + ow[3 * 64 + oi * 32 + nd];
        v += (oi ? bo1[0] : bo0[0]);
        outp[(size_t)oi * N + node] = v;
      }
    }
  }
}

// per-graph (256 threads): parallel partial-reduce + split-K GEMVs + LSTM
__global__ __launch_bounds__(256) void k_graph(const int* __restrict__ gstart,
                                               const int* __restrict__ gend,
                                               const float* __restrict__ bmaxA,
                                               const float* __restrict__ bmaxB,
                                               const int* __restrict__ bgidA,
                                               const int* __restrict__ bgidB,
                                               unsigned* __restrict__ xu_enc,
                                               float* __restrict__ u,
                                               const float* __restrict__ W_gl,
                                               const float* __restrict__ b_gl,
                                               const float* __restrict__ W_ih,
                                               const float* __restrict__ b_ih,
                                               const float* __restrict__ b_hh,
                                               float* __restrict__ c_out) {
  __shared__ float red[4][3][64];
  __shared__ float xu_s[64], us[64], un[64];
  int g = blockIdx.x;
  int t = threadIdx.x, h = t & 63, qd = t >> 6;
  const float NEG = -__builtin_huge_valf();

  // strided block-partial reduce across 4 waves
  float m = NEG;
  int gs = gstart[g], ge = gend[g];
  if (gs < ge) {
    int bs = gs >> 5, be = (ge - 1) >> 5;
    for (int b = bs + qd; b <= be; b += 4) {
      if (bgidA[b] == g) m = fmaxf(m, bmaxA[(size_t)b * 64 + h]);
      if (bgidB[b] == g) m = fmaxf(m, bmaxB[(size_t)b * 64 + h]);
    }
  }
  red[qd][0][h] = m;
  __syncthreads();
  if (qd == 0) {
    m = fmaxf(fmaxf(red[0][0][h], red[1][0][h]), fmaxf(red[2][0][h], red[3][0][h]));
    unsigned Ev = xu_enc[g * 64 + h];  // fallback decode + reset
    float fd = (Ev & 0x80000000u) ? __uint_as_float(Ev & 0x7FFFFFFFu)
                                  : __uint_as_float(~Ev);
    m = fmaxf(m, fd);
    xu_enc[g * 64 + h] = 0x007FFFFFu;
    xu_s[h] = isfinite(m) ? m : 0.f;
    us[h] = u[g * 64 + h];
  }
  __syncthreads();

  // W_gl GEMV split-K: pre[h] = b_gl[h] + [xu|us] . W_gl[h]
  float pre = 0.f;
  {
    const float* Wrow = W_gl + h * 128 + qd * 32;
    const float* src = (qd < 2) ? (xu_s + qd * 32) : (us + (qd - 2) * 32);
#pragma unroll 8
    for (int k = 0; k < 32; ++k) pre += src[k] * Wrow[k];
  }
  red[qd][0][h] = pre;
  __syncthreads();
  if (qd == 0) {
    float prs = red[0][0][h] + red[1][0][h] + red[2][0][h] + red[3][0][h] + b_gl[h];
    un[h] = us[h] + fmaxf(prs, 0.f);
  }
  __syncthreads();

  // LSTM gates split-K (16 each over 4 waves)
  float gi = 0.f, gg = 0.f, go = 0.f;
#pragma unroll 4
  for (int k = qd * 16; k < qd * 16 + 16; ++k) {
    float uv = un[k];
    gi += uv * W_ih[h * 64 + k];
    gg += uv * W_ih[(128 + h) * 64 + k];
    go += uv * W_ih[(192 + h) * 64 + k];
  }
  red[qd][0][h] = gi; red[qd][1][h] = gg; red[qd][2][h] = go;
  __syncthreads();
  if (qd == 0) {
    gi = red[0][0][h] + red[1][0][h] + red[2][0][h] + red[3][0][h] + b_ih[h] + b_hh[h];
    gg = red[0][1][h] + red[1][1][h] + red[2][1][h] + red[3][1][h] +
         b_ih[128 + h] + b_hh[128 + h];
    go = red[0][2][h] + red[1][2][h] + red[2][2][h] + red[3][2][h] +
         b_ih[192 + h] + b_hh[192 + h];
    float cc = (1.f / (1.f + expf(-gi))) * tanhf(gg);
    float u2v = (1.f / (1.f + expf(-go))) * tanhf(cc);
    c_out[g * 64 + h] = cc;
    u[g * 64 + h] = u2v;
  }
}

extern "C" void kernel_launch(void* const* d_in, const int* in_sizes, int n_in,
                              void* d_out, int out_size, void* d_ws, size_t ws_size,
                              hipStream_t stream) {
  const float* v0 = (const float*)d_in[0];
  const float* v1 = (const float*)d_in[1];
  const float* dist = (const float*)d_in[2];
  const int* eidx = (const int*)d_in[3];
  const int* batch = (const int*)d_in[4];
  const float* wte = (const float*)d_in[6];
  const float* Wi0 = (const float*)d_in[7];
  const float* bi0 = (const float*)d_in[8];
  const float* Wi1 = (const float*)d_in[9];
  const float* bi1 = (const float*)d_in[10];
  const float* Wo0 = (const float*)d_in[11];
  const float* bo0 = (const float*)d_in[12];
  const float* Wo1 = (const float*)d_in[13];
  const float* bo1 = (const float*)d_in[14];
  const float* W_edge = (const float*)d_in[15];
  const float* b_edge = (const float*)d_in[16];
  const float* W_el = (const float*)d_in[17];
  const float* b_el = (const float*)d_in[18];
  const float* W_n1 = (const float*)d_in[19];
  const float* b_n1 = (const float*)d_in[20];
  const float* W_n2 = (const float*)d_in[21];
  const float* b_n2 = (const float*)d_in[22];
  const float* W_gl = (const float*)d_in[23];
  const float* b_gl = (const float*)d_in[24];
  const float* W_ih = (const float*)d_in[25];
  const float* b_ih = (const float*)d_in[27];
  const float* b_hh = (const float*)d_in[28];

  const int N = in_sizes[0];
  const int E = in_sizes[2];
  const int NH = N * 64;
  const int NB512 = (N + 511) / 512;
  const int nblk = (N + 31) / 32;

  float* ws = (float*)d_ws;
  float* x = ws;                                   // NH
  float* u = x + NH;                               // 4096
  unsigned* xu_enc = (unsigned*)(u + 4096);        // 4096
  float* p = (float*)(xu_enc + 4096);
  float* q = p + 64;
  float* c0 = q + 64;
  float* c1 = c0 + 64;
  float* c2 = c1 + 64;
  unsigned short* W1b = (unsigned short*)(c2 + 64);  // 49152
  unsigned short* W2b = W1b + 49152;                 // 16384
  unsigned short* Welb = W2b + 16384;                // 4096
  unsigned short* y_bf = Welb + 4096;                // NH
  int* deg = (int*)(y_bf + NH);                      // N
  int* off = deg + N;                                // N
  int* cur = off + N;                                // N
  int* bsum = cur + N;                               // 128
  int* gstart = bsum + 128;                          // 64
  int* gend = gstart + 64;                           // 64
  int* bgidA = gend + 64;                            // nblk
  int* bgidB = bgidA + nblk;                         // nblk
  float* bmaxA = (float*)(bgidB + nblk);             // nblk*64
  float* bmaxB = bmaxA + (size_t)nblk * 64;          // nblk*64
  uint2* spack = (uint2*)(((size_t)(bmaxB + (size_t)nblk * 64) + 15) & ~(size_t)15);  // E

  float* outp = (float*)d_out;

  k_init<<<(77824 + 3 * N + 64 + 255) / 256, 256, 0, stream>>>(
      v0, v1, wte, Wi0, bi0, Wi1, bi1, batch, gstart, gend,
      u, xu_enc, W1b, W2b, Welb, W_n1, W_n2, W_el, b_el, W_edge, b_edge,
      p, q, c0, c1, c2, deg, cur, N);
  k_hist<<<(E + 255) / 256, 256, 0, stream>>>(eidx, deg, E);
  k_scan1<<<NB512, 256, 0, stream>>>(deg, off, bsum, N);
  k_scan2<<<1, 128, 0, stream>>>(bsum, NB512);
  k_scatter<<<(E + 255) / 256, 256, 0, stream>>>(eidx, dist, off, bsum, cur, spack, E);

  for (int l = 0; l < 4; ++l) {
    if (l == 0) {
      k_node<0><<<nblk, 256, 0, stream>>>(off, bsum, spack, p, q, c0, c1, c2, v0, v1,
                                          wte, Wi0, bi0, Wi1, bi1,
                                          x, y_bf, batch, u, W1b, W2b, Welb, b_n1, b_n2,
                                          xu_enc, bmaxA, bmaxB, bgidA, bgidB,
                                          Wo0, bo0, Wo1, bo1, outp, N);
    } else if (l < 3) {
      k_node<1><<<nblk, 256, 0, stream>>>(off, bsum, spack, p, q, c0, c1, c2, v0, v1,
                                          wte, Wi0, bi0, Wi1, bi1,
                                          x, y_bf, batch, u, W1b, W2b, Welb, b_n1, b_n2,
                                          xu_enc, bmaxA, bmaxB, bgidA, bgidB,
                                          Wo0, bo0, Wo1, bo1, outp, N);
    } else {
      k_node<2><<<nblk, 256, 0, stream>>>(off, bsum, spack, p, q, c0, c1, c2, v0, v1,
                                          wte, Wi0, bi0, Wi1, bi1,
                                          x, y_bf, batch, u, W1b, W2b, Welb, b_n1, b_n2,
                                          xu_enc, bmaxA, bmaxB, bgidA, bgidB,
                                          Wo0, bo0, Wo1, bo1, outp, N);
    }
    k_graph<<<64, 256, 0, stream>>>(gstart, gend, bmaxA, bmaxB, bgidA, bgidB,
                                    xu_enc, u, W_gl, b_gl, W_ih, b_ih, b_hh,
                                    outp + 2 * N + l * 4096);
  }
}